// Round 1
// baseline (8409.581 us; speedup 1.0000x reference)
//
#include <hip/hip_runtime.h>
#include <math.h>

using f16 = _Float16;
typedef __attribute__((ext_vector_type(8))) _Float16 f16x8;
typedef __attribute__((ext_vector_type(4))) _Float16 f16x4;
typedef __attribute__((ext_vector_type(4))) float f32x4;

#define T_STEPS 128
#define HID 400
#define G4 1600
#define XPLD 3200
#define HLD 416

// ---------------- conversion kernels ----------------
__global__ void k_cvt_f16(const float* __restrict__ s, f16* __restrict__ d, long long n) {
  long long i = ((long long)blockIdx.x * blockDim.x + threadIdx.x) * 4;
  long long stride = (long long)gridDim.x * blockDim.x * 4;
  for (; i < n; i += stride) {
    float4 v = *(const float4*)(s + i);
    f16x4 o = { (f16)v.x, (f16)v.y, (f16)v.z, (f16)v.w };
    *(f16x4*)(d + i) = o;
  }
}

// Whh (rows x 400) -> padded (rows x 416), cols 400..416 = 0
__global__ void k_cvt_whh(const float* __restrict__ s, f16* __restrict__ d, int nrows) {
  long long n = (long long)nrows * HLD;
  for (long long i = (long long)blockIdx.x * blockDim.x + threadIdx.x; i < n;
       i += (long long)gridDim.x * blockDim.x) {
    int row = (int)(i / HLD), c = (int)(i % HLD);
    d[i] = (c < HID) ? (f16)s[(long long)row * HID + c] : (f16)0.f;
  }
}

__global__ void k_bias(const float* __restrict__ a, const float* __restrict__ b,
                       float* __restrict__ d, int n) {
  for (int i = blockIdx.x * blockDim.x + threadIdx.x; i < n; i += gridDim.x * blockDim.x)
    d[i] = a[i] + b[i];
}

// ---------------- input-projection GEMM ----------------
// C[m][n] = sum_k A[m][k] * Bw[n][k];  A: M x lda (row-major), Bw: 3200 x 800 slab
// (row-major, K-contiguous), C: f16, ldc = 3200.  Tile 128x128, BK=32.
// grid = (25, M/128): blockIdx.x = n-tile (fast) so A panel reuses in L2.
__global__ __launch_bounds__(256) void k_gemm(const f16* __restrict__ A,
                                              const f16* __restrict__ Bw,
                                              f16* __restrict__ C, int lda, int K) {
  __shared__ f16 As[128 * 40];   // +8 pad per row: bank-conflict-light
  __shared__ f16 Bs[128 * 40];
  const int tid = threadIdx.x;
  const int lane = tid & 63, w = tid >> 6;
  const int wm = w >> 1, wn = w & 1;
  const int bn = blockIdx.x * 128;
  const long long bm = (long long)blockIdx.y * 128;

  const int srow = tid >> 1, scb = (tid & 1) * 16;
  const f16* gA = A + (bm + srow) * (long long)lda + scb;
  const f16* gB = Bw + (long long)(bn + srow) * 800 + scb;
  f16* lA = &As[srow * 40 + scb];
  f16* lB = &Bs[srow * 40 + scb];

  const int lr = lane & 15;
  const int kreg = (lane >> 4) * 8;

  f32x4 acc[4][4] = {};

  for (int k0 = 0; k0 < K; k0 += 32) {
    f16x8 a0 = *(const f16x8*)(gA + k0);
    f16x8 a1 = *(const f16x8*)(gA + k0 + 8);
    f16x8 b0 = *(const f16x8*)(gB + k0);
    f16x8 b1 = *(const f16x8*)(gB + k0 + 8);
    __syncthreads();
    *(f16x8*)lA = a0; *(f16x8*)(lA + 8) = a1;
    *(f16x8*)lB = b0; *(f16x8*)(lB + 8) = b1;
    __syncthreads();
    f16x8 af[4], bf[4];
#pragma unroll
    for (int mt = 0; mt < 4; ++mt)
      af[mt] = *(const f16x8*)&As[(wm * 64 + mt * 16 + lr) * 40 + kreg];
#pragma unroll
    for (int nt = 0; nt < 4; ++nt)
      bf[nt] = *(const f16x8*)&Bs[(wn * 64 + nt * 16 + lr) * 40 + kreg];
#pragma unroll
    for (int mt = 0; mt < 4; ++mt)
#pragma unroll
      for (int nt = 0; nt < 4; ++nt)
        acc[mt][nt] = __builtin_amdgcn_mfma_f32_16x16x32_f16(af[mt], bf[nt], acc[mt][nt], 0, 0, 0);
  }
#pragma unroll
  for (int mt = 0; mt < 4; ++mt) {
#pragma unroll
    for (int nt = 0; nt < 4; ++nt) {
      long long gm = bm + wm * 64 + mt * 16 + ((lane >> 4) * 4);
      int gn = bn + wn * 64 + nt * 16 + lr;
#pragma unroll
      for (int r = 0; r < 4; ++r)
        C[(gm + r) * XPLD + gn] = (f16)acc[mt][nt][r];
    }
  }
}

// ---------------- fused recurrent step (both directions) ----------------
// One launch per (layer, s). Forward processes t=s, backward t=127-s.
// Blocks: 25 j-slices x (nTf + nTb) batch tiles of 128.
__global__ __launch_bounds__(256) void k_step(
    const f16* __restrict__ xp,       // (65536+128) x 3200 fp16
    const f16* __restrict__ whh,      // layer base: 2 x 1600 x 416 fp16
    const float* __restrict__ bias2,  // layer base: 2 x 1600 fp32 (bih+bhh)
    const f16* __restrict__ h16r0,    // read pp slice (dir-0 base)
    f16* __restrict__ h16w0,          // write pp slice (dir-0 base)
    float* __restrict__ hn,           // d_out h_n layer base (2 x 1024 x 400)
    float* __restrict__ cn,           // d_out c_n layer base
    f16* __restrict__ outf16,         // next-layer input buffer (or null)
    float* __restrict__ outf32,       // d_out packed (last layer, or null)
    int bs_f, int off_f, int bs_b, int off_b, int nTf) {
  const int slice = blockIdx.x % 25;
  const int tl = blockIdx.x / 25;
  int dir, bt, bs, off;
  if (tl < nTf) { dir = 0; bt = tl; bs = bs_f; off = off_f; }
  else          { dir = 1; bt = tl - nTf; bs = bs_b; off = off_b; }
  const int lane = threadIdx.x & 63, w = threadIdx.x >> 6;
  const int lr = lane & 15, kreg = (lane >> 4) * 8;
  const int b0 = bt * 128;
  const int j0 = slice * 16;
  const f16* hr = h16r0 + (size_t)dir * (2 * 1024 * HLD);
  f16* hw = h16w0 + (size_t)dir * (2 * 1024 * HLD);
  const f16* W = whh + (size_t)dir * (G4 * HLD);
  const float* bi = bias2 + dir * G4;
  float* hp = hn + (size_t)dir * (1024 * HID);
  float* cp = cn + (size_t)dir * (1024 * HID);

  f32x4 acc[2][4] = {};
  for (int k0 = 0; k0 < HLD; k0 += 32) {
    f16x8 af0 = *(const f16x8*)&hr[(b0 + (w * 2 + 0) * 16 + lr) * HLD + k0 + kreg];
    f16x8 af1 = *(const f16x8*)&hr[(b0 + (w * 2 + 1) * 16 + lr) * HLD + k0 + kreg];
#pragma unroll
    for (int g = 0; g < 4; ++g) {
      f16x8 bf = *(const f16x8*)&W[(g * HID + j0 + lr) * HLD + k0 + kreg];
      acc[0][g] = __builtin_amdgcn_mfma_f32_16x16x32_f16(af0, bf, acc[0][g], 0, 0, 0);
      acc[1][g] = __builtin_amdgcn_mfma_f32_16x16x32_f16(af1, bf, acc[1][g], 0, 0, 0);
    }
  }
  const int j = j0 + lr;
#pragma unroll
  for (int mt = 0; mt < 2; ++mt) {
#pragma unroll
    for (int r = 0; r < 4; ++r) {
      int b = b0 + (w * 2 + mt) * 16 + (lane >> 4) * 4 + r;
      if (b < bs) {
        size_t prow = (size_t)(off + b);
        const f16* xr = xp + prow * XPLD + dir * G4;
        float Gi = acc[mt][0][r] + (float)xr[j]           + bi[j];
        float Gf = acc[mt][1][r] + (float)xr[HID + j]     + bi[HID + j];
        float Gg = acc[mt][2][r] + (float)xr[2 * HID + j] + bi[2 * HID + j];
        float Go = acc[mt][3][r] + (float)xr[3 * HID + j] + bi[3 * HID + j];
        float ii = 1.f / (1.f + __expf(-Gi));
        float ff = 1.f / (1.f + __expf(-Gf));
        float gg = 1.f - 2.f / (__expf(2.f * Gg) + 1.f);
        float oo = 1.f / (1.f + __expf(-Go));
        float co = cp[b * HID + j];
        float cnew = ff * co + ii * gg;
        float hnew = oo * (1.f - 2.f / (__expf(2.f * cnew) + 1.f));
        cp[b * HID + j] = cnew;
        hp[b * HID + j] = hnew;
        hw[b * HLD + j] = (f16)hnew;
        if (outf32) outf32[prow * 800 + dir * HID + j] = hnew;
        else        outf16[prow * 800 + dir * HID + j] = (f16)hnew;
      }
    }
  }
}

// ---------------- host ----------------
extern "C" void kernel_launch(void* const* d_in, const int* in_sizes, int n_in,
                              void* d_out, int out_size, void* d_ws, size_t ws_size,
                              hipStream_t stream) {
  (void)in_sizes; (void)n_in; (void)out_size; (void)ws_size;
  const float* x   = (const float*)d_in[0];
  const float* Wih = (const float*)d_in[1];
  const float* Whh = (const float*)d_in[2];
  const float* bih = (const float*)d_in[3];
  const float* bhh = (const float*)d_in[4];
  float* out = (float*)d_out;

  // Replicate _make_batch_sizes exactly (pure host math, input-independent).
  long long bsv[128];
  {
    double step = (1.0 - 1024.0) / 127.0;
    for (int i = 0; i < 128; ++i) {
      double m = (double)i * step;
      double v = m + 1024.0;
      bsv[i] = (long long)floor(v);
    }
    bsv[127] = 1;  // numpy linspace endpoint is exact
    bsv[0] = 1024;
    long long sum = 0;
    for (int i = 0; i < 128; ++i) sum += bsv[i];
    long long diff = 65536 - sum;
    while (diff != 0) {
      if (diff > 0) {
        for (int jj = 1; jj < 128 && diff != 0; ++jj) {
          long long cap = bsv[jj - 1] - bsv[jj];
          long long add = cap < diff ? cap : diff;
          bsv[jj] += add; diff -= add;
        }
      } else {
        for (int jj = 127; jj >= 1 && diff != 0; --jj) {
          long long nxt = (jj + 1 < 128) ? bsv[jj + 1] : 1;
          long long room = bsv[jj] - nxt;
          long long sub = room < (-diff) ? room : (-diff);
          bsv[jj] -= sub; diff += sub;
        }
      }
    }
  }
  long long offv[128], a0 = 0;
  for (int i = 0; i < 128; ++i) { offv[i] = a0; a0 += bsv[i]; }

  // workspace layout (bytes, all 256-aligned); total ~709.2 MB
  char* p = (char*)d_ws;
  f16*   x16   = (f16*)(p);                    // 65536x400 f16 (+256B pad)
  f16*   wih16 = (f16*)(p + 52429056LL);       // 6x1600x800 f16
  f16*   whh16 = (f16*)(p + 67789056LL);       // 6x1600x416 f16 (zero-padded K)
  float* bias  = (float*)(p + 75776256LL);     // 6x1600 f32 (bih+bhh)
  f16*   xproj = (f16*)(p + 75814656LL);       // (65536+128)x3200 f16
  f16*   layA  = (f16*)(p + 496064256LL);      // 65536x800 f16
  f16*   layB  = (f16*)(p + 600921856LL);      // 65536x800 f16
  f16*   h16   = (f16*)(p + 705779456LL);      // 2 dir x 2 pp x 1024x416 f16

  hipMemsetAsync(p + 52428800LL, 0, 256, stream);                 // x16 K-pad
  hipMemsetAsync(out + 52428800LL, 0, 4915200LL * 4, stream);     // h_n + c_n

  k_cvt_f16<<<2048, 256, 0, stream>>>(x, x16, 26214400LL);
  k_cvt_f16<<<2048, 256, 0, stream>>>(Wih, wih16, 7680000LL);
  k_cvt_whh<<<2048, 256, 0, stream>>>(Whh, whh16, 9600);
  k_bias<<<40, 256, 0, stream>>>(bih, bhh, bias, 9600);

  const long long OUTP = 52428800LL, HNSZ = 2457600LL;

  for (int L = 0; L < 3; ++L) {
    const f16* Ain = (L == 0) ? x16 : (L == 1 ? layA : layB);
    int lda = (L == 0) ? 400 : 800;
    int K   = (L == 0) ? 416 : 800;   // layer0: K padded; Wih cols 400..416 are zeros
    k_gemm<<<dim3(25, 512), 256, 0, stream>>>(Ain, wih16 + (size_t)(2 * L) * 1600 * 800,
                                              xproj, lda, K);
    hipMemsetAsync(h16, 0, 3407872LL, stream);  // reset recurrent f16 state per layer
    float* hnL = out + OUTP + (size_t)(2 * L) * 409600;
    float* cnL = out + OUTP + HNSZ + (size_t)(2 * L) * 409600;
    f16* o16 = (L == 0) ? layA : (L == 1 ? layB : nullptr);
    float* o32 = (L == 2) ? out : nullptr;
    for (int s = 0; s < 128; ++s) {
      int tf = s, tb = 127 - s;
      int bsf = (int)bsv[tf], bsb = (int)bsv[tb];
      int nTf = (bsf + 127) / 128, nTb = (bsb + 127) / 128;
      k_step<<<25 * (nTf + nTb), 256, 0, stream>>>(
          xproj, whh16 + (size_t)(2 * L) * 1600 * HLD, bias + (size_t)(2 * L) * 1600,
          h16 + (size_t)(s & 1) * 1024 * HLD, h16 + (size_t)((s + 1) & 1) * 1024 * HLD,
          hnL, cnL, o16, o32,
          bsf, (int)offv[tf], bsb, (int)offv[tb], nTf);
    }
  }
}

// Round 2
// 8324.324 us; speedup vs baseline: 1.0102x; 1.0102x over previous
//
#include <hip/hip_runtime.h>
#include <math.h>

using f16 = _Float16;
typedef __attribute__((ext_vector_type(8))) _Float16 f16x8;
typedef __attribute__((ext_vector_type(4))) _Float16 f16x4;
typedef __attribute__((ext_vector_type(4))) float f32x4;

#define T_STEPS 128
#define HID 400
#define G4 1600
#define XPLD 3200
#define HLD 416
#define WPAD 424
#define RNN_BLOCKS 400

__device__ __forceinline__ void gl_lds16(const void* g, void* l) {
  __builtin_amdgcn_global_load_lds((const __attribute__((address_space(1))) void*)g,
                                   (__attribute__((address_space(3))) void*)l, 16, 0, 0);
}

// ---------------- conversion kernels ----------------
__global__ void k_cvt_f16(const float* __restrict__ s, f16* __restrict__ d, long long n) {
  long long i = ((long long)blockIdx.x * blockDim.x + threadIdx.x) * 4;
  long long stride = (long long)gridDim.x * blockDim.x * 4;
  for (; i < n; i += stride) {
    float4 v = *(const float4*)(s + i);
    f16x4 o = { (f16)v.x, (f16)v.y, (f16)v.z, (f16)v.w };
    *(f16x4*)(d + i) = o;
  }
}

__global__ void k_cvt_whh(const float* __restrict__ s, f16* __restrict__ d, int nrows) {
  long long n = (long long)nrows * HLD;
  for (long long i = (long long)blockIdx.x * blockDim.x + threadIdx.x; i < n;
       i += (long long)gridDim.x * blockDim.x) {
    int row = (int)(i / HLD), c = (int)(i % HLD);
    d[i] = (c < HID) ? (f16)s[(long long)row * HID + c] : (f16)0.f;
  }
}

__global__ void k_bias(const float* __restrict__ a, const float* __restrict__ b,
                       float* __restrict__ d, int n) {
  for (int i = blockIdx.x * blockDim.x + threadIdx.x; i < n; i += gridDim.x * blockDim.x)
    d[i] = a[i] + b[i];
}

// ---------------- input-projection GEMM (m97 structure) ----------------
// C[m][n] = sum_k A[m][k]*Bw[n][k]; A: M x lda, Bw: 3200 x 800, C f16 ldc=3200.
// 128x128 tile, BK=32, global_load_lds width-16 staging, linear LDS.
__global__ __launch_bounds__(256) void k_gemm(const f16* __restrict__ A,
                                              const f16* __restrict__ Bw,
                                              f16* __restrict__ C, int lda, int K) {
  __shared__ f16 As[128 * 32];
  __shared__ f16 Bs[128 * 32];
  const int tid = threadIdx.x;
  const int lane = tid & 63, w = tid >> 6;
  const int wm = w >> 1, wn = w & 1;
  const int bn = blockIdx.x * 128;
  const long long bm = (long long)blockIdx.y * 128;

  // staging addresses: wave w covers 16 rows; lane l -> row l>>2, ksub (l&3)*8
  const f16* gA = A + (bm + w * 16 + (lane >> 2)) * (long long)lda + (lane & 3) * 8;
  const f16* gB = Bw + (long long)(bn + w * 16 + (lane >> 2)) * 800 + (lane & 3) * 8;
  f16* lA = As + w * 16 * 32;
  f16* lB = Bs + w * 16 * 32;

  const int lr = lane & 15;
  const int kreg = (lane >> 4) * 8;

  f32x4 acc[4][4] = {};

  for (int k0 = 0; k0 < K; k0 += 32) {
    __syncthreads();
    gl_lds16(gA + k0, lA);
    gl_lds16(gA + 64LL * lda + k0, lA + 64 * 32);
    gl_lds16(gB + k0, lB);
    gl_lds16(gB + 64LL * 800 + k0, lB + 64 * 32);
    __syncthreads();
    f16x8 af[4], bf[4];
#pragma unroll
    for (int mt = 0; mt < 4; ++mt)
      af[mt] = *(const f16x8*)&As[(wm * 64 + mt * 16 + lr) * 32 + kreg];
#pragma unroll
    for (int nt = 0; nt < 4; ++nt)
      bf[nt] = *(const f16x8*)&Bs[(wn * 64 + nt * 16 + lr) * 32 + kreg];
#pragma unroll
    for (int mt = 0; mt < 4; ++mt)
#pragma unroll
      for (int nt = 0; nt < 4; ++nt)
        acc[mt][nt] = __builtin_amdgcn_mfma_f32_16x16x32_f16(af[mt], bf[nt], acc[mt][nt], 0, 0, 0);
  }
#pragma unroll
  for (int mt = 0; mt < 4; ++mt) {
#pragma unroll
    for (int nt = 0; nt < 4; ++nt) {
      long long gm = bm + wm * 64 + mt * 16 + ((lane >> 4) * 4);
      int gn = bn + wn * 64 + nt * 16 + lr;
#pragma unroll
      for (int r = 0; r < 4; ++r)
        C[(gm + r) * XPLD + gn] = (f16)acc[mt][nt][r];
    }
  }
}

// ---------------- persistent recurrence (one launch per layer) ----------------
// 400 blocks: slice(25) x [dir(2) x btile(8)]. W slice resident in LDS.
// Grid-wide sense barrier between time steps (device-scope atomics).
__global__ __launch_bounds__(256, 2) void k_rnn(
    const f16* __restrict__ xp, const f16* __restrict__ whh,
    const float* __restrict__ bias2, f16* __restrict__ h16,
    float* __restrict__ hn, float* __restrict__ cn,
    f16* __restrict__ outf16, float* __restrict__ outf32,
    unsigned* __restrict__ bar, int nblocks) {
  __shared__ f16 Wl[64 * WPAD];
  __shared__ int bsT[T_STEPS], offT[T_STEPS];

  const int tid = threadIdx.x;
  const int slice = blockIdx.x % 25;
  const int q = blockIdx.x / 25;
  const int dir = q >> 3, bt = q & 7;
  const int lane = tid & 63, w = tid >> 6;
  const int lr = lane & 15, kreg = (lane >> 4) * 8;
  const int j0 = slice * 16;
  const int j = j0 + lr;

  // --- step table (thread 0, replicates numpy linspace+floor+redistribute) ---
  if (tid == 0) {
    double step = (1.0 - 1024.0) / 127.0;
    for (int i = 0; i < T_STEPS; ++i) bsT[i] = (int)floor((double)i * step + 1024.0);
    bsT[127] = 1; bsT[0] = 1024;
    int sum = 0;
    for (int i = 0; i < T_STEPS; ++i) sum += bsT[i];
    int diff = 65536 - sum;
    while (diff != 0) {
      if (diff > 0) {
        for (int jj = 1; jj < T_STEPS && diff != 0; ++jj) {
          int cap = bsT[jj - 1] - bsT[jj];
          int add = cap < diff ? cap : diff;
          bsT[jj] += add; diff -= add;
        }
      } else {
        for (int jj = T_STEPS - 1; jj >= 1 && diff != 0; --jj) {
          int nxt = (jj + 1 < T_STEPS) ? bsT[jj + 1] : 1;
          int room = bsT[jj] - nxt;
          int sub = room < (-diff) ? room : (-diff);
          bsT[jj] -= sub; diff += sub;
        }
      }
    }
    int a0 = 0;
    for (int i = 0; i < T_STEPS; ++i) { offT[i] = a0; a0 += bsT[i]; }
  }

  // --- load W slice into LDS (rows: 4 gates x 16 j; cols 416, pad to 424) ---
  const f16* whhD = whh + (size_t)dir * (G4 * HLD);
  {
    int rr = tid >> 2, seg = tid & 3;
    int g = rr >> 4, jr = rr & 15;
    const f16* src = whhD + (size_t)(g * HID + j0 + jr) * HLD + seg * 104;
    f16* dst = &Wl[rr * WPAD + seg * 104];
#pragma unroll
    for (int kk = 0; kk < 13; ++kk)
      *(f16x8*)(dst + kk * 8) = *(const f16x8*)(src + kk * 8);
  }
  const float* biD = bias2 + dir * G4;
  const float bi0 = biD[j], bi1 = biD[HID + j], bi2 = biD[2 * HID + j], bi3 = biD[3 * HID + j];
  float* hp = hn + (size_t)dir * (1024 * HID);
  float* cp = cn + (size_t)dir * (1024 * HID);
  __syncthreads();

#pragma unroll 1
  for (int s = 0; s < T_STEPS; ++s) {
    const int t = dir ? (T_STEPS - 1 - s) : s;
    const int bs = bsT[t], off = offT[t];
    const int cur = s & 1;
    const f16* hr = h16 + (size_t)((dir << 1) | cur) * (1024 * HLD);
    f16* hww = h16 + (size_t)((dir << 1) | (cur ^ 1)) * (1024 * HLD);

    if (bt * 128 < bs) {
      const f16* ha = hr + (size_t)(bt * 128 + w * 32 + lr) * HLD + kreg;
      f32x4 acc[2][4] = {};
#pragma unroll
      for (int k0 = 0; k0 < HLD; k0 += 32) {
        f16x8 a0 = *(const f16x8*)(ha + k0);
        f16x8 a1 = *(const f16x8*)(ha + 16 * HLD + k0);
#pragma unroll
        for (int g = 0; g < 4; ++g) {
          f16x8 bf = *(const f16x8*)&Wl[(g * 16 + lr) * WPAD + k0 + kreg];
          acc[0][g] = __builtin_amdgcn_mfma_f32_16x16x32_f16(a0, bf, acc[0][g], 0, 0, 0);
          acc[1][g] = __builtin_amdgcn_mfma_f32_16x16x32_f16(a1, bf, acc[1][g], 0, 0, 0);
        }
      }
#pragma unroll
      for (int mt = 0; mt < 2; ++mt) {
#pragma unroll
        for (int r = 0; r < 4; ++r) {
          int b = bt * 128 + w * 32 + mt * 16 + (lane >> 4) * 4 + r;
          if (b < bs) {
            size_t prow = (size_t)(off + b);
            const f16* xr = xp + prow * XPLD + dir * G4;
            float Gi = acc[mt][0][r] + (float)xr[j]           + bi0;
            float Gf = acc[mt][1][r] + (float)xr[HID + j]     + bi1;
            float Gg = acc[mt][2][r] + (float)xr[2 * HID + j] + bi2;
            float Go = acc[mt][3][r] + (float)xr[3 * HID + j] + bi3;
            float ii = 1.f / (1.f + __expf(-Gi));
            float ff = 1.f / (1.f + __expf(-Gf));
            float gg = 1.f - 2.f / (__expf(2.f * Gg) + 1.f);
            float oo = 1.f / (1.f + __expf(-Go));
            float co = cp[b * HID + j];
            float cnew = ff * co + ii * gg;
            float hnew = oo * (1.f - 2.f / (__expf(2.f * cnew) + 1.f));
            cp[b * HID + j] = cnew;
            hp[b * HID + j] = hnew;
            hww[b * HLD + j] = (f16)hnew;
            if (outf32) outf32[prow * 800 + dir * HID + j] = hnew;
            else        outf16[prow * 800 + dir * HID + j] = (f16)hnew;
          }
        }
      }
    }
    // ---- grid barrier (skip after last step) ----
    if (s != T_STEPS - 1) {
      __syncthreads();
      if (tid == 0) {
        __hip_atomic_fetch_add(bar, 1u, __ATOMIC_RELEASE, __HIP_MEMORY_SCOPE_AGENT);
        const unsigned tgt = (unsigned)nblocks * (unsigned)(s + 1);
        while (__hip_atomic_load(bar, __ATOMIC_ACQUIRE, __HIP_MEMORY_SCOPE_AGENT) < tgt)
          __builtin_amdgcn_s_sleep(2);
      }
      __syncthreads();
    }
  }
}

// ---------------- fallback per-step kernel (round-0, proven) ----------------
__global__ __launch_bounds__(256) void k_step(
    const f16* __restrict__ xp, const f16* __restrict__ whh,
    const float* __restrict__ bias2, const f16* __restrict__ h16r0,
    f16* __restrict__ h16w0, float* __restrict__ hn, float* __restrict__ cn,
    f16* __restrict__ outf16, float* __restrict__ outf32,
    int bs_f, int off_f, int bs_b, int off_b, int nTf) {
  const int slice = blockIdx.x % 25;
  const int tl = blockIdx.x / 25;
  int dir, bt, bs, off;
  if (tl < nTf) { dir = 0; bt = tl; bs = bs_f; off = off_f; }
  else          { dir = 1; bt = tl - nTf; bs = bs_b; off = off_b; }
  const int lane = threadIdx.x & 63, w = threadIdx.x >> 6;
  const int lr = lane & 15, kreg = (lane >> 4) * 8;
  const int b0 = bt * 128;
  const int j0 = slice * 16;
  const f16* hr = h16r0 + (size_t)dir * (2 * 1024 * HLD);
  f16* hw = h16w0 + (size_t)dir * (2 * 1024 * HLD);
  const f16* W = whh + (size_t)dir * (G4 * HLD);
  const float* bi = bias2 + dir * G4;
  float* hp = hn + (size_t)dir * (1024 * HID);
  float* cp = cn + (size_t)dir * (1024 * HID);

  f32x4 acc[2][4] = {};
  for (int k0 = 0; k0 < HLD; k0 += 32) {
    f16x8 af0 = *(const f16x8*)&hr[(b0 + (w * 2 + 0) * 16 + lr) * HLD + k0 + kreg];
    f16x8 af1 = *(const f16x8*)&hr[(b0 + (w * 2 + 1) * 16 + lr) * HLD + k0 + kreg];
#pragma unroll
    for (int g = 0; g < 4; ++g) {
      f16x8 bf = *(const f16x8*)&W[(g * HID + j0 + lr) * HLD + k0 + kreg];
      acc[0][g] = __builtin_amdgcn_mfma_f32_16x16x32_f16(af0, bf, acc[0][g], 0, 0, 0);
      acc[1][g] = __builtin_amdgcn_mfma_f32_16x16x32_f16(af1, bf, acc[1][g], 0, 0, 0);
    }
  }
  const int j = j0 + lr;
#pragma unroll
  for (int mt = 0; mt < 2; ++mt) {
#pragma unroll
    for (int r = 0; r < 4; ++r) {
      int b = b0 + (w * 2 + mt) * 16 + (lane >> 4) * 4 + r;
      if (b < bs) {
        size_t prow = (size_t)(off + b);
        const f16* xr = xp + prow * XPLD + dir * G4;
        float Gi = acc[mt][0][r] + (float)xr[j]           + bi[j];
        float Gf = acc[mt][1][r] + (float)xr[HID + j]     + bi[HID + j];
        float Gg = acc[mt][2][r] + (float)xr[2 * HID + j] + bi[2 * HID + j];
        float Go = acc[mt][3][r] + (float)xr[3 * HID + j] + bi[3 * HID + j];
        float ii = 1.f / (1.f + __expf(-Gi));
        float ff = 1.f / (1.f + __expf(-Gf));
        float gg = 1.f - 2.f / (__expf(2.f * Gg) + 1.f);
        float oo = 1.f / (1.f + __expf(-Go));
        float co = cp[b * HID + j];
        float cnew = ff * co + ii * gg;
        float hnew = oo * (1.f - 2.f / (__expf(2.f * cnew) + 1.f));
        cp[b * HID + j] = cnew;
        hp[b * HID + j] = hnew;
        hw[b * HLD + j] = (f16)hnew;
        if (outf32) outf32[prow * 800 + dir * HID + j] = hnew;
        else        outf16[prow * 800 + dir * HID + j] = (f16)hnew;
      }
    }
  }
}

// ---------------- host ----------------
extern "C" void kernel_launch(void* const* d_in, const int* in_sizes, int n_in,
                              void* d_out, int out_size, void* d_ws, size_t ws_size,
                              hipStream_t stream) {
  (void)in_sizes; (void)n_in; (void)out_size; (void)ws_size;
  const float* x   = (const float*)d_in[0];
  const float* Wih = (const float*)d_in[1];
  const float* Whh = (const float*)d_in[2];
  const float* bih = (const float*)d_in[3];
  const float* bhh = (const float*)d_in[4];
  float* out = (float*)d_out;

  // step table (host copy, for fallback path)
  long long bsv[128];
  {
    double step = (1.0 - 1024.0) / 127.0;
    for (int i = 0; i < 128; ++i) bsv[i] = (long long)floor((double)i * step + 1024.0);
    bsv[127] = 1; bsv[0] = 1024;
    long long sum = 0;
    for (int i = 0; i < 128; ++i) sum += bsv[i];
    long long diff = 65536 - sum;
    while (diff != 0) {
      if (diff > 0) {
        for (int jj = 1; jj < 128 && diff != 0; ++jj) {
          long long cap = bsv[jj - 1] - bsv[jj];
          long long add = cap < diff ? cap : diff;
          bsv[jj] += add; diff -= add;
        }
      } else {
        for (int jj = 127; jj >= 1 && diff != 0; --jj) {
          long long nxt = (jj + 1 < 128) ? bsv[jj + 1] : 1;
          long long room = bsv[jj] - nxt;
          long long sub = room < (-diff) ? room : (-diff);
          bsv[jj] -= sub; diff += sub;
        }
      }
    }
  }
  long long offv[128], a0 = 0;
  for (int i = 0; i < 128; ++i) { offv[i] = a0; a0 += bsv[i]; }

  // workspace layout
  char* p = (char*)d_ws;
  f16*      x16   = (f16*)(p);                 // 65536x400 f16 (+pad)
  unsigned* bar   = (unsigned*)(p + 52428928); // barrier counter (in x16 pad gap)
  f16*      wih16 = (f16*)(p + 52429056LL);    // 6x1600x800 f16
  f16*      whh16 = (f16*)(p + 67789056LL);    // 6x1600x416 f16 (zero-padded K)
  float*    bias  = (float*)(p + 75776256LL);  // 6x1600 f32
  f16*      xproj = (f16*)(p + 75814656LL);    // (65536+128)x3200 f16
  f16*      layA  = (f16*)(p + 496064256LL);   // 65536x800 f16
  f16*      layB  = (f16*)(p + 600921856LL);   // 65536x800 f16
  f16*      h16   = (f16*)(p + 705779456LL);   // 2 dir x 2 pp x 1024x416 f16

  hipMemsetAsync(p + 52428800LL, 0, 256, stream);              // x16 K-pad + bar
  hipMemsetAsync(out + 52428800LL, 0, 4915200LL * 4, stream);  // h_n + c_n

  k_cvt_f16<<<2048, 256, 0, stream>>>(x, x16, 26214400LL);
  k_cvt_f16<<<2048, 256, 0, stream>>>(Wih, wih16, 7680000LL);
  k_cvt_whh<<<2048, 256, 0, stream>>>(Whh, whh16, 9600);
  k_bias<<<40, 256, 0, stream>>>(bih, bhh, bias, 9600);

  int occ = 0;
  hipOccupancyMaxActiveBlocksPerMultiprocessor(&occ, k_rnn, 256, 0);
  const bool persistent = (occ >= 2);  // 2/CU x 256 CU = 512 >= 400 co-resident

  const long long OUTP = 52428800LL, HNSZ = 2457600LL;

  for (int L = 0; L < 3; ++L) {
    const f16* Ain = (L == 0) ? x16 : (L == 1 ? layA : layB);
    int lda = (L == 0) ? 400 : 800;
    int K   = (L == 0) ? 416 : 800;
    k_gemm<<<dim3(25, 512), 256, 0, stream>>>(Ain, wih16 + (size_t)(2 * L) * 1600 * 800,
                                              xproj, lda, K);
    hipMemsetAsync(h16, 0, 3407872LL, stream);
    float* hnL = out + OUTP + (size_t)(2 * L) * 409600;
    float* cnL = out + OUTP + HNSZ + (size_t)(2 * L) * 409600;
    f16* o16 = (L == 0) ? layA : (L == 1 ? layB : nullptr);
    float* o32 = (L == 2) ? out : nullptr;
    if (persistent) {
      hipMemsetAsync(bar, 0, 4, stream);
      k_rnn<<<RNN_BLOCKS, 256, 0, stream>>>(
          xproj, whh16 + (size_t)(2 * L) * 1600 * HLD, bias + (size_t)(2 * L) * 1600,
          h16, hnL, cnL, o16, o32, bar, RNN_BLOCKS);
    } else {
      for (int s = 0; s < 128; ++s) {
        int tf = s, tb = 127 - s;
        int bsf = (int)bsv[tf], bsb = (int)bsv[tb];
        int nTf = (bsf + 127) / 128, nTb = (bsb + 127) / 128;
        k_step<<<25 * (nTf + nTb), 256, 0, stream>>>(
            xproj, whh16 + (size_t)(2 * L) * 1600 * HLD, bias + (size_t)(2 * L) * 1600,
            h16 + (size_t)(s & 1) * 1024 * HLD, h16 + (size_t)((s + 1) & 1) * 1024 * HLD,
            hnL, cnL, o16, o32,
            bsf, (int)offv[tf], bsb, (int)offv[tb], nTf);
      }
    }
  }
}

// Round 3
// 8084.071 us; speedup vs baseline: 1.0403x; 1.0297x over previous
//
#include <hip/hip_runtime.h>
#include <math.h>

using f16 = _Float16;
typedef __attribute__((ext_vector_type(8))) _Float16 f16x8;
typedef __attribute__((ext_vector_type(4))) _Float16 f16x4;
typedef __attribute__((ext_vector_type(4))) float f32x4;

#define T_STEPS 128
#define HID 400
#define G4 1600
#define XPLD 3200
#define HLD 416
#define WPAD 424
#define RNN_BLOCKS 400

__device__ __forceinline__ void gl_lds16(const void* g, void* l) {
  __builtin_amdgcn_global_load_lds((const __attribute__((address_space(1))) void*)g,
                                   (__attribute__((address_space(3))) void*)l, 16, 0, 0);
}

// ---------------- conversion kernels ----------------
__global__ void k_cvt_f16(const float* __restrict__ s, f16* __restrict__ d, long long n) {
  long long i = ((long long)blockIdx.x * blockDim.x + threadIdx.x) * 4;
  long long stride = (long long)gridDim.x * blockDim.x * 4;
  for (; i < n; i += stride) {
    float4 v = *(const float4*)(s + i);
    f16x4 o = { (f16)v.x, (f16)v.y, (f16)v.z, (f16)v.w };
    *(f16x4*)(d + i) = o;
  }
}

__global__ void k_cvt_whh(const float* __restrict__ s, f16* __restrict__ d, int nrows) {
  long long n = (long long)nrows * HLD;
  for (long long i = (long long)blockIdx.x * blockDim.x + threadIdx.x; i < n;
       i += (long long)gridDim.x * blockDim.x) {
    int row = (int)(i / HLD), c = (int)(i % HLD);
    d[i] = (c < HID) ? (f16)s[(long long)row * HID + c] : (f16)0.f;
  }
}

__global__ void k_bias(const float* __restrict__ a, const float* __restrict__ b,
                       float* __restrict__ d, int n) {
  for (int i = blockIdx.x * blockDim.x + threadIdx.x; i < n; i += gridDim.x * blockDim.x)
    d[i] = a[i] + b[i];
}

// ---------------- input-projection GEMM ----------------
// C[m][n'] = sum_k A[m][k]*Bw[n][k]; 128x128 tile, BK=32, global_load_lds staging.
// Output col permuted: n = dir*1600+g*400+j  ->  n' = dir*1600 + (j/16)*64 + g*16 + j%16
// so the rnn's per-row 4-gate x-reads are one contiguous 128B chunk.
__global__ __launch_bounds__(256) void k_gemm(const f16* __restrict__ A,
                                              const f16* __restrict__ Bw,
                                              f16* __restrict__ C, int lda, int K) {
  __shared__ f16 As[128 * 32];
  __shared__ f16 Bs[128 * 32];
  const int tid = threadIdx.x;
  const int lane = tid & 63, w = tid >> 6;
  const int wm = w >> 1, wn = w & 1;
  // bijective XCD swizzle (12800 % 8 == 0): each XCD gets a contiguous chunk
  const int wg = blockIdx.x;
  const int swz = (wg & 7) * 1600 + (wg >> 3);
  const int bn = (swz % 25) * 128;
  const long long bm = (long long)(swz / 25) * 128;

  const f16* gA = A + (bm + w * 16 + (lane >> 2)) * (long long)lda + (lane & 3) * 8;
  const f16* gB = Bw + (long long)(bn + w * 16 + (lane >> 2)) * 800 + (lane & 3) * 8;
  f16* lA = As + w * 16 * 32;
  f16* lB = Bs + w * 16 * 32;

  const int lr = lane & 15;
  const int kreg = (lane >> 4) * 8;

  f32x4 acc[4][4] = {};

  for (int k0 = 0; k0 < K; k0 += 32) {
    __syncthreads();
    gl_lds16(gA + k0, lA);
    gl_lds16(gA + 64LL * lda + k0, lA + 64 * 32);
    gl_lds16(gB + k0, lB);
    gl_lds16(gB + 64LL * 800 + k0, lB + 64 * 32);
    __syncthreads();
    f16x8 af[4], bf[4];
#pragma unroll
    for (int mt = 0; mt < 4; ++mt)
      af[mt] = *(const f16x8*)&As[(wm * 64 + mt * 16 + lr) * 32 + kreg];
#pragma unroll
    for (int nt = 0; nt < 4; ++nt)
      bf[nt] = *(const f16x8*)&Bs[(wn * 64 + nt * 16 + lr) * 32 + kreg];
#pragma unroll
    for (int mt = 0; mt < 4; ++mt)
#pragma unroll
      for (int nt = 0; nt < 4; ++nt)
        acc[mt][nt] = __builtin_amdgcn_mfma_f32_16x16x32_f16(af[mt], bf[nt], acc[mt][nt], 0, 0, 0);
  }
#pragma unroll
  for (int mt = 0; mt < 4; ++mt) {
#pragma unroll
    for (int nt = 0; nt < 4; ++nt) {
      long long gm = bm + wm * 64 + mt * 16 + ((lane >> 4) * 4);
      int n = bn + wn * 64 + nt * 16 + lr;
      int dirn = (n >= G4) ? 1 : 0;
      int rem = n - dirn * G4;
      int g = rem / HID;
      int jj = rem - g * HID;
      int np = dirn * G4 + ((jj >> 4) << 6) + (g << 4) + (jj & 15);
#pragma unroll
      for (int r = 0; r < 4; ++r)
        C[(gm + r) * XPLD + np] = (f16)acc[mt][nt][r];
    }
  }
}

// ---------------- persistent recurrence (one launch per layer) ----------------
// 400 blocks = 25 slices x 16 groups (dir x bt). h rows are private per (dir,bt),
// so sync is a per-group 25-block barrier (per-step counters), not grid-wide.
// c-state lives in registers (thread owns fixed (b,j) cells across steps).
__global__ __launch_bounds__(256, 2) void k_rnn(
    const f16* __restrict__ xp, const f16* __restrict__ whh,
    const float* __restrict__ bias2, f16* __restrict__ h16,
    float* __restrict__ hn, float* __restrict__ cn,
    f16* __restrict__ outf16, float* __restrict__ outf32,
    unsigned* __restrict__ cnt) {
  __shared__ f16 Wl[64 * WPAD];
  __shared__ int bsT[T_STEPS], offT[T_STEPS];

  const int tid = threadIdx.x;
  const int slice = blockIdx.x % 25;
  const int q = blockIdx.x / 25;  // 0..15 : dir*8 + bt
  const int dir = q >> 3, bt = q & 7;
  const int lane = tid & 63, w = tid >> 6;
  const int lr = lane & 15, kreg = (lane >> 4) * 8;
  const int qr4 = (lane >> 4) * 4;
  const int j0 = slice * 16;
  const int j = j0 + lr;
  unsigned* gc = cnt + (size_t)q * (T_STEPS * 32);  // 128B line per (group,step)

  if (tid == 0) {
    double step = (1.0 - 1024.0) / 127.0;
    for (int i = 0; i < T_STEPS; ++i) bsT[i] = (int)floor((double)i * step + 1024.0);
    bsT[127] = 1; bsT[0] = 1024;
    int sum = 0;
    for (int i = 0; i < T_STEPS; ++i) sum += bsT[i];
    int diff = 65536 - sum;
    while (diff != 0) {
      if (diff > 0) {
        for (int jj = 1; jj < T_STEPS && diff != 0; ++jj) {
          int cap = bsT[jj - 1] - bsT[jj];
          int add = cap < diff ? cap : diff;
          bsT[jj] += add; diff -= add;
        }
      } else {
        for (int jj = T_STEPS - 1; jj >= 1 && diff != 0; --jj) {
          int nxt = (jj + 1 < T_STEPS) ? bsT[jj + 1] : 1;
          int room = bsT[jj] - nxt;
          int sub = room < (-diff) ? room : (-diff);
          bsT[jj] -= sub; diff += sub;
        }
      }
    }
    int a0 = 0;
    for (int i = 0; i < T_STEPS; ++i) { offT[i] = a0; a0 += bsT[i]; }
  }

  // W slice -> LDS (64 rows = 4 gates x 16 j; 416 cols padded to 424)
  const f16* whhD = whh + (size_t)dir * (G4 * HLD);
  {
    int rr = tid >> 2, seg = tid & 3;
    int g = rr >> 4, jr = rr & 15;
    const f16* src = whhD + (size_t)(g * HID + j0 + jr) * HLD + seg * 104;
    f16* dst = &Wl[rr * WPAD + seg * 104];
#pragma unroll
    for (int kk = 0; kk < 13; ++kk)
      *(f16x8*)(dst + kk * 8) = *(const f16x8*)(src + kk * 8);
  }
  const float* biD = bias2 + dir * G4;
  const float bi0 = biD[j], bi1 = biD[HID + j], bi2 = biD[2 * HID + j], bi3 = biD[3 * HID + j];
  float* hp = hn + (size_t)dir * (1024 * HID);
  float* cp = cn + (size_t)dir * (1024 * HID);
  __syncthreads();

  int s_begin = 0;
  if (dir) {  // backward: skip steps where this batch tile is inactive (h provably 0)
    while (s_begin < T_STEPS && bsT[T_STEPS - 1 - s_begin] <= bt * 128) ++s_begin;
  }
  const int rowb = bt * 128 + w * 32;
  float ch[2][4] = {{0.f, 0.f, 0.f, 0.f}, {0.f, 0.f, 0.f, 0.f}};  // c-state in regs

#pragma unroll 1
  for (int s = s_begin; s < T_STEPS; ++s) {
    const int t = dir ? (T_STEPS - 1 - s) : s;
    const int bs = bsT[t], off = offT[t];

    // prefetch x gates (independent of h -> issue before barrier spin)
    f16 xg[2][4][4];
#pragma unroll
    for (int mt = 0; mt < 2; ++mt)
#pragma unroll
      for (int r = 0; r < 4; ++r) {
        const f16* xr = xp + (size_t)(off + rowb + mt * 16 + qr4 + r) * XPLD
                        + dir * G4 + slice * 64 + lr;
#pragma unroll
        for (int g = 0; g < 4; ++g) xg[mt][r][g] = xr[g * 16];
      }

    if (s > s_begin) {
      if (tid == 0) {
        while (__hip_atomic_load(gc + (size_t)(s - 1) * 32, __ATOMIC_ACQUIRE,
                                 __HIP_MEMORY_SCOPE_AGENT) < 25u)
          __builtin_amdgcn_s_sleep(2);
      }
      __syncthreads();
    }

    const int cur = s & 1;
    const f16* hr = h16 + (size_t)((dir << 1) | cur) * (1024 * HLD);
    f16* hww = h16 + (size_t)((dir << 1) | (cur ^ 1)) * (1024 * HLD);

    const f16* ha = hr + (size_t)(rowb + lr) * HLD + kreg;
    f32x4 acc[2][4] = {};
#pragma unroll
    for (int k0 = 0; k0 < HLD; k0 += 32) {
      f16x8 a0 = *(const f16x8*)(ha + k0);
      f16x8 a1 = *(const f16x8*)(ha + 16 * HLD + k0);
#pragma unroll
      for (int g = 0; g < 4; ++g) {
        f16x8 bf = *(const f16x8*)&Wl[(g * 16 + lr) * WPAD + k0 + kreg];
        acc[0][g] = __builtin_amdgcn_mfma_f32_16x16x32_f16(a0, bf, acc[0][g], 0, 0, 0);
        acc[1][g] = __builtin_amdgcn_mfma_f32_16x16x32_f16(a1, bf, acc[1][g], 0, 0, 0);
      }
    }
#pragma unroll
    for (int mt = 0; mt < 2; ++mt) {
#pragma unroll
      for (int r = 0; r < 4; ++r) {
        int b = rowb + mt * 16 + qr4 + r;
        if (b < bs) {
          size_t prow = (size_t)(off + b);
          float Gi = acc[mt][0][r] + (float)xg[mt][r][0] + bi0;
          float Gf = acc[mt][1][r] + (float)xg[mt][r][1] + bi1;
          float Gg = acc[mt][2][r] + (float)xg[mt][r][2] + bi2;
          float Go = acc[mt][3][r] + (float)xg[mt][r][3] + bi3;
          float ii = 1.f / (1.f + __expf(-Gi));
          float ff = 1.f / (1.f + __expf(-Gf));
          float gg = 1.f - 2.f / (__expf(2.f * Gg) + 1.f);
          float oo = 1.f / (1.f + __expf(-Go));
          float cnew = ff * ch[mt][r] + ii * gg;
          ch[mt][r] = cnew;
          float hnew = oo * (1.f - 2.f / (__expf(2.f * cnew) + 1.f));
          hww[(size_t)b * HLD + j] = (f16)hnew;
          if (outf32) outf32[prow * 800 + dir * HID + j] = hnew;
          else        outf16[prow * 800 + dir * HID + j] = (f16)hnew;
          bool lastv = dir ? (s == T_STEPS - 1)
                           : (s == T_STEPS - 1 || bsT[s + 1] <= b);
          if (lastv) {
            cp[(size_t)b * HID + j] = cnew;
            hp[(size_t)b * HID + j] = hnew;
          }
        }
      }
    }

    if (s == T_STEPS - 1) break;
    if (!dir && bsT[s + 1] <= bt * 128) break;  // forward tile exhausted
    __syncthreads();  // all h writes drained (vmcnt0) before arrive
    if (tid == 0)
      __hip_atomic_fetch_add(gc + (size_t)s * 32, 1u, __ATOMIC_RELEASE,
                             __HIP_MEMORY_SCOPE_AGENT);
  }
}

// ---------------- fallback per-step kernel (updated xproj layout) ----------------
__global__ __launch_bounds__(256) void k_step(
    const f16* __restrict__ xp, const f16* __restrict__ whh,
    const float* __restrict__ bias2, const f16* __restrict__ h16r0,
    f16* __restrict__ h16w0, float* __restrict__ hn, float* __restrict__ cn,
    f16* __restrict__ outf16, float* __restrict__ outf32,
    int bs_f, int off_f, int bs_b, int off_b, int nTf) {
  const int slice = blockIdx.x % 25;
  const int tl = blockIdx.x / 25;
  int dir, bt, bs, off;
  if (tl < nTf) { dir = 0; bt = tl; bs = bs_f; off = off_f; }
  else          { dir = 1; bt = tl - nTf; bs = bs_b; off = off_b; }
  const int lane = threadIdx.x & 63, w = threadIdx.x >> 6;
  const int lr = lane & 15, kreg = (lane >> 4) * 8;
  const int b0 = bt * 128;
  const int j0 = slice * 16;
  const f16* hr = h16r0 + (size_t)dir * (2 * 1024 * HLD);
  f16* hw = h16w0 + (size_t)dir * (2 * 1024 * HLD);
  const f16* W = whh + (size_t)dir * (G4 * HLD);
  const float* bi = bias2 + dir * G4;
  float* hp = hn + (size_t)dir * (1024 * HID);
  float* cp = cn + (size_t)dir * (1024 * HID);

  f32x4 acc[2][4] = {};
  for (int k0 = 0; k0 < HLD; k0 += 32) {
    f16x8 af0 = *(const f16x8*)&hr[(b0 + (w * 2 + 0) * 16 + lr) * HLD + k0 + kreg];
    f16x8 af1 = *(const f16x8*)&hr[(b0 + (w * 2 + 1) * 16 + lr) * HLD + k0 + kreg];
#pragma unroll
    for (int g = 0; g < 4; ++g) {
      f16x8 bf = *(const f16x8*)&W[(g * HID + j0 + lr) * HLD + k0 + kreg];
      acc[0][g] = __builtin_amdgcn_mfma_f32_16x16x32_f16(af0, bf, acc[0][g], 0, 0, 0);
      acc[1][g] = __builtin_amdgcn_mfma_f32_16x16x32_f16(af1, bf, acc[1][g], 0, 0, 0);
    }
  }
  const int j = j0 + lr;
#pragma unroll
  for (int mt = 0; mt < 2; ++mt) {
#pragma unroll
    for (int r = 0; r < 4; ++r) {
      int b = b0 + (w * 2 + mt) * 16 + (lane >> 4) * 4 + r;
      if (b < bs) {
        size_t prow = (size_t)(off + b);
        const f16* xr = xp + prow * XPLD + dir * G4 + slice * 64 + lr;
        float Gi = acc[mt][0][r] + (float)xr[0]  + bi[j];
        float Gf = acc[mt][1][r] + (float)xr[16] + bi[HID + j];
        float Gg = acc[mt][2][r] + (float)xr[32] + bi[2 * HID + j];
        float Go = acc[mt][3][r] + (float)xr[48] + bi[3 * HID + j];
        float ii = 1.f / (1.f + __expf(-Gi));
        float ff = 1.f / (1.f + __expf(-Gf));
        float gg = 1.f - 2.f / (__expf(2.f * Gg) + 1.f);
        float oo = 1.f / (1.f + __expf(-Go));
        float co = cp[b * HID + j];
        float cnew = ff * co + ii * gg;
        float hnew = oo * (1.f - 2.f / (__expf(2.f * cnew) + 1.f));
        cp[b * HID + j] = cnew;
        hp[b * HID + j] = hnew;
        hw[b * HLD + j] = (f16)hnew;
        if (outf32) outf32[prow * 800 + dir * HID + j] = hnew;
        else        outf16[prow * 800 + dir * HID + j] = (f16)hnew;
      }
    }
  }
}

// ---------------- host ----------------
extern "C" void kernel_launch(void* const* d_in, const int* in_sizes, int n_in,
                              void* d_out, int out_size, void* d_ws, size_t ws_size,
                              hipStream_t stream) {
  (void)in_sizes; (void)n_in; (void)out_size; (void)ws_size;
  const float* x   = (const float*)d_in[0];
  const float* Wih = (const float*)d_in[1];
  const float* Whh = (const float*)d_in[2];
  const float* bih = (const float*)d_in[3];
  const float* bhh = (const float*)d_in[4];
  float* out = (float*)d_out;

  // step table (host copy, for fallback path)
  long long bsv[128];
  {
    double step = (1.0 - 1024.0) / 127.0;
    for (int i = 0; i < 128; ++i) bsv[i] = (long long)floor((double)i * step + 1024.0);
    bsv[127] = 1; bsv[0] = 1024;
    long long sum = 0;
    for (int i = 0; i < 128; ++i) sum += bsv[i];
    long long diff = 65536 - sum;
    while (diff != 0) {
      if (diff > 0) {
        for (int jj = 1; jj < 128 && diff != 0; ++jj) {
          long long cap = bsv[jj - 1] - bsv[jj];
          long long add = cap < diff ? cap : diff;
          bsv[jj] += add; diff -= add;
        }
      } else {
        for (int jj = 127; jj >= 1 && diff != 0; --jj) {
          long long nxt = (jj + 1 < 128) ? bsv[jj + 1] : 1;
          long long room = bsv[jj] - nxt;
          long long sub = room < (-diff) ? room : (-diff);
          bsv[jj] -= sub; diff += sub;
        }
      }
    }
  }
  long long offv[128], a0 = 0;
  for (int i = 0; i < 128; ++i) { offv[i] = a0; a0 += bsv[i]; }

  // workspace layout (unchanged footprint, ~709.2 MB)
  char* p = (char*)d_ws;
  f16*      x16   = (f16*)(p);                 // 65536x400 f16 (+256B zero pad)
  f16*      wih16 = (f16*)(p + 52429056LL);    // 6x1600x800 f16
  f16*      whh16 = (f16*)(p + 67789056LL);    // 6x1600x416 f16 (zero-padded K)
  float*    bias  = (float*)(p + 75776256LL);  // 6x1600 f32
  f16*      xproj = (f16*)(p + 75814656LL);    // (65536+128)x3200 f16
  unsigned* cnt   = (unsigned*)(p + 495654656LL);  // barrier counters, inside xproj pad rows
  f16*      layA  = (f16*)(p + 496064256LL);   // 65536x800 f16
  f16*      layB  = (f16*)(p + 600921856LL);   // 65536x800 f16
  f16*      h16   = (f16*)(p + 705779456LL);   // 2 dir x 2 pp x 1024x416 f16

  hipMemsetAsync(p + 52428800LL, 0, 256, stream);              // x16 K-pad
  hipMemsetAsync(out + 52428800LL, 0, 4915200LL * 4, stream);  // h_n + c_n

  k_cvt_f16<<<2048, 256, 0, stream>>>(x, x16, 26214400LL);
  k_cvt_f16<<<2048, 256, 0, stream>>>(Wih, wih16, 7680000LL);
  k_cvt_whh<<<2048, 256, 0, stream>>>(Whh, whh16, 9600);
  k_bias<<<40, 256, 0, stream>>>(bih, bhh, bias, 9600);

  int occ = 0;
  hipOccupancyMaxActiveBlocksPerMultiprocessor(&occ, k_rnn, 256, 0);
  const bool persistent = (occ >= 2);  // 2/CU x 256 CU = 512 >= 400 co-resident

  const long long OUTP = 52428800LL, HNSZ = 2457600LL;

  for (int L = 0; L < 3; ++L) {
    const f16* Ain = (L == 0) ? x16 : (L == 1 ? layA : layB);
    int lda = (L == 0) ? 400 : 800;
    int K   = (L == 0) ? 416 : 800;
    k_gemm<<<12800, 256, 0, stream>>>(Ain, wih16 + (size_t)(2 * L) * 1600 * 800,
                                      xproj, lda, K);
    hipMemsetAsync(h16, 0, 3407872LL, stream);
    float* hnL = out + OUTP + (size_t)(2 * L) * 409600;
    float* cnL = out + OUTP + HNSZ + (size_t)(2 * L) * 409600;
    f16* o16 = (L == 0) ? layA : (L == 1 ? layB : nullptr);
    float* o32 = (L == 2) ? out : nullptr;
    if (persistent) {
      hipMemsetAsync(cnt, 0, 262144, stream);
      k_rnn<<<RNN_BLOCKS, 256, 0, stream>>>(
          xproj, whh16 + (size_t)(2 * L) * 1600 * HLD, bias + (size_t)(2 * L) * 1600,
          h16, hnL, cnL, o16, o32, cnt);
    } else {
      for (int s = 0; s < 128; ++s) {
        int tf = s, tb = 127 - s;
        int bsf = (int)bsv[tf], bsb = (int)bsv[tb];
        int nTf = (bsf + 127) / 128, nTb = (bsb + 127) / 128;
        k_step<<<25 * (nTf + nTb), 256, 0, stream>>>(
            xproj, whh16 + (size_t)(2 * L) * 1600 * HLD, bias + (size_t)(2 * L) * 1600,
            h16 + (size_t)(s & 1) * 1024 * HLD, h16 + (size_t)((s + 1) & 1) * 1024 * HLD,
            hnL, cnL, o16, o32,
            bsf, (int)offv[tf], bsb, (int)offv[tb], nTf);
      }
    }
  }
}

// Round 4
// 8066.728 us; speedup vs baseline: 1.0425x; 1.0021x over previous
//
#include <hip/hip_runtime.h>
#include <math.h>

using f16 = _Float16;
typedef __attribute__((ext_vector_type(8))) _Float16 f16x8;
typedef __attribute__((ext_vector_type(4))) _Float16 f16x4;
typedef __attribute__((ext_vector_type(4))) float f32x4;

#define T_STEPS 128
#define HID 400
#define G4 1600
#define XPLD 3200
#define HLD 416
#define WPAD 424
#define RNN_BLOCKS 400

__device__ __forceinline__ void gl_lds16(const void* g, void* l) {
  __builtin_amdgcn_global_load_lds((const __attribute__((address_space(1))) void*)g,
                                   (__attribute__((address_space(3))) void*)l, 16, 0, 0);
}

// cross-XCD-coherent ops: bypass L1+L2, hit the L3 coherence point
__device__ __forceinline__ f16x8 ld_cc(const f16* p) {
  f16x8 r;
  asm volatile("global_load_dwordx4 %0, %1, off sc0 sc1" : "=v"(r) : "v"(p));
  return r;  // NOTE: caller must s_waitcnt vmcnt(0) + sched_barrier before use
}
__device__ __forceinline__ void st_cc2(f16* p, unsigned v) {
  asm volatile("global_store_short %0, %1, off sc0 sc1" :: "v"(p), "v"(v) : "memory");
}
__device__ __forceinline__ void st_cc4(unsigned* p, unsigned v) {
  asm volatile("global_store_dword %0, %1, off sc0 sc1" :: "v"(p), "v"(v) : "memory");
}
__device__ __forceinline__ unsigned ld_cc4(const unsigned* p) {
  unsigned v;
  asm volatile("global_load_dword %0, %1, off sc0 sc1\n\ts_waitcnt vmcnt(0)"
               : "=v"(v) : "v"(p) : "memory");
  return v;
}

// ---------------- conversion kernels ----------------
__global__ void k_cvt_f16(const float* __restrict__ s, f16* __restrict__ d, long long n) {
  long long i = ((long long)blockIdx.x * blockDim.x + threadIdx.x) * 4;
  long long stride = (long long)gridDim.x * blockDim.x * 4;
  for (; i < n; i += stride) {
    float4 v = *(const float4*)(s + i);
    f16x4 o = { (f16)v.x, (f16)v.y, (f16)v.z, (f16)v.w };
    *(f16x4*)(d + i) = o;
  }
}

__global__ void k_cvt_whh(const float* __restrict__ s, f16* __restrict__ d, int nrows) {
  long long n = (long long)nrows * HLD;
  for (long long i = (long long)blockIdx.x * blockDim.x + threadIdx.x; i < n;
       i += (long long)gridDim.x * blockDim.x) {
    int row = (int)(i / HLD), c = (int)(i % HLD);
    d[i] = (c < HID) ? (f16)s[(long long)row * HID + c] : (f16)0.f;
  }
}

__global__ void k_bias(const float* __restrict__ a, const float* __restrict__ b,
                       float* __restrict__ d, int n) {
  for (int i = blockIdx.x * blockDim.x + threadIdx.x; i < n; i += gridDim.x * blockDim.x)
    d[i] = a[i] + b[i];
}

// ---------------- input-projection GEMM ----------------
__global__ __launch_bounds__(256) void k_gemm(const f16* __restrict__ A,
                                              const f16* __restrict__ Bw,
                                              f16* __restrict__ C, int lda, int K) {
  __shared__ f16 As[128 * 32];
  __shared__ f16 Bs[128 * 32];
  const int tid = threadIdx.x;
  const int lane = tid & 63, w = tid >> 6;
  const int wm = w >> 1, wn = w & 1;
  const int wg = blockIdx.x;
  const int swz = (wg & 7) * 1600 + (wg >> 3);
  const int bn = (swz % 25) * 128;
  const long long bm = (long long)(swz / 25) * 128;

  const f16* gA = A + (bm + w * 16 + (lane >> 2)) * (long long)lda + (lane & 3) * 8;
  const f16* gB = Bw + (long long)(bn + w * 16 + (lane >> 2)) * 800 + (lane & 3) * 8;
  f16* lA = As + w * 16 * 32;
  f16* lB = Bs + w * 16 * 32;

  const int lr = lane & 15;
  const int kreg = (lane >> 4) * 8;

  f32x4 acc[4][4] = {};

  for (int k0 = 0; k0 < K; k0 += 32) {
    __syncthreads();
    gl_lds16(gA + k0, lA);
    gl_lds16(gA + 64LL * lda + k0, lA + 64 * 32);
    gl_lds16(gB + k0, lB);
    gl_lds16(gB + 64LL * 800 + k0, lB + 64 * 32);
    __syncthreads();
    f16x8 af[4], bf[4];
#pragma unroll
    for (int mt = 0; mt < 4; ++mt)
      af[mt] = *(const f16x8*)&As[(wm * 64 + mt * 16 + lr) * 32 + kreg];
#pragma unroll
    for (int nt = 0; nt < 4; ++nt)
      bf[nt] = *(const f16x8*)&Bs[(wn * 64 + nt * 16 + lr) * 32 + kreg];
#pragma unroll
    for (int mt = 0; mt < 4; ++mt)
#pragma unroll
      for (int nt = 0; nt < 4; ++nt)
        acc[mt][nt] = __builtin_amdgcn_mfma_f32_16x16x32_f16(af[mt], bf[nt], acc[mt][nt], 0, 0, 0);
  }
#pragma unroll
  for (int mt = 0; mt < 4; ++mt) {
#pragma unroll
    for (int nt = 0; nt < 4; ++nt) {
      long long gm = bm + wm * 64 + mt * 16 + ((lane >> 4) * 4);
      int n = bn + wn * 64 + nt * 16 + lr;
      int dirn = (n >= G4) ? 1 : 0;
      int rem = n - dirn * G4;
      int g = rem / HID;
      int jj = rem - g * HID;
      int np = dirn * G4 + ((jj >> 4) << 6) + (g << 4) + (jj & 15);
#pragma unroll
      for (int r = 0; r < 4; ++r)
        C[(gm + r) * XPLD + np] = (f16)acc[mt][nt][r];
    }
  }
}

// ---------------- persistent recurrence ----------------
// 400 blocks = 25 slices x 16 groups (dir x bt). W slice in LDS; c in registers.
// Cross-block h exchange + per-block monotonic flag lines via sc0|sc1 (L3-coherent)
// -> no L2 writeback/invalidate on the step critical path.
__global__ __launch_bounds__(256, 2) void k_rnn(
    const f16* __restrict__ xp, const f16* __restrict__ whh,
    const float* __restrict__ bias2, f16* __restrict__ h16,
    float* __restrict__ hn, float* __restrict__ cn,
    f16* __restrict__ outf16, float* __restrict__ outf32,
    unsigned* __restrict__ flags) {
  __shared__ f16 Wl[64 * WPAD];
  __shared__ int bsT[T_STEPS], offT[T_STEPS];

  const int tid = threadIdx.x;
  const int slice = blockIdx.x % 25;
  const int q = blockIdx.x / 25;  // 0..15 : dir*8 + bt
  const int dir = q >> 3, bt = q & 7;
  const int lane = tid & 63, w = tid >> 6;
  const int lr = lane & 15, kreg = (lane >> 4) * 8;
  const int qr4 = (lane >> 4) * 4;
  const int j0 = slice * 16;
  const int j = j0 + lr;
  unsigned* gflag = flags + (size_t)q * (25 * 32);  // group's 25 flag lines (128B each)
  unsigned* myflag = gflag + slice * 32;
  const unsigned* peer = gflag + (lane < 25 ? lane : 0) * 32;

  if (tid == 0) {
    double step = (1.0 - 1024.0) / 127.0;
    for (int i = 0; i < T_STEPS; ++i) bsT[i] = (int)floor((double)i * step + 1024.0);
    bsT[127] = 1; bsT[0] = 1024;
    int sum = 0;
    for (int i = 0; i < T_STEPS; ++i) sum += bsT[i];
    int diff = 65536 - sum;
    while (diff != 0) {
      if (diff > 0) {
        for (int jj = 1; jj < T_STEPS && diff != 0; ++jj) {
          int cap = bsT[jj - 1] - bsT[jj];
          int add = cap < diff ? cap : diff;
          bsT[jj] += add; diff -= add;
        }
      } else {
        for (int jj = T_STEPS - 1; jj >= 1 && diff != 0; --jj) {
          int nxt = (jj + 1 < T_STEPS) ? bsT[jj + 1] : 1;
          int room = bsT[jj] - nxt;
          int sub = room < (-diff) ? room : (-diff);
          bsT[jj] -= sub; diff += sub;
        }
      }
    }
    int a0 = 0;
    for (int i = 0; i < T_STEPS; ++i) { offT[i] = a0; a0 += bsT[i]; }
  }

  // W slice -> LDS (64 rows = 4 gates x 16 j; 416 cols padded to 424)
  const f16* whhD = whh + (size_t)dir * (G4 * HLD);
  {
    int rr = tid >> 2, seg = tid & 3;
    int g = rr >> 4, jr = rr & 15;
    const f16* src = whhD + (size_t)(g * HID + j0 + jr) * HLD + seg * 104;
    f16* dst = &Wl[rr * WPAD + seg * 104];
#pragma unroll
    for (int kk = 0; kk < 13; ++kk)
      *(f16x8*)(dst + kk * 8) = *(const f16x8*)(src + kk * 8);
  }
  const float* biD = bias2 + dir * G4;
  const float bi0 = biD[j], bi1 = biD[HID + j], bi2 = biD[2 * HID + j], bi3 = biD[3 * HID + j];
  float* hp = hn + (size_t)dir * (1024 * HID);
  float* cp = cn + (size_t)dir * (1024 * HID);
  __syncthreads();

  int s_begin = 0;
  if (dir) {  // backward: batch tile inactive until bs grows past it (h rows still 0)
    while (s_begin < T_STEPS && bsT[T_STEPS - 1 - s_begin] <= bt * 128) ++s_begin;
  }
  const int rowb = bt * 128 + w * 32;
  float ch[2][4] = {{0.f, 0.f, 0.f, 0.f}, {0.f, 0.f, 0.f, 0.f}};

#pragma unroll 1
  for (int s = s_begin; s < T_STEPS; ++s) {
    const int t = dir ? (T_STEPS - 1 - s) : s;
    const int bs = bsT[t], off = offT[t];

    // x-gate prefetch (normal cached loads; latency hides under the flag spin)
    f16 xg[2][4][4];
#pragma unroll
    for (int mt = 0; mt < 2; ++mt)
#pragma unroll
      for (int r = 0; r < 4; ++r) {
        const f16* xr = xp + (size_t)(off + rowb + mt * 16 + qr4 + r) * XPLD
                        + dir * G4 + slice * 64 + lr;
#pragma unroll
        for (int g = 0; g < 4; ++g) xg[mt][r][g] = xr[g * 16];
      }

    // wait: all 25 peer blocks completed step s-1 (parallel flag-line poll)
    if (s > s_begin) {
      if (w == 0) {
        while (true) {
          unsigned v = ld_cc4(peer);
          if (!__ballot((lane < 25) && (v < (unsigned)s))) break;
          __builtin_amdgcn_s_sleep(1);
        }
      }
      __syncthreads();
    }

    const int cur = s & 1;
    const f16* hr = h16 + (size_t)((dir << 1) | cur) * (1024 * HLD);
    f16* hww = h16 + (size_t)((dir << 1) | (cur ^ 1)) * (1024 * HLD);

    // issue all h loads (L3-coherent), single drain, then MFMA from LDS W
    const f16* ha = hr + (size_t)(rowb + lr) * HLD + kreg;
    f16x8 hfa[13], hfb[13];
#pragma unroll
    for (int kk = 0; kk < 13; ++kk) {
      hfa[kk] = ld_cc(ha + kk * 32);
      hfb[kk] = ld_cc(ha + 16 * HLD + kk * 32);
    }
    asm volatile("s_waitcnt vmcnt(0)" ::: "memory");
    __builtin_amdgcn_sched_barrier(0);

    f32x4 acc[2][4] = {};
#pragma unroll
    for (int kk = 0; kk < 13; ++kk) {
#pragma unroll
      for (int g = 0; g < 4; ++g) {
        f16x8 bf = *(const f16x8*)&Wl[(g * 16 + lr) * WPAD + kk * 32 + kreg];
        acc[0][g] = __builtin_amdgcn_mfma_f32_16x16x32_f16(hfa[kk], bf, acc[0][g], 0, 0, 0);
        acc[1][g] = __builtin_amdgcn_mfma_f32_16x16x32_f16(hfb[kk], bf, acc[1][g], 0, 0, 0);
      }
    }
#pragma unroll
    for (int mt = 0; mt < 2; ++mt) {
#pragma unroll
      for (int r = 0; r < 4; ++r) {
        int b = rowb + mt * 16 + qr4 + r;
        if (b < bs) {
          size_t prow = (size_t)(off + b);
          float Gi = acc[mt][0][r] + (float)xg[mt][r][0] + bi0;
          float Gf = acc[mt][1][r] + (float)xg[mt][r][1] + bi1;
          float Gg = acc[mt][2][r] + (float)xg[mt][r][2] + bi2;
          float Go = acc[mt][3][r] + (float)xg[mt][r][3] + bi3;
          float ii = 1.f / (1.f + __expf(-Gi));
          float ff = 1.f / (1.f + __expf(-Gf));
          float gg = 1.f - 2.f / (__expf(2.f * Gg) + 1.f);
          float oo = 1.f / (1.f + __expf(-Go));
          float cnew = ff * ch[mt][r] + ii * gg;
          ch[mt][r] = cnew;
          float hnew = oo * (1.f - 2.f / (__expf(2.f * cnew) + 1.f));
          union { f16 f; unsigned short u; } cv; cv.f = (f16)hnew;
          st_cc2(&hww[(size_t)b * HLD + j], (unsigned)cv.u);
          if (outf32) outf32[prow * 800 + dir * HID + j] = hnew;
          else        outf16[prow * 800 + dir * HID + j] = (f16)hnew;
          bool lastv = dir ? (s == T_STEPS - 1)
                           : (s == T_STEPS - 1 || bsT[s + 1] <= b);
          if (lastv) {
            cp[(size_t)b * HID + j] = cnew;
            hp[(size_t)b * HID + j] = hnew;
          }
        }
      }
    }

    if (s == T_STEPS - 1) break;
    if (!dir && bsT[s + 1] <= bt * 128) break;  // forward tile exhausted (group-uniform)
    asm volatile("s_waitcnt vmcnt(0)" ::: "memory");  // h stores ACKed at L3
    __syncthreads();                                   // all waves drained
    if (tid == 0) st_cc4(myflag, (unsigned)(s + 1));   // publish AFTER h visible
  }
}

// ---------------- fallback per-step kernel ----------------
__global__ __launch_bounds__(256) void k_step(
    const f16* __restrict__ xp, const f16* __restrict__ whh,
    const float* __restrict__ bias2, const f16* __restrict__ h16r0,
    f16* __restrict__ h16w0, float* __restrict__ hn, float* __restrict__ cn,
    f16* __restrict__ outf16, float* __restrict__ outf32,
    int bs_f, int off_f, int bs_b, int off_b, int nTf) {
  const int slice = blockIdx.x % 25;
  const int tl = blockIdx.x / 25;
  int dir, bt, bs, off;
  if (tl < nTf) { dir = 0; bt = tl; bs = bs_f; off = off_f; }
  else          { dir = 1; bt = tl - nTf; bs = bs_b; off = off_b; }
  const int lane = threadIdx.x & 63, w = threadIdx.x >> 6;
  const int lr = lane & 15, kreg = (lane >> 4) * 8;
  const int b0 = bt * 128;
  const int j0 = slice * 16;
  const f16* hr = h16r0 + (size_t)dir * (2 * 1024 * HLD);
  f16* hw = h16w0 + (size_t)dir * (2 * 1024 * HLD);
  const f16* W = whh + (size_t)dir * (G4 * HLD);
  const float* bi = bias2 + dir * G4;
  float* hp = hn + (size_t)dir * (1024 * HID);
  float* cp = cn + (size_t)dir * (1024 * HID);

  f32x4 acc[2][4] = {};
  for (int k0 = 0; k0 < HLD; k0 += 32) {
    f16x8 af0 = *(const f16x8*)&hr[(b0 + (w * 2 + 0) * 16 + lr) * HLD + k0 + kreg];
    f16x8 af1 = *(const f16x8*)&hr[(b0 + (w * 2 + 1) * 16 + lr) * HLD + k0 + kreg];
#pragma unroll
    for (int g = 0; g < 4; ++g) {
      f16x8 bf = *(const f16x8*)&W[(g * HID + j0 + lr) * HLD + k0 + kreg];
      acc[0][g] = __builtin_amdgcn_mfma_f32_16x16x32_f16(af0, bf, acc[0][g], 0, 0, 0);
      acc[1][g] = __builtin_amdgcn_mfma_f32_16x16x32_f16(af1, bf, acc[1][g], 0, 0, 0);
    }
  }
  const int j = j0 + lr;
#pragma unroll
  for (int mt = 0; mt < 2; ++mt) {
#pragma unroll
    for (int r = 0; r < 4; ++r) {
      int b = b0 + (w * 2 + mt) * 16 + (lane >> 4) * 4 + r;
      if (b < bs) {
        size_t prow = (size_t)(off + b);
        const f16* xr = xp + prow * XPLD + dir * G4 + slice * 64 + lr;
        float Gi = acc[mt][0][r] + (float)xr[0]  + bi[j];
        float Gf = acc[mt][1][r] + (float)xr[16] + bi[HID + j];
        float Gg = acc[mt][2][r] + (float)xr[32] + bi[2 * HID + j];
        float Go = acc[mt][3][r] + (float)xr[48] + bi[3 * HID + j];
        float ii = 1.f / (1.f + __expf(-Gi));
        float ff = 1.f / (1.f + __expf(-Gf));
        float gg = 1.f - 2.f / (__expf(2.f * Gg) + 1.f);
        float oo = 1.f / (1.f + __expf(-Go));
        float co = cp[b * HID + j];
        float cnew = ff * co + ii * gg;
        float hnew = oo * (1.f - 2.f / (__expf(2.f * cnew) + 1.f));
        cp[b * HID + j] = cnew;
        hp[b * HID + j] = hnew;
        hw[b * HLD + j] = (f16)hnew;
        if (outf32) outf32[prow * 800 + dir * HID + j] = hnew;
        else        outf16[prow * 800 + dir * HID + j] = (f16)hnew;
      }
    }
  }
}

// ---------------- host ----------------
extern "C" void kernel_launch(void* const* d_in, const int* in_sizes, int n_in,
                              void* d_out, int out_size, void* d_ws, size_t ws_size,
                              hipStream_t stream) {
  (void)in_sizes; (void)n_in; (void)out_size; (void)ws_size;
  const float* x   = (const float*)d_in[0];
  const float* Wih = (const float*)d_in[1];
  const float* Whh = (const float*)d_in[2];
  const float* bih = (const float*)d_in[3];
  const float* bhh = (const float*)d_in[4];
  float* out = (float*)d_out;

  long long bsv[128];
  {
    double step = (1.0 - 1024.0) / 127.0;
    for (int i = 0; i < 128; ++i) bsv[i] = (long long)floor((double)i * step + 1024.0);
    bsv[127] = 1; bsv[0] = 1024;
    long long sum = 0;
    for (int i = 0; i < 128; ++i) sum += bsv[i];
    long long diff = 65536 - sum;
    while (diff != 0) {
      if (diff > 0) {
        for (int jj = 1; jj < 128 && diff != 0; ++jj) {
          long long cap = bsv[jj - 1] - bsv[jj];
          long long add = cap < diff ? cap : diff;
          bsv[jj] += add; diff -= add;
        }
      } else {
        for (int jj = 127; jj >= 1 && diff != 0; --jj) {
          long long nxt = (jj + 1 < 128) ? bsv[jj + 1] : 1;
          long long room = bsv[jj] - nxt;
          long long sub = room < (-diff) ? room : (-diff);
          bsv[jj] -= sub; diff += sub;
        }
      }
    }
  }
  long long offv[128], a0 = 0;
  for (int i = 0; i < 128; ++i) { offv[i] = a0; a0 += bsv[i]; }

  char* p = (char*)d_ws;
  f16*      x16   = (f16*)(p);                 // 65536x400 f16 (+256B zero pad)
  f16*      wih16 = (f16*)(p + 52429056LL);    // 6x1600x800 f16
  f16*      whh16 = (f16*)(p + 67789056LL);    // 6x1600x416 f16 (zero-padded K)
  float*    bias  = (float*)(p + 75776256LL);  // 6x1600 f32
  f16*      xproj = (f16*)(p + 75814656LL);    // (65536+128)x3200 f16
  unsigned* flags = (unsigned*)(p + 495654656LL);  // 3 layers x 16 groups x 25 x 128B
  f16*      layA  = (f16*)(p + 496064256LL);   // 65536x800 f16
  f16*      layB  = (f16*)(p + 600921856LL);   // 65536x800 f16
  f16*      h16   = (f16*)(p + 705779456LL);   // 2 dir x 2 pp x 1024x416 f16

  hipMemsetAsync(p + 52428800LL, 0, 256, stream);              // x16 K-pad
  hipMemsetAsync(out + 52428800LL, 0, 4915200LL * 4, stream);  // h_n + c_n
  hipMemsetAsync(flags, 0, 3 * 16 * 25 * 128, stream);         // all layer flags

  k_cvt_f16<<<2048, 256, 0, stream>>>(x, x16, 26214400LL);
  k_cvt_f16<<<2048, 256, 0, stream>>>(Wih, wih16, 7680000LL);
  k_cvt_whh<<<2048, 256, 0, stream>>>(Whh, whh16, 9600);
  k_bias<<<40, 256, 0, stream>>>(bih, bhh, bias, 9600);

  int occ = 0;
  hipOccupancyMaxActiveBlocksPerMultiprocessor(&occ, k_rnn, 256, 0);
  const bool persistent = (occ >= 2);  // 2/CU x 256 CU = 512 >= 400 co-resident

  const long long OUTP = 52428800LL, HNSZ = 2457600LL;

  for (int L = 0; L < 3; ++L) {
    const f16* Ain = (L == 0) ? x16 : (L == 1 ? layA : layB);
    int lda = (L == 0) ? 400 : 800;
    int K   = (L == 0) ? 416 : 800;
    k_gemm<<<12800, 256, 0, stream>>>(Ain, wih16 + (size_t)(2 * L) * 1600 * 800,
                                      xproj, lda, K);
    hipMemsetAsync(h16, 0, 3407872LL, stream);
    float* hnL = out + OUTP + (size_t)(2 * L) * 409600;
    float* cnL = out + OUTP + HNSZ + (size_t)(2 * L) * 409600;
    f16* o16 = (L == 0) ? layA : (L == 1 ? layB : nullptr);
    float* o32 = (L == 2) ? out : nullptr;
    if (persistent) {
      k_rnn<<<RNN_BLOCKS, 256, 0, stream>>>(
          xproj, whh16 + (size_t)(2 * L) * 1600 * HLD, bias + (size_t)(2 * L) * 1600,
          h16, hnL, cnL, o16, o32, flags + (size_t)L * 16 * 25 * 32);
    } else {
      for (int s = 0; s < 128; ++s) {
        int tf = s, tb = 127 - s;
        int bsf = (int)bsv[tf], bsb = (int)bsv[tb];
        int nTf = (bsf + 127) / 128, nTb = (bsb + 127) / 128;
        k_step<<<25 * (nTf + nTb), 256, 0, stream>>>(
            xproj, whh16 + (size_t)(2 * L) * 1600 * HLD, bias + (size_t)(2 * L) * 1600,
            h16 + (size_t)(s & 1) * 1024 * HLD, h16 + (size_t)((s + 1) & 1) * 1024 * HLD,
            hnL, cnL, o16, o32,
            bsf, (int)offv[tf], bsb, (int)offv[tb], nTf);
      }
    }
  }
}

// Round 5
// 8057.184 us; speedup vs baseline: 1.0437x; 1.0012x over previous
//
#include <hip/hip_runtime.h>
#include <math.h>

using f16 = _Float16;
typedef __attribute__((ext_vector_type(8))) _Float16 f16x8;
typedef __attribute__((ext_vector_type(4))) _Float16 f16x4;
typedef __attribute__((ext_vector_type(4))) float f32x4;

#define T_STEPS 128
#define HID 400
#define G4 1600
#define XPLD 3200
#define HLD 416
#define WPAD 424
#define RNN_BLOCKS 400

__device__ __forceinline__ void gl_lds16(const void* g, void* l) {
  __builtin_amdgcn_global_load_lds((const __attribute__((address_space(1))) void*)g,
                                   (__attribute__((address_space(3))) void*)l, 16, 0, 0);
}

// cross-XCD-coherent ops: bypass L1+L2, hit the L3 coherence point
__device__ __forceinline__ f16x8 ld_cc(const f16* p) {
  f16x8 r;
  asm volatile("global_load_dwordx4 %0, %1, off sc0 sc1" : "=v"(r) : "v"(p));
  return r;  // caller must s_waitcnt vmcnt(0) + sched_barrier before use
}
__device__ __forceinline__ void st_cc2(f16* p, unsigned v) {
  asm volatile("global_store_short %0, %1, off sc0 sc1" :: "v"(p), "v"(v) : "memory");
}
__device__ __forceinline__ void st_cc4(unsigned* p, unsigned v) {
  asm volatile("global_store_dword %0, %1, off sc0 sc1" :: "v"(p), "v"(v) : "memory");
}
__device__ __forceinline__ unsigned ld_cc4(const unsigned* p) {
  unsigned v;
  asm volatile("global_load_dword %0, %1, off sc0 sc1\n\ts_waitcnt vmcnt(0)"
               : "=v"(v) : "v"(p) : "memory");
  return v;
}

// ---------------- conversion kernels ----------------
__global__ void k_cvt_f16(const float* __restrict__ s, f16* __restrict__ d, long long n) {
  long long i = ((long long)blockIdx.x * blockDim.x + threadIdx.x) * 4;
  long long stride = (long long)gridDim.x * blockDim.x * 4;
  for (; i < n; i += stride) {
    float4 v = *(const float4*)(s + i);
    f16x4 o = { (f16)v.x, (f16)v.y, (f16)v.z, (f16)v.w };
    *(f16x4*)(d + i) = o;
  }
}

__global__ void k_cvt_whh(const float* __restrict__ s, f16* __restrict__ d, int nrows) {
  long long n = (long long)nrows * HLD;
  for (long long i = (long long)blockIdx.x * blockDim.x + threadIdx.x; i < n;
       i += (long long)gridDim.x * blockDim.x) {
    int row = (int)(i / HLD), c = (int)(i % HLD);
    d[i] = (c < HID) ? (f16)s[(long long)row * HID + c] : (f16)0.f;
  }
}

__global__ void k_bias(const float* __restrict__ a, const float* __restrict__ b,
                       float* __restrict__ d, int n) {
  for (int i = blockIdx.x * blockDim.x + threadIdx.x; i < n; i += gridDim.x * blockDim.x)
    d[i] = a[i] + b[i];
}

// ---------------- input-projection GEMM (double-buffered staging) ----------------
// C[m][np] = sum_k A[m][k]*Bw[n][k]; 128x128 tile, BK=32.
// Pipeline: STAGE(next) -> compute(cur) -> __syncthreads (implicit vmcnt0 drains
// next-tile gl_lds AFTER compute; one barrier per K-iter).
// Output col permute: n = dir*1600+g*400+j -> np = dir*1600 + (j/16)*64 + (j%16)*4 + g
// so rnn's per-thread 4-gate read is one contiguous f16x4.
__global__ __launch_bounds__(256) void k_gemm(const f16* __restrict__ A,
                                              const f16* __restrict__ Bw,
                                              f16* __restrict__ C, int lda, int K) {
  __shared__ f16 As[2][128 * 32];
  __shared__ f16 Bs[2][128 * 32];
  const int tid = threadIdx.x;
  const int lane = tid & 63, w = tid >> 6;
  const int wm = w >> 1, wn = w & 1;
  const int wg = blockIdx.x;
  const int swz = (wg & 7) * 1600 + (wg >> 3);  // bijective XCD swizzle (12800%8==0)
  const int bn = (swz % 25) * 128;
  const long long bm = (long long)(swz / 25) * 128;

  const f16* gA = A + (bm + w * 16 + (lane >> 2)) * (long long)lda + (lane & 3) * 8;
  const f16* gB = Bw + (long long)(bn + w * 16 + (lane >> 2)) * 800 + (lane & 3) * 8;

  const int lr = lane & 15;
  const int kreg = (lane >> 4) * 8;
  const int nk = K / 32;

  f32x4 acc[4][4] = {};

#define STAGE(b, k0)                                        \
  do {                                                      \
    gl_lds16(gA + (k0), &As[b][w * 512]);                   \
    gl_lds16(gA + 64LL * lda + (k0), &As[b][64 * 32 + w * 512]); \
    gl_lds16(gB + (k0), &Bs[b][w * 512]);                   \
    gl_lds16(gB + 64LL * 800 + (k0), &Bs[b][64 * 32 + w * 512]); \
  } while (0)

  STAGE(0, 0);
  __syncthreads();
  int cur = 0;
  for (int kt = 0; kt < nk; ++kt) {
    if (kt + 1 < nk) STAGE(cur ^ 1, (kt + 1) * 32);
    f16x8 af[4], bf[4];
#pragma unroll
    for (int mt = 0; mt < 4; ++mt)
      af[mt] = *(const f16x8*)&As[cur][(wm * 64 + mt * 16 + lr) * 32 + kreg];
#pragma unroll
    for (int nt = 0; nt < 4; ++nt)
      bf[nt] = *(const f16x8*)&Bs[cur][(wn * 64 + nt * 16 + lr) * 32 + kreg];
#pragma unroll
    for (int mt = 0; mt < 4; ++mt)
#pragma unroll
      for (int nt = 0; nt < 4; ++nt)
        acc[mt][nt] = __builtin_amdgcn_mfma_f32_16x16x32_f16(af[mt], bf[nt], acc[mt][nt], 0, 0, 0);
    __syncthreads();  // drains next-tile gl_lds; protects cur^1 overwrite
    cur ^= 1;
  }
#undef STAGE

#pragma unroll
  for (int mt = 0; mt < 4; ++mt) {
#pragma unroll
    for (int nt = 0; nt < 4; ++nt) {
      long long gm = bm + wm * 64 + mt * 16 + ((lane >> 4) * 4);
      int n = bn + wn * 64 + nt * 16 + lr;
      int dirn = (n >= G4) ? 1 : 0;
      int rem = n - dirn * G4;
      int g = rem / HID;
      int jj = rem - g * HID;
      int np = dirn * G4 + ((jj >> 4) << 6) + ((jj & 15) << 2) + g;
#pragma unroll
      for (int r = 0; r < 4; ++r)
        C[(gm + r) * XPLD + np] = (f16)acc[mt][nt][r];
    }
  }
}

// ---------------- persistent recurrence ----------------
// 400 blocks = 25 slices x 16 groups (dir x bt). W slice in LDS; c in registers.
// L3-coherent (sc0 sc1) h exchange + per-block flag lines; out/h_n/c_n writes
// deferred past the flag publish so only h-stores sit on the critical path.
__global__ __launch_bounds__(256, 2) void k_rnn(
    const f16* __restrict__ xp, const f16* __restrict__ whh,
    const float* __restrict__ bias2, f16* __restrict__ h16,
    float* __restrict__ hn, float* __restrict__ cn,
    f16* __restrict__ outf16, float* __restrict__ outf32,
    unsigned* __restrict__ flags) {
  __shared__ f16 Wl[64 * WPAD];
  __shared__ int bsT[T_STEPS], offT[T_STEPS];

  const int tid = threadIdx.x;
  const int slice = blockIdx.x % 25;
  const int q = blockIdx.x / 25;  // 0..15 : dir*8 + bt
  const int dir = q >> 3, bt = q & 7;
  const int lane = tid & 63, w = tid >> 6;
  const int lr = lane & 15, kreg = (lane >> 4) * 8;
  const int qr4 = (lane >> 4) * 4;
  const int j0 = slice * 16;
  const int j = j0 + lr;
  unsigned* gflag = flags + (size_t)q * (25 * 32);
  unsigned* myflag = gflag + slice * 32;
  const unsigned* peer = gflag + (lane < 25 ? lane : 0) * 32;

  if (tid == 0) {
    double step = (1.0 - 1024.0) / 127.0;
    for (int i = 0; i < T_STEPS; ++i) bsT[i] = (int)floor((double)i * step + 1024.0);
    bsT[127] = 1; bsT[0] = 1024;
    int sum = 0;
    for (int i = 0; i < T_STEPS; ++i) sum += bsT[i];
    int diff = 65536 - sum;
    while (diff != 0) {
      if (diff > 0) {
        for (int jj = 1; jj < T_STEPS && diff != 0; ++jj) {
          int cap = bsT[jj - 1] - bsT[jj];
          int add = cap < diff ? cap : diff;
          bsT[jj] += add; diff -= add;
        }
      } else {
        for (int jj = T_STEPS - 1; jj >= 1 && diff != 0; --jj) {
          int nxt = (jj + 1 < T_STEPS) ? bsT[jj + 1] : 1;
          int room = bsT[jj] - nxt;
          int sub = room < (-diff) ? room : (-diff);
          bsT[jj] -= sub; diff += sub;
        }
      }
    }
    int a0 = 0;
    for (int i = 0; i < T_STEPS; ++i) { offT[i] = a0; a0 += bsT[i]; }
  }

  // W slice -> LDS (64 rows = 4 gates x 16 j; 416 cols padded to 424)
  const f16* whhD = whh + (size_t)dir * (G4 * HLD);
  {
    int rr = tid >> 2, seg = tid & 3;
    int g = rr >> 4, jr = rr & 15;
    const f16* src = whhD + (size_t)(g * HID + j0 + jr) * HLD + seg * 104;
    f16* dst = &Wl[rr * WPAD + seg * 104];
#pragma unroll
    for (int kk = 0; kk < 13; ++kk)
      *(f16x8*)(dst + kk * 8) = *(const f16x8*)(src + kk * 8);
  }
  const float* biD = bias2 + dir * G4;
  const float bi0 = biD[j], bi1 = biD[HID + j], bi2 = biD[2 * HID + j], bi3 = biD[3 * HID + j];
  float* hp = hn + (size_t)dir * (1024 * HID);
  float* cp = cn + (size_t)dir * (1024 * HID);
  __syncthreads();

  int s_begin = 0;
  if (dir) {  // backward: tile inactive until bs grows past it (h rows still 0)
    while (s_begin < T_STEPS && bsT[T_STEPS - 1 - s_begin] <= bt * 128) ++s_begin;
  }
  const int rowb = bt * 128 + w * 32;
  float ch[2][4] = {{0.f, 0.f, 0.f, 0.f}, {0.f, 0.f, 0.f, 0.f}};

#pragma unroll 1
  for (int s = s_begin; s < T_STEPS; ++s) {
    const int t = dir ? (T_STEPS - 1 - s) : s;
    const int bs = bsT[t], off = offT[t];

    // x-gate prefetch: one f16x4 per (mt,r) — gates contiguous in new layout
    f16x4 xg[2][4];
#pragma unroll
    for (int mt = 0; mt < 2; ++mt)
#pragma unroll
      for (int r = 0; r < 4; ++r)
        xg[mt][r] = *(const f16x4*)(xp + (size_t)(off + rowb + mt * 16 + qr4 + r) * XPLD
                                    + dir * G4 + slice * 64 + lr * 4);

    // wait: all 25 peer blocks completed step s-1
    if (s > s_begin) {
      if (w == 0) {
        while (true) {
          unsigned v = ld_cc4(peer);
          if (!__ballot((lane < 25) && (v < (unsigned)s))) break;
          __builtin_amdgcn_s_sleep(1);
        }
      }
      __syncthreads();
    }

    const int cur = s & 1;
    const f16* hr = h16 + (size_t)((dir << 1) | cur) * (1024 * HLD);
    f16* hww = h16 + (size_t)((dir << 1) | (cur ^ 1)) * (1024 * HLD);

    const f16* ha = hr + (size_t)(rowb + lr) * HLD + kreg;
    f16x8 hfa[13], hfb[13];
#pragma unroll
    for (int kk = 0; kk < 13; ++kk) {
      hfa[kk] = ld_cc(ha + kk * 32);
      hfb[kk] = ld_cc(ha + 16 * HLD + kk * 32);
    }
    asm volatile("s_waitcnt vmcnt(0)" ::: "memory");
    __builtin_amdgcn_sched_barrier(0);

    f32x4 acc[2][4] = {};
#pragma unroll
    for (int kk = 0; kk < 13; ++kk) {
#pragma unroll
      for (int g = 0; g < 4; ++g) {
        f16x8 bf = *(const f16x8*)&Wl[(g * 16 + lr) * WPAD + kk * 32 + kreg];
        acc[0][g] = __builtin_amdgcn_mfma_f32_16x16x32_f16(hfa[kk], bf, acc[0][g], 0, 0, 0);
        acc[1][g] = __builtin_amdgcn_mfma_f32_16x16x32_f16(hfb[kk], bf, acc[1][g], 0, 0, 0);
      }
    }

    float hnw[2][4];
    f16 hv16[2][4];
#pragma unroll
    for (int mt = 0; mt < 2; ++mt) {
#pragma unroll
      for (int r = 0; r < 4; ++r) {
        int b = rowb + mt * 16 + qr4 + r;
        if (b < bs) {
          float Gi = acc[mt][0][r] + (float)xg[mt][r][0] + bi0;
          float Gf = acc[mt][1][r] + (float)xg[mt][r][1] + bi1;
          float Gg = acc[mt][2][r] + (float)xg[mt][r][2] + bi2;
          float Go = acc[mt][3][r] + (float)xg[mt][r][3] + bi3;
          float ii = 1.f / (1.f + __expf(-Gi));
          float ff = 1.f / (1.f + __expf(-Gf));
          float gg = 1.f - 2.f / (__expf(2.f * Gg) + 1.f);
          float oo = 1.f / (1.f + __expf(-Go));
          float cnew = ff * ch[mt][r] + ii * gg;
          ch[mt][r] = cnew;
          float hnew = oo * (1.f - 2.f / (__expf(2.f * cnew) + 1.f));
          union { f16 f; unsigned short u; } cv; cv.f = (f16)hnew;
          st_cc2(&hww[(size_t)b * HLD + j], (unsigned)cv.u);
          hnw[mt][r] = hnew;
          hv16[mt][r] = cv.f;
        }
      }
    }

    const bool lastStep = (s == T_STEPS - 1) || (!dir && bsT[s + 1] <= bt * 128);
    if (!lastStep) {
      __syncthreads();                                 // implicit vmcnt(0): h ACKed at L3
      if (tid == 0) st_cc4(myflag, (unsigned)(s + 1)); // publish AFTER h visible
    }

    // deferred outputs (overlap next step's prefetch/spin)
#pragma unroll
    for (int mt = 0; mt < 2; ++mt) {
#pragma unroll
      for (int r = 0; r < 4; ++r) {
        int b = rowb + mt * 16 + qr4 + r;
        if (b < bs) {
          size_t prow = (size_t)(off + b);
          if (outf32) outf32[prow * 800 + dir * HID + j] = hnw[mt][r];
          else        outf16[prow * 800 + dir * HID + j] = hv16[mt][r];
          bool lastv = dir ? (s == T_STEPS - 1)
                           : (s == T_STEPS - 1 || bsT[s + 1] <= b);
          if (lastv) {
            cp[(size_t)b * HID + j] = ch[mt][r];
            hp[(size_t)b * HID + j] = hnw[mt][r];
          }
        }
      }
    }
    if (lastStep) break;
  }
}

// ---------------- fallback per-step kernel (matches new xproj layout) ----------------
__global__ __launch_bounds__(256) void k_step(
    const f16* __restrict__ xp, const f16* __restrict__ whh,
    const float* __restrict__ bias2, const f16* __restrict__ h16r0,
    f16* __restrict__ h16w0, float* __restrict__ hn, float* __restrict__ cn,
    f16* __restrict__ outf16, float* __restrict__ outf32,
    int bs_f, int off_f, int bs_b, int off_b, int nTf) {
  const int slice = blockIdx.x % 25;
  const int tl = blockIdx.x / 25;
  int dir, bt, bs, off;
  if (tl < nTf) { dir = 0; bt = tl; bs = bs_f; off = off_f; }
  else          { dir = 1; bt = tl - nTf; bs = bs_b; off = off_b; }
  const int lane = threadIdx.x & 63, w = threadIdx.x >> 6;
  const int lr = lane & 15, kreg = (lane >> 4) * 8;
  const int b0 = bt * 128;
  const int j0 = slice * 16;
  const f16* hr = h16r0 + (size_t)dir * (2 * 1024 * HLD);
  f16* hw = h16w0 + (size_t)dir * (2 * 1024 * HLD);
  const f16* W = whh + (size_t)dir * (G4 * HLD);
  const float* bi = bias2 + dir * G4;
  float* hp = hn + (size_t)dir * (1024 * HID);
  float* cp = cn + (size_t)dir * (1024 * HID);

  f32x4 acc[2][4] = {};
  for (int k0 = 0; k0 < HLD; k0 += 32) {
    f16x8 af0 = *(const f16x8*)&hr[(b0 + (w * 2 + 0) * 16 + lr) * HLD + k0 + kreg];
    f16x8 af1 = *(const f16x8*)&hr[(b0 + (w * 2 + 1) * 16 + lr) * HLD + k0 + kreg];
#pragma unroll
    for (int g = 0; g < 4; ++g) {
      f16x8 bf = *(const f16x8*)&W[(g * HID + j0 + lr) * HLD + k0 + kreg];
      acc[0][g] = __builtin_amdgcn_mfma_f32_16x16x32_f16(af0, bf, acc[0][g], 0, 0, 0);
      acc[1][g] = __builtin_amdgcn_mfma_f32_16x16x32_f16(af1, bf, acc[1][g], 0, 0, 0);
    }
  }
  const int j = j0 + lr;
#pragma unroll
  for (int mt = 0; mt < 2; ++mt) {
#pragma unroll
    for (int r = 0; r < 4; ++r) {
      int b = b0 + (w * 2 + mt) * 16 + (lane >> 4) * 4 + r;
      if (b < bs) {
        size_t prow = (size_t)(off + b);
        const f16* xr = xp + prow * XPLD + dir * G4 + slice * 64 + lr * 4;
        float Gi = acc[mt][0][r] + (float)xr[0] + bi[j];
        float Gf = acc[mt][1][r] + (float)xr[1] + bi[HID + j];
        float Gg = acc[mt][2][r] + (float)xr[2] + bi[2 * HID + j];
        float Go = acc[mt][3][r] + (float)xr[3] + bi[3 * HID + j];
        float ii = 1.f / (1.f + __expf(-Gi));
        float ff = 1.f / (1.f + __expf(-Gf));
        float gg = 1.f - 2.f / (__expf(2.f * Gg) + 1.f);
        float oo = 1.f / (1.f + __expf(-Go));
        float co = cp[b * HID + j];
        float cnew = ff * co + ii * gg;
        float hnew = oo * (1.f - 2.f / (__expf(2.f * cnew) + 1.f));
        cp[b * HID + j] = cnew;
        hp[b * HID + j] = hnew;
        hw[b * HLD + j] = (f16)hnew;
        if (outf32) outf32[prow * 800 + dir * HID + j] = hnew;
        else        outf16[prow * 800 + dir * HID + j] = (f16)hnew;
      }
    }
  }
}

// ---------------- host ----------------
extern "C" void kernel_launch(void* const* d_in, const int* in_sizes, int n_in,
                              void* d_out, int out_size, void* d_ws, size_t ws_size,
                              hipStream_t stream) {
  (void)in_sizes; (void)n_in; (void)out_size; (void)ws_size;
  const float* x   = (const float*)d_in[0];
  const float* Wih = (const float*)d_in[1];
  const float* Whh = (const float*)d_in[2];
  const float* bih = (const float*)d_in[3];
  const float* bhh = (const float*)d_in[4];
  float* out = (float*)d_out;

  long long bsv[128];
  {
    double step = (1.0 - 1024.0) / 127.0;
    for (int i = 0; i < 128; ++i) bsv[i] = (long long)floor((double)i * step + 1024.0);
    bsv[127] = 1; bsv[0] = 1024;
    long long sum = 0;
    for (int i = 0; i < 128; ++i) sum += bsv[i];
    long long diff = 65536 - sum;
    while (diff != 0) {
      if (diff > 0) {
        for (int jj = 1; jj < 128 && diff != 0; ++jj) {
          long long cap = bsv[jj - 1] - bsv[jj];
          long long add = cap < diff ? cap : diff;
          bsv[jj] += add; diff -= add;
        }
      } else {
        for (int jj = 127; jj >= 1 && diff != 0; --jj) {
          long long nxt = (jj + 1 < 128) ? bsv[jj + 1] : 1;
          long long room = bsv[jj] - nxt;
          long long sub = room < (-diff) ? room : (-diff);
          bsv[jj] -= sub; diff += sub;
        }
      }
    }
  }
  long long offv[128], a0 = 0;
  for (int i = 0; i < 128; ++i) { offv[i] = a0; a0 += bsv[i]; }

  char* p = (char*)d_ws;
  f16*      x16   = (f16*)(p);                 // 65536x400 f16 (+256B zero pad)
  f16*      wih16 = (f16*)(p + 52429056LL);    // 6x1600x800 f16
  f16*      whh16 = (f16*)(p + 67789056LL);    // 6x1600x416 f16 (zero-padded K)
  float*    bias  = (float*)(p + 75776256LL);  // 6x1600 f32
  f16*      xproj = (f16*)(p + 75814656LL);    // (65536+128)x3200 f16
  unsigned* flags = (unsigned*)(p + 495654656LL);  // 3 layers x 16 groups x 25 x 128B
  f16*      layA  = (f16*)(p + 496064256LL);   // 65536x800 f16
  f16*      layB  = (f16*)(p + 600921856LL);   // 65536x800 f16
  f16*      h16   = (f16*)(p + 705779456LL);   // 2 dir x 2 pp x 1024x416 f16

  hipMemsetAsync(p + 52428800LL, 0, 256, stream);              // x16 K-pad
  hipMemsetAsync(out + 52428800LL, 0, 4915200LL * 4, stream);  // h_n + c_n
  hipMemsetAsync(flags, 0, 3 * 16 * 25 * 128, stream);         // all layer flags

  k_cvt_f16<<<2048, 256, 0, stream>>>(x, x16, 26214400LL);
  k_cvt_f16<<<2048, 256, 0, stream>>>(Wih, wih16, 7680000LL);
  k_cvt_whh<<<2048, 256, 0, stream>>>(Whh, whh16, 9600);
  k_bias<<<40, 256, 0, stream>>>(bih, bhh, bias, 9600);

  int occ = 0;
  hipOccupancyMaxActiveBlocksPerMultiprocessor(&occ, k_rnn, 256, 0);
  const bool persistent = (occ >= 2);  // 2/CU x 256 CU = 512 >= 400 co-resident

  const long long OUTP = 52428800LL, HNSZ = 2457600LL;

  for (int L = 0; L < 3; ++L) {
    const f16* Ain = (L == 0) ? x16 : (L == 1 ? layA : layB);
    int lda = (L == 0) ? 400 : 800;
    int K   = (L == 0) ? 416 : 800;
    k_gemm<<<12800, 256, 0, stream>>>(Ain, wih16 + (size_t)(2 * L) * 1600 * 800,
                                      xproj, lda, K);
    hipMemsetAsync(h16, 0, 3407872LL, stream);
    float* hnL = out + OUTP + (size_t)(2 * L) * 409600;
    float* cnL = out + OUTP + HNSZ + (size_t)(2 * L) * 409600;
    f16* o16 = (L == 0) ? layA : (L == 1 ? layB : nullptr);
    float* o32 = (L == 2) ? out : nullptr;
    if (persistent) {
      k_rnn<<<RNN_BLOCKS, 256, 0, stream>>>(
          xproj, whh16 + (size_t)(2 * L) * 1600 * HLD, bias + (size_t)(2 * L) * 1600,
          h16, hnL, cnL, o16, o32, flags + (size_t)L * 16 * 25 * 32);
    } else {
      for (int s = 0; s < 128; ++s) {
        int tf = s, tb = 127 - s;
        int bsf = (int)bsv[tf], bsb = (int)bsv[tb];
        int nTf = (bsf + 127) / 128, nTb = (bsb + 127) / 128;
        k_step<<<25 * (nTf + nTb), 256, 0, stream>>>(
            xproj, whh16 + (size_t)(2 * L) * 1600 * HLD, bias + (size_t)(2 * L) * 1600,
            h16 + (size_t)(s & 1) * 1024 * HLD, h16 + (size_t)((s + 1) & 1) * 1024 * HLD,
            hnL, cnL, o16, o32,
            bsf, (int)offv[tf], bsb, (int)offv[tb], nTf);
      }
    }
  }
}

// Round 6
// 8045.625 us; speedup vs baseline: 1.0452x; 1.0014x over previous
//
#include <hip/hip_runtime.h>
#include <math.h>

using f16 = _Float16;
typedef __attribute__((ext_vector_type(8))) _Float16 f16x8;
typedef __attribute__((ext_vector_type(4))) _Float16 f16x4;
typedef __attribute__((ext_vector_type(4))) float f32x4;

#define T_STEPS 128
#define HID 400
#define G4 1600
#define XPLD 3200
#define HLD 416
#define WPAD 424
#define RNN_BLOCKS 200

__device__ __forceinline__ void gl_lds16(const void* g, void* l) {
  __builtin_amdgcn_global_load_lds((const __attribute__((address_space(1))) void*)g,
                                   (__attribute__((address_space(3))) void*)l, 16, 0, 0);
}

// cross-XCD-coherent ops: bypass L1+L2, hit the L3 coherence point
__device__ __forceinline__ f16x8 ld_cc(const f16* p) {
  f16x8 r;
  asm volatile("global_load_dwordx4 %0, %1, off sc0 sc1" : "=v"(r) : "v"(p));
  return r;  // caller must s_waitcnt vmcnt(0) + sched_barrier before use
}
__device__ __forceinline__ void st_cc2(f16* p, unsigned v) {
  asm volatile("global_store_short %0, %1, off sc0 sc1" :: "v"(p), "v"(v) : "memory");
}
__device__ __forceinline__ void st_cc4(unsigned* p, unsigned v) {
  asm volatile("global_store_dword %0, %1, off sc0 sc1" :: "v"(p), "v"(v) : "memory");
}
__device__ __forceinline__ unsigned ld_cc4(const unsigned* p) {
  unsigned v;
  asm volatile("global_load_dword %0, %1, off sc0 sc1\n\ts_waitcnt vmcnt(0)"
               : "=v"(v) : "v"(p) : "memory");
  return v;
}

// ---------------- conversion kernels ----------------
__global__ void k_cvt_f16(const float* __restrict__ s, f16* __restrict__ d, long long n) {
  long long i = ((long long)blockIdx.x * blockDim.x + threadIdx.x) * 4;
  long long stride = (long long)gridDim.x * blockDim.x * 4;
  for (; i < n; i += stride) {
    float4 v = *(const float4*)(s + i);
    f16x4 o = { (f16)v.x, (f16)v.y, (f16)v.z, (f16)v.w };
    *(f16x4*)(d + i) = o;
  }
}

__global__ void k_cvt_whh(const float* __restrict__ s, f16* __restrict__ d, int nrows) {
  long long n = (long long)nrows * HLD;
  for (long long i = (long long)blockIdx.x * blockDim.x + threadIdx.x; i < n;
       i += (long long)gridDim.x * blockDim.x) {
    int row = (int)(i / HLD), c = (int)(i % HLD);
    d[i] = (c < HID) ? (f16)s[(long long)row * HID + c] : (f16)0.f;
  }
}

__global__ void k_bias(const float* __restrict__ a, const float* __restrict__ b,
                       float* __restrict__ d, int n) {
  for (int i = blockIdx.x * blockDim.x + threadIdx.x; i < n; i += gridDim.x * blockDim.x)
    d[i] = a[i] + b[i];
}

// ---------------- input-projection GEMM (256x128 tile, 8 waves, 2-buf) ----------------
// C[m][np] = sum_k A[m][k]*Bw[n][k]; BK=32.
// Output col permute: n = dir*1600+g*400+j -> np = dir*1600 + (j/16)*64 + (j%16)*4 + g
__global__ __launch_bounds__(512) void k_gemm(const f16* __restrict__ A,
                                              const f16* __restrict__ Bw,
                                              f16* __restrict__ C, int lda, int K) {
  __shared__ f16 As[2][256 * 32];
  __shared__ f16 Bs[2][128 * 32];
  const int tid = threadIdx.x;
  const int lane = tid & 63, v = tid >> 6;  // 8 waves
  const int wm = v >> 1, wn = v & 1;        // 4 x 2 wave grid (64x64 each)
  const int wg = blockIdx.x;
  const int swz = (wg & 7) * 800 + (wg >> 3);  // bijective XCD swizzle (6400%8==0)
  const int bn = (swz % 25) * 128;
  const long long bm = (long long)(swz / 25) * 256;

  // staging: A = 1024 16B-segs (2/thread), B = 512 segs (1/thread); dest linear per wave
  const int sA0 = v * 64 + lane, sA1 = 512 + v * 64 + lane;
  const f16* gA0 = A + (bm + (sA0 >> 2)) * (long long)lda + (sA0 & 3) * 8;
  const f16* gA1 = A + (bm + (sA1 >> 2)) * (long long)lda + (sA1 & 3) * 8;
  const f16* gB0 = Bw + (long long)(bn + (sA0 >> 2)) * 800 + (sA0 & 3) * 8;

  const int lr = lane & 15;
  const int kreg = (lane >> 4) * 8;
  const int qr4 = (lane >> 4) * 4;
  const int nk = K / 32;

  f32x4 acc[4][4] = {};

#define STAGE(bb, k0)                                   \
  do {                                                  \
    gl_lds16(gA0 + (k0), &As[bb][v * 512]);             \
    gl_lds16(gA1 + (k0), &As[bb][4096 + v * 512]);      \
    gl_lds16(gB0 + (k0), &Bs[bb][v * 512]);             \
  } while (0)

  STAGE(0, 0);
  __syncthreads();
  int cur = 0;
  for (int kt = 0; kt < nk; ++kt) {
    if (kt + 1 < nk) STAGE(cur ^ 1, (kt + 1) * 32);
    f16x8 af[4], bf[4];
#pragma unroll
    for (int mt = 0; mt < 4; ++mt)
      af[mt] = *(const f16x8*)&As[cur][(wm * 64 + mt * 16 + lr) * 32 + kreg];
#pragma unroll
    for (int nt = 0; nt < 4; ++nt)
      bf[nt] = *(const f16x8*)&Bs[cur][(wn * 64 + nt * 16 + lr) * 32 + kreg];
#pragma unroll
    for (int mt = 0; mt < 4; ++mt)
#pragma unroll
      for (int nt = 0; nt < 4; ++nt)
        acc[mt][nt] = __builtin_amdgcn_mfma_f32_16x16x32_f16(af[mt], bf[nt], acc[mt][nt], 0, 0, 0);
    __syncthreads();  // drains next-tile gl_lds; protects buffer overwrite
    cur ^= 1;
  }
#undef STAGE

#pragma unroll
  for (int mt = 0; mt < 4; ++mt) {
#pragma unroll
    for (int nt = 0; nt < 4; ++nt) {
      long long gm = bm + wm * 64 + mt * 16 + qr4;
      int n = bn + wn * 64 + nt * 16 + lr;
      int dirn = (n >= G4) ? 1 : 0;
      int rem = n - dirn * G4;
      int g = rem / HID;
      int jj = rem - g * HID;
      int np = dirn * G4 + ((jj >> 4) << 6) + ((jj & 15) << 2) + g;
#pragma unroll
      for (int r = 0; r < 4; ++r)
        C[(gm + r) * XPLD + np] = (f16)acc[mt][nt][r];
    }
  }
}

// ---------------- persistent recurrence (200 blocks, 1 block/CU) ----------------
// 200 blocks = 25 slices x 8 groups (2 dir x 4 bt of 256 rows). W slice in LDS;
// c in registers; h fragments for 4 m-tiles held in VGPRs (one vmcnt drain).
// L3-coherent (sc0 sc1) h exchange + per-block flag lines.
__global__ __launch_bounds__(256, 1) void k_rnn(
    const f16* __restrict__ xp, const f16* __restrict__ whh,
    const float* __restrict__ bias2, f16* __restrict__ h16,
    float* __restrict__ hn, float* __restrict__ cn,
    f16* __restrict__ outf16, float* __restrict__ outf32,
    unsigned* __restrict__ flags) {
  __shared__ f16 Wl[64 * WPAD];
  __shared__ int bsT[T_STEPS], offT[T_STEPS];

  const int tid = threadIdx.x;
  const int slice = blockIdx.x % 25;
  const int q = blockIdx.x / 25;  // 0..7 : dir*4 + bt
  const int dir = q >> 2, bt = q & 3;
  const int lane = tid & 63, w = tid >> 6;
  const int lr = lane & 15, kreg = (lane >> 4) * 8;
  const int qr4 = (lane >> 4) * 4;
  const int j0 = slice * 16;
  const int j = j0 + lr;
  unsigned* gflag = flags + (size_t)q * (25 * 32);
  unsigned* myflag = gflag + slice * 32;
  const unsigned* peer = gflag + (lane < 25 ? lane : 0) * 32;

  if (tid == 0) {
    double step = (1.0 - 1024.0) / 127.0;
    for (int i = 0; i < T_STEPS; ++i) bsT[i] = (int)floor((double)i * step + 1024.0);
    bsT[127] = 1; bsT[0] = 1024;
    int sum = 0;
    for (int i = 0; i < T_STEPS; ++i) sum += bsT[i];
    int diff = 65536 - sum;
    while (diff != 0) {
      if (diff > 0) {
        for (int jj = 1; jj < T_STEPS && diff != 0; ++jj) {
          int cap = bsT[jj - 1] - bsT[jj];
          int add = cap < diff ? cap : diff;
          bsT[jj] += add; diff -= add;
        }
      } else {
        for (int jj = T_STEPS - 1; jj >= 1 && diff != 0; --jj) {
          int nxt = (jj + 1 < T_STEPS) ? bsT[jj + 1] : 1;
          int room = bsT[jj] - nxt;
          int sub = room < (-diff) ? room : (-diff);
          bsT[jj] -= sub; diff += sub;
        }
      }
    }
    int a0 = 0;
    for (int i = 0; i < T_STEPS; ++i) { offT[i] = a0; a0 += bsT[i]; }
  }

  // W slice -> LDS (64 rows = 4 gates x 16 j; 416 cols padded to 424)
  const f16* whhD = whh + (size_t)dir * (G4 * HLD);
  {
    int rr = tid >> 2, seg = tid & 3;
    int g = rr >> 4, jr = rr & 15;
    const f16* src = whhD + (size_t)(g * HID + j0 + jr) * HLD + seg * 104;
    f16* dst = &Wl[rr * WPAD + seg * 104];
#pragma unroll
    for (int kk = 0; kk < 13; ++kk)
      *(f16x8*)(dst + kk * 8) = *(const f16x8*)(src + kk * 8);
  }
  const float* biD = bias2 + dir * G4;
  const float bi0 = biD[j], bi1 = biD[HID + j], bi2 = biD[2 * HID + j], bi3 = biD[3 * HID + j];
  float* hp = hn + (size_t)dir * (1024 * HID);
  float* cp = cn + (size_t)dir * (1024 * HID);
  __syncthreads();

  int s_begin = 0;
  if (dir) {  // backward: tile inactive until bs grows past it (h rows still 0)
    while (s_begin < T_STEPS && bsT[T_STEPS - 1 - s_begin] <= bt * 256) ++s_begin;
  }
  const int rw = bt * 256 + w * 64;  // wave's 64-row span (4 m-tiles of 16)
  float ch[4][4] = {};

#pragma unroll 1
  for (int s = s_begin; s < T_STEPS; ++s) {
    const int t = dir ? (T_STEPS - 1 - s) : s;
    const int bs = bsT[t], off = offT[t];

    // x-gate prefetch: one f16x4 per (mt,r)
    f16x4 xg[4][4];
#pragma unroll
    for (int mt = 0; mt < 4; ++mt)
#pragma unroll
      for (int r = 0; r < 4; ++r)
        xg[mt][r] = *(const f16x4*)(xp + (size_t)(off + rw + mt * 16 + qr4 + r) * XPLD
                                    + dir * G4 + slice * 64 + lr * 4);

    // wait: all 25 peer blocks completed step s-1
    if (s > s_begin) {
      if (w == 0) {
        while (true) {
          unsigned vv = ld_cc4(peer);
          if (!__ballot((lane < 25) && (vv < (unsigned)s))) break;
          __builtin_amdgcn_s_sleep(1);
        }
      }
      __syncthreads();
    }

    const int cur = s & 1;
    const f16* hr = h16 + (size_t)((dir << 1) | cur) * (1024 * HLD);
    f16* hww = h16 + (size_t)((dir << 1) | (cur ^ 1)) * (1024 * HLD);

    // issue all h loads (L3-coherent), single drain, then MFMA from LDS W
    f16x8 hf[4][13];
#pragma unroll
    for (int mt = 0; mt < 4; ++mt) {
      const f16* ha = hr + (size_t)(rw + mt * 16 + lr) * HLD + kreg;
#pragma unroll
      for (int kk = 0; kk < 13; ++kk)
        hf[mt][kk] = ld_cc(ha + kk * 32);
    }
    asm volatile("s_waitcnt vmcnt(0)" ::: "memory");
    __builtin_amdgcn_sched_barrier(0);

    f32x4 acc[4][4] = {};
#pragma unroll
    for (int kk = 0; kk < 13; ++kk) {
#pragma unroll
      for (int g = 0; g < 4; ++g) {
        f16x8 bf = *(const f16x8*)&Wl[(g * 16 + lr) * WPAD + kk * 32 + kreg];
#pragma unroll
        for (int mt = 0; mt < 4; ++mt)
          acc[mt][g] = __builtin_amdgcn_mfma_f32_16x16x32_f16(hf[mt][kk], bf, acc[mt][g], 0, 0, 0);
      }
    }

    float hnw[4][4];
    f16 hv16[4][4];
#pragma unroll
    for (int mt = 0; mt < 4; ++mt) {
#pragma unroll
      for (int r = 0; r < 4; ++r) {
        int b = rw + mt * 16 + qr4 + r;
        if (b < bs) {
          float Gi = acc[mt][0][r] + (float)xg[mt][r][0] + bi0;
          float Gf = acc[mt][1][r] + (float)xg[mt][r][1] + bi1;
          float Gg = acc[mt][2][r] + (float)xg[mt][r][2] + bi2;
          float Go = acc[mt][3][r] + (float)xg[mt][r][3] + bi3;
          float ii = 1.f / (1.f + __expf(-Gi));
          float ff = 1.f / (1.f + __expf(-Gf));
          float gg = 1.f - 2.f / (__expf(2.f * Gg) + 1.f);
          float oo = 1.f / (1.f + __expf(-Go));
          float cnew = ff * ch[mt][r] + ii * gg;
          ch[mt][r] = cnew;
          float hnew = oo * (1.f - 2.f / (__expf(2.f * cnew) + 1.f));
          union { f16 f; unsigned short u; } cv; cv.f = (f16)hnew;
          st_cc2(&hww[(size_t)b * HLD + j], (unsigned)cv.u);
          hnw[mt][r] = hnew;
          hv16[mt][r] = cv.f;
        }
      }
    }

    const bool lastStep = (s == T_STEPS - 1) || (!dir && bsT[s + 1] <= bt * 256);
    if (!lastStep) {
      __syncthreads();                                 // implicit vmcnt(0): h ACKed at L3
      if (tid == 0) st_cc4(myflag, (unsigned)(s + 1)); // publish AFTER h visible
    }

    // deferred outputs (overlap next step's prefetch/spin)
#pragma unroll
    for (int mt = 0; mt < 4; ++mt) {
#pragma unroll
      for (int r = 0; r < 4; ++r) {
        int b = rw + mt * 16 + qr4 + r;
        if (b < bs) {
          size_t prow = (size_t)(off + b);
          if (outf32) outf32[prow * 800 + dir * HID + j] = hnw[mt][r];
          else        outf16[prow * 800 + dir * HID + j] = hv16[mt][r];
          bool lastv = dir ? (s == T_STEPS - 1)
                           : (s == T_STEPS - 1 || bsT[s + 1] <= b);
          if (lastv) {
            cp[(size_t)b * HID + j] = ch[mt][r];
            hp[(size_t)b * HID + j] = hnw[mt][r];
          }
        }
      }
    }
    if (lastStep) break;
  }
}

// ---------------- fallback per-step kernel (matches xproj gate layout) ----------------
__global__ __launch_bounds__(256) void k_step(
    const f16* __restrict__ xp, const f16* __restrict__ whh,
    const float* __restrict__ bias2, const f16* __restrict__ h16r0,
    f16* __restrict__ h16w0, float* __restrict__ hn, float* __restrict__ cn,
    f16* __restrict__ outf16, float* __restrict__ outf32,
    int bs_f, int off_f, int bs_b, int off_b, int nTf) {
  const int slice = blockIdx.x % 25;
  const int tl = blockIdx.x / 25;
  int dir, bt, bs, off;
  if (tl < nTf) { dir = 0; bt = tl; bs = bs_f; off = off_f; }
  else          { dir = 1; bt = tl - nTf; bs = bs_b; off = off_b; }
  const int lane = threadIdx.x & 63, w = threadIdx.x >> 6;
  const int lr = lane & 15, kreg = (lane >> 4) * 8;
  const int b0 = bt * 128;
  const int j0 = slice * 16;
  const f16* hr = h16r0 + (size_t)dir * (2 * 1024 * HLD);
  f16* hw = h16w0 + (size_t)dir * (2 * 1024 * HLD);
  const f16* W = whh + (size_t)dir * (G4 * HLD);
  const float* bi = bias2 + dir * G4;
  float* hp = hn + (size_t)dir * (1024 * HID);
  float* cp = cn + (size_t)dir * (1024 * HID);

  f32x4 acc[2][4] = {};
  for (int k0 = 0; k0 < HLD; k0 += 32) {
    f16x8 af0 = *(const f16x8*)&hr[(b0 + (w * 2 + 0) * 16 + lr) * HLD + k0 + kreg];
    f16x8 af1 = *(const f16x8*)&hr[(b0 + (w * 2 + 1) * 16 + lr) * HLD + k0 + kreg];
#pragma unroll
    for (int g = 0; g < 4; ++g) {
      f16x8 bf = *(const f16x8*)&W[(g * HID + j0 + lr) * HLD + k0 + kreg];
      acc[0][g] = __builtin_amdgcn_mfma_f32_16x16x32_f16(af0, bf, acc[0][g], 0, 0, 0);
      acc[1][g] = __builtin_amdgcn_mfma_f32_16x16x32_f16(af1, bf, acc[1][g], 0, 0, 0);
    }
  }
  const int j = j0 + lr;
#pragma unroll
  for (int mt = 0; mt < 2; ++mt) {
#pragma unroll
    for (int r = 0; r < 4; ++r) {
      int b = b0 + (w * 2 + mt) * 16 + (lane >> 4) * 4 + r;
      if (b < bs) {
        size_t prow = (size_t)(off + b);
        const f16* xr = xp + prow * XPLD + dir * G4 + slice * 64 + lr * 4;
        float Gi = acc[mt][0][r] + (float)xr[0] + bi[j];
        float Gf = acc[mt][1][r] + (float)xr[1] + bi[HID + j];
        float Gg = acc[mt][2][r] + (float)xr[2] + bi[2 * HID + j];
        float Go = acc[mt][3][r] + (float)xr[3] + bi[3 * HID + j];
        float ii = 1.f / (1.f + __expf(-Gi));
        float ff = 1.f / (1.f + __expf(-Gf));
        float gg = 1.f - 2.f / (__expf(2.f * Gg) + 1.f);
        float oo = 1.f / (1.f + __expf(-Go));
        float co = cp[b * HID + j];
        float cnew = ff * co + ii * gg;
        float hnew = oo * (1.f - 2.f / (__expf(2.f * cnew) + 1.f));
        cp[b * HID + j] = cnew;
        hp[b * HID + j] = hnew;
        hw[b * HLD + j] = (f16)hnew;
        if (outf32) outf32[prow * 800 + dir * HID + j] = hnew;
        else        outf16[prow * 800 + dir * HID + j] = (f16)hnew;
      }
    }
  }
}

// ---------------- host ----------------
extern "C" void kernel_launch(void* const* d_in, const int* in_sizes, int n_in,
                              void* d_out, int out_size, void* d_ws, size_t ws_size,
                              hipStream_t stream) {
  (void)in_sizes; (void)n_in; (void)out_size; (void)ws_size;
  const float* x   = (const float*)d_in[0];
  const float* Wih = (const float*)d_in[1];
  const float* Whh = (const float*)d_in[2];
  const float* bih = (const float*)d_in[3];
  const float* bhh = (const float*)d_in[4];
  float* out = (float*)d_out;

  long long bsv[128];
  {
    double step = (1.0 - 1024.0) / 127.0;
    for (int i = 0; i < 128; ++i) bsv[i] = (long long)floor((double)i * step + 1024.0);
    bsv[127] = 1; bsv[0] = 1024;
    long long sum = 0;
    for (int i = 0; i < 128; ++i) sum += bsv[i];
    long long diff = 65536 - sum;
    while (diff != 0) {
      if (diff > 0) {
        for (int jj = 1; jj < 128 && diff != 0; ++jj) {
          long long cap = bsv[jj - 1] - bsv[jj];
          long long add = cap < diff ? cap : diff;
          bsv[jj] += add; diff -= add;
        }
      } else {
        for (int jj = 127; jj >= 1 && diff != 0; --jj) {
          long long nxt = (jj + 1 < 128) ? bsv[jj + 1] : 1;
          long long room = bsv[jj] - nxt;
          long long sub = room < (-diff) ? room : (-diff);
          bsv[jj] -= sub; diff += sub;
        }
      }
    }
  }
  long long offv[128], a0 = 0;
  for (int i = 0; i < 128; ++i) { offv[i] = a0; a0 += bsv[i]; }

  char* p = (char*)d_ws;
  f16*      x16   = (f16*)(p);                 // 65536x400 f16 (+256B zero pad)
  f16*      wih16 = (f16*)(p + 52429056LL);    // 6x1600x800 f16
  f16*      whh16 = (f16*)(p + 67789056LL);    // 6x1600x416 f16 (zero-padded K)
  float*    bias  = (float*)(p + 75776256LL);  // 6x1600 f32
  f16*      xproj = (f16*)(p + 75814656LL);    // (65536+128)x3200 f16
  unsigned* flags = (unsigned*)(p + 495654656LL);  // 3 layers x 16 groups x 25 x 128B
  f16*      layA  = (f16*)(p + 496064256LL);   // 65536x800 f16
  f16*      layB  = (f16*)(p + 600921856LL);   // 65536x800 f16
  f16*      h16   = (f16*)(p + 705779456LL);   // 2 dir x 2 pp x 1024x416 f16

  hipMemsetAsync(p + 52428800LL, 0, 256, stream);              // x16 K-pad
  hipMemsetAsync(out + 52428800LL, 0, 4915200LL * 4, stream);  // h_n + c_n
  hipMemsetAsync(flags, 0, 3 * 16 * 25 * 128, stream);         // all layer flags

  k_cvt_f16<<<2048, 256, 0, stream>>>(x, x16, 26214400LL);
  k_cvt_f16<<<2048, 256, 0, stream>>>(Wih, wih16, 7680000LL);
  k_cvt_whh<<<2048, 256, 0, stream>>>(Whh, whh16, 9600);
  k_bias<<<40, 256, 0, stream>>>(bih, bhh, bias, 9600);

  int occ = 0;
  hipOccupancyMaxActiveBlocksPerMultiprocessor(&occ, k_rnn, 256, 0);
  const bool persistent = (occ >= 1 && occ * 256 >= RNN_BLOCKS);

  const long long OUTP = 52428800LL, HNSZ = 2457600LL;

  for (int L = 0; L < 3; ++L) {
    const f16* Ain = (L == 0) ? x16 : (L == 1 ? layA : layB);
    int lda = (L == 0) ? 400 : 800;
    int K   = (L == 0) ? 416 : 800;
    k_gemm<<<6400, 512, 0, stream>>>(Ain, wih16 + (size_t)(2 * L) * 1600 * 800,
                                     xproj, lda, K);
    hipMemsetAsync(h16, 0, 3407872LL, stream);
    float* hnL = out + OUTP + (size_t)(2 * L) * 409600;
    float* cnL = out + OUTP + HNSZ + (size_t)(2 * L) * 409600;
    f16* o16 = (L == 0) ? layA : (L == 1 ? layB : nullptr);
    float* o32 = (L == 2) ? out : nullptr;
    if (persistent) {
      k_rnn<<<RNN_BLOCKS, 256, 0, stream>>>(
          xproj, whh16 + (size_t)(2 * L) * 1600 * HLD, bias + (size_t)(2 * L) * 1600,
          h16, hnL, cnL, o16, o32, flags + (size_t)L * 16 * 25 * 32);
    } else {
      for (int s = 0; s < 128; ++s) {
        int tf = s, tb = 127 - s;
        int bsf = (int)bsv[tf], bsb = (int)bsv[tb];
        int nTf = (bsf + 127) / 128, nTb = (bsb + 127) / 128;
        k_step<<<25 * (nTf + nTb), 256, 0, stream>>>(
            xproj, whh16 + (size_t)(2 * L) * 1600 * HLD, bias + (size_t)(2 * L) * 1600,
            h16 + (size_t)(s & 1) * 1024 * HLD, h16 + (size_t)((s + 1) & 1) * 1024 * HLD,
            hnL, cnL, o16, o32,
            bsf, (int)offv[tf], bsb, (int)offv[tb], nTf);
      }
    }
  }
}

// Round 7
// 7947.277 us; speedup vs baseline: 1.0582x; 1.0124x over previous
//
#include <hip/hip_runtime.h>
#include <math.h>

using f16 = _Float16;
typedef __attribute__((ext_vector_type(8))) _Float16 f16x8;
typedef __attribute__((ext_vector_type(4))) _Float16 f16x4;
typedef __attribute__((ext_vector_type(4))) float f32x4;

#define T_STEPS 128
#define HID 400
#define G4 1600
#define XPLD 3200
#define HLD 416
#define WPAD 424
#define RNN_BLOCKS 400

__device__ __forceinline__ void gl_lds16(const void* g, void* l) {
  __builtin_amdgcn_global_load_lds((const __attribute__((address_space(1))) void*)g,
                                   (__attribute__((address_space(3))) void*)l, 16, 0, 0);
}

// cross-XCD-coherent ops: bypass L1+L2, hit the L3 coherence point
__device__ __forceinline__ f16x8 ld_cc(const f16* p) {
  f16x8 r;
  asm volatile("global_load_dwordx4 %0, %1, off sc0 sc1" : "=v"(r) : "v"(p));
  return r;  // caller must s_waitcnt vmcnt(0) + sched_barrier before use
}
__device__ __forceinline__ void st_cc2(f16* p, unsigned v) {
  asm volatile("global_store_short %0, %1, off sc0 sc1" :: "v"(p), "v"(v) : "memory");
}
__device__ __forceinline__ void st_cc4(unsigned* p, unsigned v) {
  asm volatile("global_store_dword %0, %1, off sc0 sc1" :: "v"(p), "v"(v) : "memory");
}
__device__ __forceinline__ unsigned ld_cc4(const unsigned* p) {
  unsigned v;
  asm volatile("global_load_dword %0, %1, off sc0 sc1\n\ts_waitcnt vmcnt(0)"
               : "=v"(v) : "v"(p) : "memory");
  return v;
}

// ---------------- conversion kernels ----------------
__global__ void k_cvt_f16(const float* __restrict__ s, f16* __restrict__ d, long long n) {
  long long i = ((long long)blockIdx.x * blockDim.x + threadIdx.x) * 4;
  long long stride = (long long)gridDim.x * blockDim.x * 4;
  for (; i < n; i += stride) {
    float4 v = *(const float4*)(s + i);
    f16x4 o = { (f16)v.x, (f16)v.y, (f16)v.z, (f16)v.w };
    *(f16x4*)(d + i) = o;
  }
}

// Wih f32 -> f16 with gate-interleave ROW permutation folded in:
// out row R = L*3200 + dirn*1600 + (j/16)*64 + (j%16)*4 + g  <-  in row (2L+dirn)*1600 + g*400 + j
// GEMM then writes xproj LINEARLY (coalesced) while the rnn still reads gate-quads.
__global__ void k_cvt_wih(const float* __restrict__ s, f16* __restrict__ d) {
  long long n4 = 9600LL * 200;  // 4 elems per iter
  for (long long i = (long long)blockIdx.x * blockDim.x + threadIdx.x; i < n4;
       i += (long long)gridDim.x * blockDim.x) {
    long long i4 = i * 4;
    int R = (int)(i4 / 800), c = (int)(i4 % 800);
    int L = R / 3200, rem = R % 3200;
    int dirn = rem / 1600, q = rem % 1600;
    int g = q & 3, jlo = (q >> 2) & 15, jhi = q >> 6;
    int inrow = (2 * L + dirn) * 1600 + g * HID + jhi * 16 + jlo;
    float4 v = *(const float4*)(s + (long long)inrow * 800 + c);
    f16x4 o = { (f16)v.x, (f16)v.y, (f16)v.z, (f16)v.w };
    *(f16x4*)(d + i4) = o;
  }
}

__global__ void k_cvt_whh(const float* __restrict__ s, f16* __restrict__ d, int nrows) {
  long long n = (long long)nrows * HLD;
  for (long long i = (long long)blockIdx.x * blockDim.x + threadIdx.x; i < n;
       i += (long long)gridDim.x * blockDim.x) {
    int row = (int)(i / HLD), c = (int)(i % HLD);
    d[i] = (c < HID) ? (f16)s[(long long)row * HID + c] : (f16)0.f;
  }
}

__global__ void k_bias(const float* __restrict__ a, const float* __restrict__ b,
                       float* __restrict__ d, int n) {
  for (int i = blockIdx.x * blockDim.x + threadIdx.x; i < n; i += gridDim.x * blockDim.x)
    d[i] = a[i] + b[i];
}

// ---------------- input-projection GEMM (plain, coalesced C, dbuf) ----------------
// C[m][n] = sum_k A[m][k]*Bw[n][k]; 128x128 tile, BK=32, gl_lds staging, 2-buf.
// B rows already permuted by k_cvt_wih, so C layout == rnn gate-quad layout.
__global__ __launch_bounds__(256) void k_gemm(const f16* __restrict__ A,
                                              const f16* __restrict__ Bw,
                                              f16* __restrict__ C, int lda, int K) {
  __shared__ f16 As[2][128 * 32];
  __shared__ f16 Bs[2][128 * 32];
  const int tid = threadIdx.x;
  const int lane = tid & 63, w = tid >> 6;
  const int wm = w >> 1, wn = w & 1;
  const int wg = blockIdx.x;
  const int swz = (wg & 7) * 1600 + (wg >> 3);  // bijective XCD swizzle (12800%8==0)
  const int bn = (swz % 25) * 128;
  const long long bm = (long long)(swz / 25) * 128;

  const f16* gA = A + (bm + w * 16 + (lane >> 2)) * (long long)lda + (lane & 3) * 8;
  const f16* gB = Bw + (long long)(bn + w * 16 + (lane >> 2)) * 800 + (lane & 3) * 8;

  const int lr = lane & 15;
  const int kreg = (lane >> 4) * 8;
  const int nk = K / 32;

  f32x4 acc[4][4] = {};

#define STAGE(bb, k0)                                            \
  do {                                                           \
    gl_lds16(gA + (k0), &As[bb][w * 512]);                       \
    gl_lds16(gA + 64LL * lda + (k0), &As[bb][64 * 32 + w * 512]); \
    gl_lds16(gB + (k0), &Bs[bb][w * 512]);                       \
    gl_lds16(gB + 64LL * 800 + (k0), &Bs[bb][64 * 32 + w * 512]); \
  } while (0)

  STAGE(0, 0);
  __syncthreads();
  int cur = 0;
  for (int kt = 0; kt < nk; ++kt) {
    if (kt + 1 < nk) STAGE(cur ^ 1, (kt + 1) * 32);
    f16x8 af[4], bf[4];
#pragma unroll
    for (int mt = 0; mt < 4; ++mt)
      af[mt] = *(const f16x8*)&As[cur][(wm * 64 + mt * 16 + lr) * 32 + kreg];
#pragma unroll
    for (int nt = 0; nt < 4; ++nt)
      bf[nt] = *(const f16x8*)&Bs[cur][(wn * 64 + nt * 16 + lr) * 32 + kreg];
#pragma unroll
    for (int mt = 0; mt < 4; ++mt)
#pragma unroll
      for (int nt = 0; nt < 4; ++nt)
        acc[mt][nt] = __builtin_amdgcn_mfma_f32_16x16x32_f16(af[mt], bf[nt], acc[mt][nt], 0, 0, 0);
    __syncthreads();  // drains next-tile gl_lds; protects buffer overwrite
    cur ^= 1;
  }
#undef STAGE

#pragma unroll
  for (int mt = 0; mt < 4; ++mt) {
#pragma unroll
    for (int nt = 0; nt < 4; ++nt) {
      long long gm = bm + wm * 64 + mt * 16 + ((lane >> 4) * 4);
      int gn = bn + wn * 64 + nt * 16 + lr;  // LINEAR: coalesced 32B per 16-lane group
#pragma unroll
      for (int r = 0; r < 4; ++r)
        C[(gm + r) * XPLD + gn] = (f16)acc[mt][nt][r];
    }
  }
}

// ---------------- persistent recurrence (400 blocks, round-5 base) ----------------
// 25 slices x 16 groups (dir x 8 bt of 128 rows). W in LDS; c in regs.
// x-prefetch: 2 steps deep, guarded by bs (skip inactive rows -> halves x HBM).
__global__ __launch_bounds__(256, 2) void k_rnn(
    const f16* __restrict__ xp, const f16* __restrict__ whh,
    const float* __restrict__ bias2, f16* __restrict__ h16,
    float* __restrict__ hn, float* __restrict__ cn,
    f16* __restrict__ outf16, float* __restrict__ outf32,
    unsigned* __restrict__ flags) {
  __shared__ f16 Wl[64 * WPAD];
  __shared__ int bsT[T_STEPS], offT[T_STEPS];

  const int tid = threadIdx.x;
  const int slice = blockIdx.x % 25;
  const int q = blockIdx.x / 25;  // 0..15 : dir*8 + bt
  const int dir = q >> 3, bt = q & 7;
  const int lane = tid & 63, w = tid >> 6;
  const int lr = lane & 15, kreg = (lane >> 4) * 8;
  const int qr4 = (lane >> 4) * 4;
  const int j0 = slice * 16;
  const int j = j0 + lr;
  unsigned* gflag = flags + (size_t)q * (25 * 32);
  unsigned* myflag = gflag + slice * 32;
  const unsigned* peer = gflag + (lane < 25 ? lane : 0) * 32;

  if (tid == 0) {
    double step = (1.0 - 1024.0) / 127.0;
    for (int i = 0; i < T_STEPS; ++i) bsT[i] = (int)floor((double)i * step + 1024.0);
    bsT[127] = 1; bsT[0] = 1024;
    int sum = 0;
    for (int i = 0; i < T_STEPS; ++i) sum += bsT[i];
    int diff = 65536 - sum;
    while (diff != 0) {
      if (diff > 0) {
        for (int jj = 1; jj < T_STEPS && diff != 0; ++jj) {
          int cap = bsT[jj - 1] - bsT[jj];
          int add = cap < diff ? cap : diff;
          bsT[jj] += add; diff -= add;
        }
      } else {
        for (int jj = T_STEPS - 1; jj >= 1 && diff != 0; --jj) {
          int nxt = (jj + 1 < T_STEPS) ? bsT[jj + 1] : 1;
          int room = bsT[jj] - nxt;
          int sub = room < (-diff) ? room : (-diff);
          bsT[jj] -= sub; diff += sub;
        }
      }
    }
    int a0 = 0;
    for (int i = 0; i < T_STEPS; ++i) { offT[i] = a0; a0 += bsT[i]; }
  }

  // W slice -> LDS (64 rows = 4 gates x 16 j; 416 cols padded to 424)
  const f16* whhD = whh + (size_t)dir * (G4 * HLD);
  {
    int rr = tid >> 2, seg = tid & 3;
    int g = rr >> 4, jr = rr & 15;
    const f16* src = whhD + (size_t)(g * HID + j0 + jr) * HLD + seg * 104;
    f16* dst = &Wl[rr * WPAD + seg * 104];
#pragma unroll
    for (int kk = 0; kk < 13; ++kk)
      *(f16x8*)(dst + kk * 8) = *(const f16x8*)(src + kk * 8);
  }
  const float* biD = bias2 + dir * G4;
  const float bi0 = biD[j], bi1 = biD[HID + j], bi2 = biD[2 * HID + j], bi3 = biD[3 * HID + j];
  float* hp = hn + (size_t)dir * (1024 * HID);
  float* cp = cn + (size_t)dir * (1024 * HID);
  __syncthreads();

  int s_begin = 0;
  if (dir) {  // backward: tile inactive until bs grows past it (h rows still 0)
    while (s_begin < T_STEPS && bsT[T_STEPS - 1 - s_begin] <= bt * 128) ++s_begin;
  }
  const int rowb = bt * 128 + w * 32;
  float ch[2][4] = {{0.f, 0.f, 0.f, 0.f}, {0.f, 0.f, 0.f, 0.f}};

  // initial x prefetch (step s_begin), guarded by bs
  f16x4 xgA[2][4], xgB[2][4];
  {
    int tt = dir ? (T_STEPS - 1 - s_begin) : s_begin;
    int bs0 = bsT[tt], off0 = offT[tt];
#pragma unroll
    for (int mt = 0; mt < 2; ++mt)
#pragma unroll
      for (int r = 0; r < 4; ++r) {
        int b = rowb + mt * 16 + qr4 + r;
        if (b < bs0)
          xgA[mt][r] = *(const f16x4*)(xp + (size_t)(off0 + b) * XPLD
                                       + dir * G4 + slice * 64 + lr * 4);
      }
  }

#pragma unroll 1
  for (int s = s_begin; s < T_STEPS; ++s) {
    const int t = dir ? (T_STEPS - 1 - s) : s;
    const int bs = bsT[t], off = offT[t];
    const bool lastStep = (s == T_STEPS - 1) || (!dir && bsT[s + 1] <= bt * 128);

    // prefetch NEXT step's x (2-deep pipeline; guarded by next bs)
    if (!lastStep) {
      int tn = dir ? (T_STEPS - 2 - s) : (s + 1);
      int bsn = bsT[tn], offn = offT[tn];
#pragma unroll
      for (int mt = 0; mt < 2; ++mt)
#pragma unroll
        for (int r = 0; r < 4; ++r) {
          int b = rowb + mt * 16 + qr4 + r;
          if (b < bsn)
            xgB[mt][r] = *(const f16x4*)(xp + (size_t)(offn + b) * XPLD
                                         + dir * G4 + slice * 64 + lr * 4);
        }
    }

    // wait: all 25 peer blocks completed step s-1
    if (s > s_begin) {
      if (w == 0) {
        while (true) {
          unsigned vv = ld_cc4(peer);
          if (!__ballot((lane < 25) && (vv < (unsigned)s))) break;
          __builtin_amdgcn_s_sleep(1);
        }
      }
      __syncthreads();
    }

    const int cur = s & 1;
    const f16* hr = h16 + (size_t)((dir << 1) | cur) * (1024 * HLD);
    f16* hww = h16 + (size_t)((dir << 1) | (cur ^ 1)) * (1024 * HLD);

    const f16* ha = hr + (size_t)(rowb + lr) * HLD + kreg;
    f16x8 hfa[13], hfb[13];
#pragma unroll
    for (int kk = 0; kk < 13; ++kk) {
      hfa[kk] = ld_cc(ha + kk * 32);
      hfb[kk] = ld_cc(ha + 16 * HLD + kk * 32);
    }
    asm volatile("s_waitcnt vmcnt(0)" ::: "memory");
    __builtin_amdgcn_sched_barrier(0);

    f32x4 acc[2][4] = {};
#pragma unroll
    for (int kk = 0; kk < 13; ++kk) {
#pragma unroll
      for (int g = 0; g < 4; ++g) {
        f16x8 bf = *(const f16x8*)&Wl[(g * 16 + lr) * WPAD + kk * 32 + kreg];
        acc[0][g] = __builtin_amdgcn_mfma_f32_16x16x32_f16(hfa[kk], bf, acc[0][g], 0, 0, 0);
        acc[1][g] = __builtin_amdgcn_mfma_f32_16x16x32_f16(hfb[kk], bf, acc[1][g], 0, 0, 0);
      }
    }

    float hnw[2][4];
    f16 hv16[2][4];
#pragma unroll
    for (int mt = 0; mt < 2; ++mt) {
#pragma unroll
      for (int r = 0; r < 4; ++r) {
        int b = rowb + mt * 16 + qr4 + r;
        if (b < bs) {
          float Gi = acc[mt][0][r] + (float)xgA[mt][r][0] + bi0;
          float Gf = acc[mt][1][r] + (float)xgA[mt][r][1] + bi1;
          float Gg = acc[mt][2][r] + (float)xgA[mt][r][2] + bi2;
          float Go = acc[mt][3][r] + (float)xgA[mt][r][3] + bi3;
          float ii = 1.f / (1.f + __expf(-Gi));
          float ff = 1.f / (1.f + __expf(-Gf));
          float gg = 1.f - 2.f / (__expf(2.f * Gg) + 1.f);
          float oo = 1.f / (1.f + __expf(-Go));
          float cnew = ff * ch[mt][r] + ii * gg;
          ch[mt][r] = cnew;
          float hnew = oo * (1.f - 2.f / (__expf(2.f * cnew) + 1.f));
          union { f16 f; unsigned short u; } cv; cv.f = (f16)hnew;
          st_cc2(&hww[(size_t)b * HLD + j], (unsigned)cv.u);
          hnw[mt][r] = hnew;
          hv16[mt][r] = cv.f;
        }
      }
    }

    if (!lastStep) {
      __syncthreads();                                 // implicit vmcnt(0): h ACKed at L3
      if (tid == 0) st_cc4(myflag, (unsigned)(s + 1)); // publish AFTER h visible
    }

    // deferred outputs (overlap next step's prefetch/spin)
#pragma unroll
    for (int mt = 0; mt < 2; ++mt) {
#pragma unroll
      for (int r = 0; r < 4; ++r) {
        int b = rowb + mt * 16 + qr4 + r;
        if (b < bs) {
          size_t prow = (size_t)(off + b);
          if (outf32) outf32[prow * 800 + dir * HID + j] = hnw[mt][r];
          else        outf16[prow * 800 + dir * HID + j] = hv16[mt][r];
          bool lastv = dir ? (s == T_STEPS - 1)
                           : (s == T_STEPS - 1 || bsT[s + 1] <= b);
          if (lastv) {
            cp[(size_t)b * HID + j] = ch[mt][r];
            hp[(size_t)b * HID + j] = hnw[mt][r];
          }
        }
      }
    }
    if (lastStep) break;
    // rotate x pipeline
#pragma unroll
    for (int mt = 0; mt < 2; ++mt)
#pragma unroll
      for (int r = 0; r < 4; ++r) xgA[mt][r] = xgB[mt][r];
  }
}

// ---------------- fallback per-step kernel (matches xproj gate layout) ----------------
__global__ __launch_bounds__(256) void k_step(
    const f16* __restrict__ xp, const f16* __restrict__ whh,
    const float* __restrict__ bias2, const f16* __restrict__ h16r0,
    f16* __restrict__ h16w0, float* __restrict__ hn, float* __restrict__ cn,
    f16* __restrict__ outf16, float* __restrict__ outf32,
    int bs_f, int off_f, int bs_b, int off_b, int nTf) {
  const int slice = blockIdx.x % 25;
  const int tl = blockIdx.x / 25;
  int dir, bt, bs, off;
  if (tl < nTf) { dir = 0; bt = tl; bs = bs_f; off = off_f; }
  else          { dir = 1; bt = tl - nTf; bs = bs_b; off = off_b; }
  const int lane = threadIdx.x & 63, w = threadIdx.x >> 6;
  const int lr = lane & 15, kreg = (lane >> 4) * 8;
  const int b0 = bt * 128;
  const int j0 = slice * 16;
  const f16* hr = h16r0 + (size_t)dir * (2 * 1024 * HLD);
  f16* hw = h16w0 + (size_t)dir * (2 * 1024 * HLD);
  const f16* W = whh + (size_t)dir * (G4 * HLD);
  const float* bi = bias2 + dir * G4;
  float* hp = hn + (size_t)dir * (1024 * HID);
  float* cp = cn + (size_t)dir * (1024 * HID);

  f32x4 acc[2][4] = {};
  for (int k0 = 0; k0 < HLD; k0 += 32) {
    f16x8 af0 = *(const f16x8*)&hr[(b0 + (w * 2 + 0) * 16 + lr) * HLD + k0 + kreg];
    f16x8 af1 = *(const f16x8*)&hr[(b0 + (w * 2 + 1) * 16 + lr) * HLD + k0 + kreg];
#pragma unroll
    for (int g = 0; g < 4; ++g) {
      f16x8 bf = *(const f16x8*)&W[(g * HID + j0 + lr) * HLD + k0 + kreg];
      acc[0][g] = __builtin_amdgcn_mfma_f32_16x16x32_f16(af0, bf, acc[0][g], 0, 0, 0);
      acc[1][g] = __builtin_amdgcn_mfma_f32_16x16x32_f16(af1, bf, acc[1][g], 0, 0, 0);
    }
  }
  const int j = j0 + lr;
#pragma unroll
  for (int mt = 0; mt < 2; ++mt) {
#pragma unroll
    for (int r = 0; r < 4; ++r) {
      int b = b0 + (w * 2 + mt) * 16 + (lane >> 4) * 4 + r;
      if (b < bs) {
        size_t prow = (size_t)(off + b);
        const f16* xr = xp + prow * XPLD + dir * G4 + slice * 64 + lr * 4;
        float Gi = acc[mt][0][r] + (float)xr[0] + bi[j];
        float Gf = acc[mt][1][r] + (float)xr[1] + bi[HID + j];
        float Gg = acc[mt][2][r] + (float)xr[2] + bi[2 * HID + j];
        float Go = acc[mt][3][r] + (float)xr[3] + bi[3 * HID + j];
        float ii = 1.f / (1.f + __expf(-Gi));
        float ff = 1.f / (1.f + __expf(-Gf));
        float gg = 1.f - 2.f / (__expf(2.f * Gg) + 1.f);
        float oo = 1.f / (1.f + __expf(-Go));
        float co = cp[b * HID + j];
        float cnew = ff * co + ii * gg;
        float hnew = oo * (1.f - 2.f / (__expf(2.f * cnew) + 1.f));
        cp[b * HID + j] = cnew;
        hp[b * HID + j] = hnew;
        hw[b * HLD + j] = (f16)hnew;
        if (outf32) outf32[prow * 800 + dir * HID + j] = hnew;
        else        outf16[prow * 800 + dir * HID + j] = (f16)hnew;
      }
    }
  }
}

// ---------------- host ----------------
extern "C" void kernel_launch(void* const* d_in, const int* in_sizes, int n_in,
                              void* d_out, int out_size, void* d_ws, size_t ws_size,
                              hipStream_t stream) {
  (void)in_sizes; (void)n_in; (void)out_size; (void)ws_size;
  const float* x   = (const float*)d_in[0];
  const float* Wih = (const float*)d_in[1];
  const float* Whh = (const float*)d_in[2];
  const float* bih = (const float*)d_in[3];
  const float* bhh = (const float*)d_in[4];
  float* out = (float*)d_out;

  long long bsv[128];
  {
    double step = (1.0 - 1024.0) / 127.0;
    for (int i = 0; i < 128; ++i) bsv[i] = (long long)floor((double)i * step + 1024.0);
    bsv[127] = 1; bsv[0] = 1024;
    long long sum = 0;
    for (int i = 0; i < 128; ++i) sum += bsv[i];
    long long diff = 65536 - sum;
    while (diff != 0) {
      if (diff > 0) {
        for (int jj = 1; jj < 128 && diff != 0; ++jj) {
          long long cap = bsv[jj - 1] - bsv[jj];
          long long add = cap < diff ? cap : diff;
          bsv[jj] += add; diff -= add;
        }
      } else {
        for (int jj = 127; jj >= 1 && diff != 0; --jj) {
          long long nxt = (jj + 1 < 128) ? bsv[jj + 1] : 1;
          long long room = bsv[jj] - nxt;
          long long sub = room < (-diff) ? room : (-diff);
          bsv[jj] -= sub; diff += sub;
        }
      }
    }
  }
  long long offv[128], a0 = 0;
  for (int i = 0; i < 128; ++i) { offv[i] = a0; a0 += bsv[i]; }

  char* p = (char*)d_ws;
  f16*      x16   = (f16*)(p);                 // 65536x400 f16 (+256B zero pad)
  f16*      wih16 = (f16*)(p + 52429056LL);    // 6x1600x800 f16, gate-permuted rows
  f16*      whh16 = (f16*)(p + 67789056LL);    // 6x1600x416 f16 (zero-padded K)
  float*    bias  = (float*)(p + 75776256LL);  // 6x1600 f32
  f16*      xproj = (f16*)(p + 75814656LL);    // (65536+128)x3200 f16
  unsigned* flags = (unsigned*)(p + 495654656LL);  // 3 layers x 16 groups x 25 x 128B
  f16*      layA  = (f16*)(p + 496064256LL);   // 65536x800 f16
  f16*      layB  = (f16*)(p + 600921856LL);   // 65536x800 f16
  f16*      h16   = (f16*)(p + 705779456LL);   // 2 dir x 2 pp x 1024x416 f16

  hipMemsetAsync(p + 52428800LL, 0, 256, stream);              // x16 K-pad
  hipMemsetAsync(out + 52428800LL, 0, 4915200LL * 4, stream);  // h_n + c_n
  hipMemsetAsync(flags, 0, 3 * 16 * 25 * 128, stream);         // all layer flags

  k_cvt_f16<<<2048, 256, 0, stream>>>(x, x16, 26214400LL);
  k_cvt_wih<<<2048, 256, 0, stream>>>(Wih, wih16);
  k_cvt_whh<<<2048, 256, 0, stream>>>(Whh, whh16, 9600);
  k_bias<<<40, 256, 0, stream>>>(bih, bhh, bias, 9600);

  int occ = 0;
  hipOccupancyMaxActiveBlocksPerMultiprocessor(&occ, k_rnn, 256, 0);
  const bool persistent = (occ >= 2);  // 2/CU x 256 CU = 512 >= 400 co-resident

  const long long OUTP = 52428800LL, HNSZ = 2457600LL;

  for (int L = 0; L < 3; ++L) {
    const f16* Ain = (L == 0) ? x16 : (L == 1 ? layA : layB);
    int lda = (L == 0) ? 400 : 800;
    int K   = (L == 0) ? 416 : 800;
    k_gemm<<<12800, 256, 0, stream>>>(Ain, wih16 + (size_t)(2 * L) * 1600 * 800,
                                      xproj, lda, K);
    hipMemsetAsync(h16, 0, 3407872LL, stream);
    float* hnL = out + OUTP + (size_t)(2 * L) * 409600;
    float* cnL = out + OUTP + HNSZ + (size_t)(2 * L) * 409600;
    f16* o16 = (L == 0) ? layA : (L == 1 ? layB : nullptr);
    float* o32 = (L == 2) ? out : nullptr;
    if (persistent) {
      k_rnn<<<RNN_BLOCKS, 256, 0, stream>>>(
          xproj, whh16 + (size_t)(2 * L) * 1600 * HLD, bias + (size_t)(2 * L) * 1600,
          h16, hnL, cnL, o16, o32, flags + (size_t)L * 16 * 25 * 32);
    } else {
      for (int s = 0; s < 128; ++s) {
        int tf = s, tb = 127 - s;
        int bsf = (int)bsv[tf], bsb = (int)bsv[tb];
        int nTf = (bsf + 127) / 128, nTb = (bsb + 127) / 128;
        k_step<<<25 * (nTf + nTb), 256, 0, stream>>>(
            xproj, whh16 + (size_t)(2 * L) * 1600 * HLD, bias + (size_t)(2 * L) * 1600,
            h16 + (size_t)(s & 1) * 1024 * HLD, h16 + (size_t)((s + 1) & 1) * 1024 * HLD,
            hnL, cnL, o16, o32,
            bsf, (int)offv[tf], bsb, (int)offv[tb], nTf);
      }
    }
  }
}

// Round 8
// 7934.013 us; speedup vs baseline: 1.0599x; 1.0017x over previous
//
#include <hip/hip_runtime.h>
#include <math.h>

using f16 = _Float16;
typedef __attribute__((ext_vector_type(8))) _Float16 f16x8;
typedef __attribute__((ext_vector_type(4))) _Float16 f16x4;
typedef __attribute__((ext_vector_type(4))) float f32x4;

#define T_STEPS 128
#define HID 400
#define G4 1600
#define XPLD 3200
#define HLD 416
#define WPAD 424
#define NSL 13
#define JW 32
#define RNN_BLOCKS (NSL * 16)

__device__ __forceinline__ void gl_lds16(const void* g, void* l) {
  __builtin_amdgcn_global_load_lds((const __attribute__((address_space(1))) void*)g,
                                   (__attribute__((address_space(3))) void*)l, 16, 0, 0);
}

// cross-XCD-coherent ops: bypass L1+L2, hit the L3 coherence point
__device__ __forceinline__ f16x8 ld_cc(const f16* p) {
  f16x8 r;
  asm volatile("global_load_dwordx4 %0, %1, off sc0 sc1" : "=v"(r) : "v"(p));
  return r;  // caller must s_waitcnt vmcnt(0) + sched_barrier before use
}
__device__ __forceinline__ void st_cc2(f16* p, unsigned v) {
  asm volatile("global_store_short %0, %1, off sc0 sc1" :: "v"(p), "v"(v) : "memory");
}
__device__ __forceinline__ unsigned ld_cc4(const unsigned* p) {
  unsigned v;
  asm volatile("global_load_dword %0, %1, off sc0 sc1\n\ts_waitcnt vmcnt(0)"
               : "=v"(v) : "v"(p) : "memory");
  return v;
}

// ---------------- conversion kernels ----------------
__global__ void k_cvt_f16(const float* __restrict__ s, f16* __restrict__ d, long long n) {
  long long i = ((long long)blockIdx.x * blockDim.x + threadIdx.x) * 4;
  long long stride = (long long)gridDim.x * blockDim.x * 4;
  for (; i < n; i += stride) {
    float4 v = *(const float4*)(s + i);
    f16x4 o = { (f16)v.x, (f16)v.y, (f16)v.z, (f16)v.w };
    *(f16x4*)(d + i) = o;
  }
}

// Wih f32 -> f16 with gate-interleave ROW permutation folded in:
// out row R = L*3200 + dirn*1600 + (j/16)*64 + (j%16)*4 + g  <-  in row (2L+dirn)*1600 + g*400 + j
__global__ void k_cvt_wih(const float* __restrict__ s, f16* __restrict__ d) {
  long long n4 = 9600LL * 200;  // 4 elems per iter
  for (long long i = (long long)blockIdx.x * blockDim.x + threadIdx.x; i < n4;
       i += (long long)gridDim.x * blockDim.x) {
    long long i4 = i * 4;
    int R = (int)(i4 / 800), c = (int)(i4 % 800);
    int L = R / 3200, rem = R % 3200;
    int dirn = rem / 1600, q = rem % 1600;
    int g = q & 3, jlo = (q >> 2) & 15, jhi = q >> 6;
    int inrow = (2 * L + dirn) * 1600 + g * HID + jhi * 16 + jlo;
    float4 v = *(const float4*)(s + (long long)inrow * 800 + c);
    f16x4 o = { (f16)v.x, (f16)v.y, (f16)v.z, (f16)v.w };
    *(f16x4*)(d + i4) = o;
  }
}

__global__ void k_cvt_whh(const float* __restrict__ s, f16* __restrict__ d, int nrows) {
  long long n = (long long)nrows * HLD;
  for (long long i = (long long)blockIdx.x * blockDim.x + threadIdx.x; i < n;
       i += (long long)gridDim.x * blockDim.x) {
    int row = (int)(i / HLD), c = (int)(i % HLD);
    d[i] = (c < HID) ? (f16)s[(long long)row * HID + c] : (f16)0.f;
  }
}

__global__ void k_bias(const float* __restrict__ a, const float* __restrict__ b,
                       float* __restrict__ d, int n) {
  for (int i = blockIdx.x * blockDim.x + threadIdx.x; i < n; i += gridDim.x * blockDim.x)
    d[i] = a[i] + b[i];
}

// ---------------- input-projection GEMM (plain, coalesced C, dbuf) ----------------
__global__ __launch_bounds__(256) void k_gemm(const f16* __restrict__ A,
                                              const f16* __restrict__ Bw,
                                              f16* __restrict__ C, int lda, int K) {
  __shared__ f16 As[2][128 * 32];
  __shared__ f16 Bs[2][128 * 32];
  const int tid = threadIdx.x;
  const int lane = tid & 63, w = tid >> 6;
  const int wm = w >> 1, wn = w & 1;
  const int wg = blockIdx.x;
  const int swz = (wg & 7) * 1600 + (wg >> 3);  // bijective XCD swizzle (12800%8==0)
  const int bn = (swz % 25) * 128;
  const long long bm = (long long)(swz / 25) * 128;

  const f16* gA = A + (bm + w * 16 + (lane >> 2)) * (long long)lda + (lane & 3) * 8;
  const f16* gB = Bw + (long long)(bn + w * 16 + (lane >> 2)) * 800 + (lane & 3) * 8;

  const int lr = lane & 15;
  const int kreg = (lane >> 4) * 8;
  const int nk = K / 32;

  f32x4 acc[4][4] = {};

#define STAGE(bb, k0)                                            \
  do {                                                           \
    gl_lds16(gA + (k0), &As[bb][w * 512]);                       \
    gl_lds16(gA + 64LL * lda + (k0), &As[bb][64 * 32 + w * 512]); \
    gl_lds16(gB + (k0), &Bs[bb][w * 512]);                       \
    gl_lds16(gB + 64LL * 800 + (k0), &Bs[bb][64 * 32 + w * 512]); \
  } while (0)

  STAGE(0, 0);
  __syncthreads();
  int cur = 0;
  for (int kt = 0; kt < nk; ++kt) {
    if (kt + 1 < nk) STAGE(cur ^ 1, (kt + 1) * 32);
    f16x8 af[4], bf[4];
#pragma unroll
    for (int mt = 0; mt < 4; ++mt)
      af[mt] = *(const f16x8*)&As[cur][(wm * 64 + mt * 16 + lr) * 32 + kreg];
#pragma unroll
    for (int nt = 0; nt < 4; ++nt)
      bf[nt] = *(const f16x8*)&Bs[cur][(wn * 64 + nt * 16 + lr) * 32 + kreg];
#pragma unroll
    for (int mt = 0; mt < 4; ++mt)
#pragma unroll
      for (int nt = 0; nt < 4; ++nt)
        acc[mt][nt] = __builtin_amdgcn_mfma_f32_16x16x32_f16(af[mt], bf[nt], acc[mt][nt], 0, 0, 0);
    __syncthreads();
    cur ^= 1;
  }
#undef STAGE

#pragma unroll
  for (int mt = 0; mt < 4; ++mt) {
#pragma unroll
    for (int nt = 0; nt < 4; ++nt) {
      long long gm = bm + wm * 64 + mt * 16 + ((lane >> 4) * 4);
      int gn = bn + wn * 64 + nt * 16 + lr;  // linear, coalesced
#pragma unroll
      for (int r = 0; r < 4; ++r)
        C[(gm + r) * XPLD + gn] = (f16)acc[mt][nt][r];
    }
  }
}

// ---------------- persistent recurrence (208 blocks, 1/CU, 13 j-slices) ----------------
// 13 slices x 16 groups (dir x 8 bt of 128 rows). Each block: 128 rows x 32 j-cols
// (gates padded 400->416; pad-j h stores skipped so h pad stays 0).
// Sync: per-group aggregated counter (1 atomic add per block-step; whole-wave poll
// of one L3 line, no post-wait block barrier).
__global__ __launch_bounds__(256, 1) void k_rnn(
    const f16* __restrict__ xp, const f16* __restrict__ whh,
    const float* __restrict__ bias2, f16* __restrict__ h16,
    float* __restrict__ hn, float* __restrict__ cn,
    f16* __restrict__ outf16, float* __restrict__ outf32,
    unsigned* __restrict__ cnts) {
  __shared__ f16 Wl[128 * WPAD];  // 4 gates x 32 j rows, 416(+8 pad) cols
  __shared__ int bsT[T_STEPS], offT[T_STEPS];

  const int tid = threadIdx.x;
  const int slice = blockIdx.x % NSL;
  const int q = blockIdx.x / NSL;  // 0..15 : dir*8 + bt
  const int dir = q >> 3, bt = q & 7;
  const int lane = tid & 63, w = tid >> 6;
  const int lr = lane & 15, kreg = (lane >> 4) * 8;
  const int qr4 = (lane >> 4) * 4;
  const int j0 = slice * JW;
  unsigned* cnt = cnts + (size_t)q * 32;  // group's own 128B line

  if (tid == 0) {
    double step = (1.0 - 1024.0) / 127.0;
    for (int i = 0; i < T_STEPS; ++i) bsT[i] = (int)floor((double)i * step + 1024.0);
    bsT[127] = 1; bsT[0] = 1024;
    int sum = 0;
    for (int i = 0; i < T_STEPS; ++i) sum += bsT[i];
    int diff = 65536 - sum;
    while (diff != 0) {
      if (diff > 0) {
        for (int jj = 1; jj < T_STEPS && diff != 0; ++jj) {
          int cap = bsT[jj - 1] - bsT[jj];
          int add = cap < diff ? cap : diff;
          bsT[jj] += add; diff -= add;
        }
      } else {
        for (int jj = T_STEPS - 1; jj >= 1 && diff != 0; --jj) {
          int nxt = (jj + 1 < T_STEPS) ? bsT[jj + 1] : 1;
          int room = bsT[jj] - nxt;
          int sub = room < (-diff) ? room : (-diff);
          bsT[jj] -= sub; diff += sub;
        }
      }
    }
    int a0 = 0;
    for (int i = 0; i < T_STEPS; ++i) { offT[i] = a0; a0 += bsT[i]; }
  }

  // W slice -> LDS: 128 rows (4 gates x 32 j), 416 cols (pad 424).
  // slice 12 rows j>=400 overrun-read garbage: harmless (their outputs never stored).
  const f16* whhD = whh + (size_t)dir * (G4 * HLD);
  {
    int rr = tid >> 1, seg = tid & 1;
    int g = rr >> 5, jsub = rr & 31;
    const f16* src = whhD + (size_t)(g * HID + j0 + jsub) * HLD + seg * 208;
    f16* dst = &Wl[rr * WPAD + seg * 208];
#pragma unroll
    for (int kk = 0; kk < 26; ++kk)
      *(f16x8*)(dst + kk * 8) = *(const f16x8*)(src + kk * 8);
  }
  const float* biD = bias2 + dir * G4;
  float bi[2][4];
#pragma unroll
  for (int h = 0; h < 2; ++h)
#pragma unroll
    for (int g = 0; g < 4; ++g)
      bi[h][g] = biD[g * HID + j0 + h * 16 + lr];  // j>=400: overrun garbage, dead
  float* hp = hn + (size_t)dir * (1024 * HID);
  float* cp = cn + (size_t)dir * (1024 * HID);
  __syncthreads();

  int s_begin = 0;
  if (dir) {  // backward: tile inactive until bs grows past it (h rows still 0)
    while (s_begin < T_STEPS && bsT[T_STEPS - 1 - s_begin] <= bt * 128) ++s_begin;
  }
  const int rowb = bt * 128 + w * 32;
  float ch[2][2][4] = {};  // [h16][mt][r]

  // initial x prefetch (step s_begin)
  f16x4 xgA[2][2][4], xgB[2][2][4];
  {
    int tt = dir ? (T_STEPS - 1 - s_begin) : s_begin;
    int bs0 = bsT[tt], off0 = offT[tt];
#pragma unroll
    for (int mt = 0; mt < 2; ++mt)
#pragma unroll
      for (int r = 0; r < 4; ++r) {
        int b = rowb + mt * 16 + qr4 + r;
        if (b < bs0) {
          const f16* xr = xp + (size_t)(off0 + b) * XPLD + dir * G4 + slice * 128 + lr * 4;
          xgA[0][mt][r] = *(const f16x4*)(xr);
          xgA[1][mt][r] = *(const f16x4*)(xr + 64);
        }
      }
  }

#pragma unroll 1
  for (int s = s_begin; s < T_STEPS; ++s) {
    const int t = dir ? (T_STEPS - 1 - s) : s;
    const int bs = bsT[t], off = offT[t];
    const bool lastStep = (s == T_STEPS - 1) || (!dir && bsT[s + 1] <= bt * 128);

    // prefetch NEXT step's x (2-deep; guarded by next bs)
    if (!lastStep) {
      int tn = dir ? (T_STEPS - 2 - s) : (s + 1);
      int bsn = bsT[tn], offn = offT[tn];
#pragma unroll
      for (int mt = 0; mt < 2; ++mt)
#pragma unroll
        for (int r = 0; r < 4; ++r) {
          int b = rowb + mt * 16 + qr4 + r;
          if (b < bsn) {
            const f16* xr = xp + (size_t)(offn + b) * XPLD + dir * G4 + slice * 128 + lr * 4;
            xgB[0][mt][r] = *(const f16x4*)(xr);
            xgB[1][mt][r] = *(const f16x4*)(xr + 64);
          }
        }
    }

    // wait: all NSL peers done step s-1 (whole-wave poll of one line; no barrier)
    if (s > s_begin) {
      const unsigned tgt = (unsigned)(NSL * (s - s_begin));
      while (ld_cc4(cnt) < tgt) __builtin_amdgcn_s_sleep(2);
    }

    const int cur = s & 1;
    const f16* hr = h16 + (size_t)((dir << 1) | cur) * (1024 * HLD);
    f16* hww = h16 + (size_t)((dir << 1) | (cur ^ 1)) * (1024 * HLD);

    const f16* ha = hr + (size_t)(rowb + lr) * HLD + kreg;
    f16x8 hfa[13], hfb[13];
#pragma unroll
    for (int kk = 0; kk < 13; ++kk) {
      hfa[kk] = ld_cc(ha + kk * 32);
      hfb[kk] = ld_cc(ha + 16 * HLD + kk * 32);
    }
    asm volatile("s_waitcnt vmcnt(0)" ::: "memory");
    __builtin_amdgcn_sched_barrier(0);

    f32x4 acc[2][8] = {};  // [mt][g*2+h16]
#pragma unroll
    for (int kk = 0; kk < 13; ++kk) {
#pragma unroll
      for (int nt = 0; nt < 8; ++nt) {
        f16x8 bf = *(const f16x8*)&Wl[(((nt >> 1) << 5) + ((nt & 1) << 4) + lr) * WPAD
                                      + kk * 32 + kreg];
        acc[0][nt] = __builtin_amdgcn_mfma_f32_16x16x32_f16(hfa[kk], bf, acc[0][nt], 0, 0, 0);
        acc[1][nt] = __builtin_amdgcn_mfma_f32_16x16x32_f16(hfb[kk], bf, acc[1][nt], 0, 0, 0);
      }
    }

    float hnw[2][2][4];
    f16 hv16[2][2][4];
#pragma unroll
    for (int h = 0; h < 2; ++h) {
      const int jc = j0 + h * 16 + lr;
#pragma unroll
      for (int mt = 0; mt < 2; ++mt) {
#pragma unroll
        for (int r = 0; r < 4; ++r) {
          int b = rowb + mt * 16 + qr4 + r;
          if (b < bs && jc < HID) {  // pad-j cells never stored -> h pad stays 0
            float Gi = acc[mt][0 + h][r] + (float)xgA[h][mt][r][0] + bi[h][0];
            float Gf = acc[mt][2 + h][r] + (float)xgA[h][mt][r][1] + bi[h][1];
            float Gg = acc[mt][4 + h][r] + (float)xgA[h][mt][r][2] + bi[h][2];
            float Go = acc[mt][6 + h][r] + (float)xgA[h][mt][r][3] + bi[h][3];
            float ii = 1.f / (1.f + __expf(-Gi));
            float ff = 1.f / (1.f + __expf(-Gf));
            float gg = 1.f - 2.f / (__expf(2.f * Gg) + 1.f);
            float oo = 1.f / (1.f + __expf(-Go));
            float cnew = ff * ch[h][mt][r] + ii * gg;
            ch[h][mt][r] = cnew;
            float hnew = oo * (1.f - 2.f / (__expf(2.f * cnew) + 1.f));
            union { f16 f; unsigned short u; } cv; cv.f = (f16)hnew;
            st_cc2(&hww[(size_t)b * HLD + jc], (unsigned)cv.u);
            hnw[h][mt][r] = hnew;
            hv16[h][mt][r] = cv.f;
          }
        }
      }
    }

    if (!lastStep) {
      asm volatile("s_waitcnt vmcnt(0)" ::: "memory");  // h stores ACKed at L3
      __syncthreads();                                   // all waves drained
      if (tid == 0)
        __hip_atomic_fetch_add(cnt, 1u, __ATOMIC_RELAXED, __HIP_MEMORY_SCOPE_AGENT);
    }

    // deferred outputs (overlap next step's prefetch/spin)
#pragma unroll
    for (int h = 0; h < 2; ++h) {
      const int jc = j0 + h * 16 + lr;
#pragma unroll
      for (int mt = 0; mt < 2; ++mt) {
#pragma unroll
        for (int r = 0; r < 4; ++r) {
          int b = rowb + mt * 16 + qr4 + r;
          if (b < bs && jc < HID) {
            size_t prow = (size_t)(off + b);
            if (outf32) outf32[prow * 800 + dir * HID + jc] = hnw[h][mt][r];
            else        outf16[prow * 800 + dir * HID + jc] = hv16[h][mt][r];
            bool lastv = dir ? (s == T_STEPS - 1)
                             : (s == T_STEPS - 1 || bsT[s + 1] <= b);
            if (lastv) {
              cp[(size_t)b * HID + jc] = ch[h][mt][r];
              hp[(size_t)b * HID + jc] = hnw[h][mt][r];
            }
          }
        }
      }
    }
    if (lastStep) break;
    // rotate x pipeline
#pragma unroll
    for (int h = 0; h < 2; ++h)
#pragma unroll
      for (int mt = 0; mt < 2; ++mt)
#pragma unroll
        for (int r = 0; r < 4; ++r) xgA[h][mt][r] = xgB[h][mt][r];
  }
}

// ---------------- fallback per-step kernel (matches xproj gate layout) ----------------
__global__ __launch_bounds__(256) void k_step(
    const f16* __restrict__ xp, const f16* __restrict__ whh,
    const float* __restrict__ bias2, const f16* __restrict__ h16r0,
    f16* __restrict__ h16w0, float* __restrict__ hn, float* __restrict__ cn,
    f16* __restrict__ outf16, float* __restrict__ outf32,
    int bs_f, int off_f, int bs_b, int off_b, int nTf) {
  const int slice = blockIdx.x % 25;
  const int tl = blockIdx.x / 25;
  int dir, bt, bs, off;
  if (tl < nTf) { dir = 0; bt = tl; bs = bs_f; off = off_f; }
  else          { dir = 1; bt = tl - nTf; bs = bs_b; off = off_b; }
  const int lane = threadIdx.x & 63, w = threadIdx.x >> 6;
  const int lr = lane & 15, kreg = (lane >> 4) * 8;
  const int b0 = bt * 128;
  const int j0 = slice * 16;
  const f16* hr = h16r0 + (size_t)dir * (2 * 1024 * HLD);
  f16* hw = h16w0 + (size_t)dir * (2 * 1024 * HLD);
  const f16* W = whh + (size_t)dir * (G4 * HLD);
  const float* bi = bias2 + dir * G4;
  float* hp = hn + (size_t)dir * (1024 * HID);
  float* cp = cn + (size_t)dir * (1024 * HID);

  f32x4 acc[2][4] = {};
  for (int k0 = 0; k0 < HLD; k0 += 32) {
    f16x8 af0 = *(const f16x8*)&hr[(b0 + (w * 2 + 0) * 16 + lr) * HLD + k0 + kreg];
    f16x8 af1 = *(const f16x8*)&hr[(b0 + (w * 2 + 1) * 16 + lr) * HLD + k0 + kreg];
#pragma unroll
    for (int g = 0; g < 4; ++g) {
      f16x8 bf = *(const f16x8*)&W[(g * HID + j0 + lr) * HLD + k0 + kreg];
      acc[0][g] = __builtin_amdgcn_mfma_f32_16x16x32_f16(af0, bf, acc[0][g], 0, 0, 0);
      acc[1][g] = __builtin_amdgcn_mfma_f32_16x16x32_f16(af1, bf, acc[1][g], 0, 0, 0);
    }
  }
  const int j = j0 + lr;
#pragma unroll
  for (int mt = 0; mt < 2; ++mt) {
#pragma unroll
    for (int r = 0; r < 4; ++r) {
      int b = b0 + (w * 2 + mt) * 16 + (lane >> 4) * 4 + r;
      if (b < bs) {
        size_t prow = (size_t)(off + b);
        const f16* xr = xp + prow * XPLD + dir * G4 + slice * 64 + lr * 4;
        float Gi = acc[mt][0][r] + (float)xr[0] + bi[j];
        float Gf = acc[mt][1][r] + (float)xr[1] + bi[HID + j];
        float Gg = acc[mt][2][r] + (float)xr[2] + bi[2 * HID + j];
        float Go = acc[mt][3][r] + (float)xr[3] + bi[3 * HID + j];
        float ii = 1.f / (1.f + __expf(-Gi));
        float ff = 1.f / (1.f + __expf(-Gf));
        float gg = 1.f - 2.f / (__expf(2.f * Gg) + 1.f);
        float oo = 1.f / (1.f + __expf(-Go));
        float co = cp[b * HID + j];
        float cnew = ff * co + ii * gg;
        float hnew = oo * (1.f - 2.f / (__expf(2.f * cnew) + 1.f));
        cp[b * HID + j] = cnew;
        hp[b * HID + j] = hnew;
        hw[b * HLD + j] = (f16)hnew;
        if (outf32) outf32[prow * 800 + dir * HID + j] = hnew;
        else        outf16[prow * 800 + dir * HID + j] = (f16)hnew;
      }
    }
  }
}

// ---------------- host ----------------
extern "C" void kernel_launch(void* const* d_in, const int* in_sizes, int n_in,
                              void* d_out, int out_size, void* d_ws, size_t ws_size,
                              hipStream_t stream) {
  (void)in_sizes; (void)n_in; (void)out_size; (void)ws_size;
  const float* x   = (const float*)d_in[0];
  const float* Wih = (const float*)d_in[1];
  const float* Whh = (const float*)d_in[2];
  const float* bih = (const float*)d_in[3];
  const float* bhh = (const float*)d_in[4];
  float* out = (float*)d_out;

  long long bsv[128];
  {
    double step = (1.0 - 1024.0) / 127.0;
    for (int i = 0; i < 128; ++i) bsv[i] = (long long)floor((double)i * step + 1024.0);
    bsv[127] = 1; bsv[0] = 1024;
    long long sum = 0;
    for (int i = 0; i < 128; ++i) sum += bsv[i];
    long long diff = 65536 - sum;
    while (diff != 0) {
      if (diff > 0) {
        for (int jj = 1; jj < 128 && diff != 0; ++jj) {
          long long cap = bsv[jj - 1] - bsv[jj];
          long long add = cap < diff ? cap : diff;
          bsv[jj] += add; diff -= add;
        }
      } else {
        for (int jj = 127; jj >= 1 && diff != 0; --jj) {
          long long nxt = (jj + 1 < 128) ? bsv[jj + 1] : 1;
          long long room = bsv[jj] - nxt;
          long long sub = room < (-diff) ? room : (-diff);
          bsv[jj] -= sub; diff += sub;
        }
      }
    }
  }
  long long offv[128], a0 = 0;
  for (int i = 0; i < 128; ++i) { offv[i] = a0; a0 += bsv[i]; }

  char* p = (char*)d_ws;
  f16*      x16   = (f16*)(p);                 // 65536x400 f16 (+256B zero pad)
  f16*      wih16 = (f16*)(p + 52429056LL);    // 6x1600x800 f16, gate-permuted rows
  f16*      whh16 = (f16*)(p + 67789056LL);    // 6x1600x416 f16 (zero-padded K)
  float*    bias  = (float*)(p + 75776256LL);  // 6x1600 f32
  f16*      xproj = (f16*)(p + 75814656LL);    // (65536+128)x3200 f16
  unsigned* cnts  = (unsigned*)(p + 495654656LL);  // 3 layers x 16 groups x 128B
  f16*      layA  = (f16*)(p + 496064256LL);   // 65536x800 f16
  f16*      layB  = (f16*)(p + 600921856LL);   // 65536x800 f16
  f16*      h16   = (f16*)(p + 705779456LL);   // 2 dir x 2 pp x 1024x416 f16

  hipMemsetAsync(p + 52428800LL, 0, 256, stream);              // x16 K-pad
  hipMemsetAsync(out + 52428800LL, 0, 4915200LL * 4, stream);  // h_n + c_n
  hipMemsetAsync(cnts, 0, 3 * 16 * 128, stream);               // all layer counters

  k_cvt_f16<<<2048, 256, 0, stream>>>(x, x16, 26214400LL);
  k_cvt_wih<<<2048, 256, 0, stream>>>(Wih, wih16);
  k_cvt_whh<<<2048, 256, 0, stream>>>(Whh, whh16, 9600);
  k_bias<<<40, 256, 0, stream>>>(bih, bhh, bias, 9600);

  int occ = 0;
  hipOccupancyMaxActiveBlocksPerMultiprocessor(&occ, k_rnn, 256, 0);
  const bool persistent = (occ >= 1);  // 208 blocks <= 256 CUs at 1/CU

  const long long OUTP = 52428800LL, HNSZ = 2457600LL;

  for (int L = 0; L < 3; ++L) {
    const f16* Ain = (L == 0) ? x16 : (L == 1 ? layA : layB);
    int lda = (L == 0) ? 400 : 800;
    int K   = (L == 0) ? 416 : 800;
    k_gemm<<<12800, 256, 0, stream>>>(Ain, wih16 + (size_t)(2 * L) * 1600 * 800,
                                      xproj, lda, K);
    hipMemsetAsync(h16, 0, 3407872LL, stream);
    float* hnL = out + OUTP + (size_t)(2 * L) * 409600;
    float* cnL = out + OUTP + HNSZ + (size_t)(2 * L) * 409600;
    f16* o16 = (L == 0) ? layA : (L == 1 ? layB : nullptr);
    float* o32 = (L == 2) ? out : nullptr;
    if (persistent) {
      k_rnn<<<RNN_BLOCKS, 256, 0, stream>>>(
          xproj, whh16 + (size_t)(2 * L) * 1600 * HLD, bias + (size_t)(2 * L) * 1600,
          h16, hnL, cnL, o16, o32, cnts + (size_t)L * 16 * 32);
    } else {
      for (int s = 0; s < 128; ++s) {
        int tf = s, tb = 127 - s;
        int bsf = (int)bsv[tf], bsb = (int)bsv[tb];
        int nTf = (bsf + 127) / 128, nTb = (bsb + 127) / 128;
        k_step<<<25 * (nTf + nTb), 256, 0, stream>>>(
            xproj, whh16 + (size_t)(2 * L) * 1600 * HLD, bias + (size_t)(2 * L) * 1600,
            h16 + (size_t)(s & 1) * 1024 * HLD, h16 + (size_t)((s + 1) & 1) * 1024 * HLD,
            hnL, cnL, o16, o32,
            bsf, (int)offv[tf], bsb, (int)offv[tb], nTf);
      }
    }
  }
}

// Round 9
// 7904.720 us; speedup vs baseline: 1.0639x; 1.0037x over previous
//
#include <hip/hip_runtime.h>
#include <math.h>

using f16 = _Float16;
typedef __attribute__((ext_vector_type(8))) _Float16 f16x8;
typedef __attribute__((ext_vector_type(4))) _Float16 f16x4;
typedef __attribute__((ext_vector_type(4))) float f32x4;

#define T_STEPS 128
#define HID 400
#define G4 1600
#define XPLD 3200
#define HLD 416
#define WPAD 424
#define RNN_BLOCKS 400

__device__ __forceinline__ void gl_lds16(const void* g, void* l) {
  __builtin_amdgcn_global_load_lds((const __attribute__((address_space(1))) void*)g,
                                   (__attribute__((address_space(3))) void*)l, 16, 0, 0);
}

// cross-XCD-coherent ops: bypass L1+L2, hit the L3 coherence point
__device__ __forceinline__ f16x8 ld_cc(const f16* p) {
  f16x8 r;
  asm volatile("global_load_dwordx4 %0, %1, off sc0 sc1" : "=v"(r) : "v"(p));
  return r;  // caller must s_waitcnt vmcnt(0) + sched_barrier before use
}
__device__ __forceinline__ void st_cc2(f16* p, unsigned v) {
  asm volatile("global_store_short %0, %1, off sc0 sc1" :: "v"(p), "v"(v) : "memory");
}
__device__ __forceinline__ void st_cc4(unsigned* p, unsigned v) {
  asm volatile("global_store_dword %0, %1, off sc0 sc1" :: "v"(p), "v"(v) : "memory");
}
__device__ __forceinline__ unsigned ld_cc4(const unsigned* p) {
  unsigned v;
  asm volatile("global_load_dword %0, %1, off sc0 sc1\n\ts_waitcnt vmcnt(0)"
               : "=v"(v) : "v"(p) : "memory");
  return v;
}

// ---------------- conversion kernels ----------------
__global__ void k_cvt_f16(const float* __restrict__ s, f16* __restrict__ d, long long n) {
  long long i = ((long long)blockIdx.x * blockDim.x + threadIdx.x) * 4;
  long long stride = (long long)gridDim.x * blockDim.x * 4;
  for (; i < n; i += stride) {
    float4 v = *(const float4*)(s + i);
    f16x4 o = { (f16)v.x, (f16)v.y, (f16)v.z, (f16)v.w };
    *(f16x4*)(d + i) = o;
  }
}

// Wih f32 -> f16 with gate-interleave ROW permutation folded in:
// out row R = L*3200 + dirn*1600 + (j/16)*64 + (j%16)*4 + g  <-  in row (2L+dirn)*1600 + g*400 + j
__global__ void k_cvt_wih(const float* __restrict__ s, f16* __restrict__ d) {
  long long n4 = 9600LL * 200;  // 4 elems per iter
  for (long long i = (long long)blockIdx.x * blockDim.x + threadIdx.x; i < n4;
       i += (long long)gridDim.x * blockDim.x) {
    long long i4 = i * 4;
    int R = (int)(i4 / 800), c = (int)(i4 % 800);
    int L = R / 3200, rem = R % 3200;
    int dirn = rem / 1600, q = rem % 1600;
    int g = q & 3, jlo = (q >> 2) & 15, jhi = q >> 6;
    int inrow = (2 * L + dirn) * 1600 + g * HID + jhi * 16 + jlo;
    float4 v = *(const float4*)(s + (long long)inrow * 800 + c);
    f16x4 o = { (f16)v.x, (f16)v.y, (f16)v.z, (f16)v.w };
    *(f16x4*)(d + i4) = o;
  }
}

__global__ void k_cvt_whh(const float* __restrict__ s, f16* __restrict__ d, int nrows) {
  long long n = (long long)nrows * HLD;
  for (long long i = (long long)blockIdx.x * blockDim.x + threadIdx.x; i < n;
       i += (long long)gridDim.x * blockDim.x) {
    int row = (int)(i / HLD), c = (int)(i % HLD);
    d[i] = (c < HID) ? (f16)s[(long long)row * HID + c] : (f16)0.f;
  }
}

__global__ void k_bias(const float* __restrict__ a, const float* __restrict__ b,
                       float* __restrict__ d, int n) {
  for (int i = blockIdx.x * blockDim.x + threadIdx.x; i < n; i += gridDim.x * blockDim.x)
    d[i] = a[i] + b[i];
}

// ---------------- input-projection GEMM (dbuf + bank-conflict-free LDS) ----------------
// C[m][n] = sum_k A[m][k]*Bw[n][k]; 128x128 tile, BK=32, gl_lds staging, 2-buf.
// LDS rows stride 64B => naive reads are 8-way bank-conflicted. Fix (T2 + rule 21):
// gl_lds dest stays linear; the 16B k-chunk stored at slot c' is global chunk
// c' ^ ((row>>1)&3), achieved by pre-swizzling the per-lane GLOBAL source address;
// reads XOR the same pattern. 16 lanes -> 8 distinct 4-bank groups x 2 = conflict-free.
__global__ __launch_bounds__(256) void k_gemm(const f16* __restrict__ A,
                                              const f16* __restrict__ Bw,
                                              f16* __restrict__ C, int lda, int K) {
  __shared__ f16 As[2][128 * 32];
  __shared__ f16 Bs[2][128 * 32];
  const int tid = threadIdx.x;
  const int lane = tid & 63, w = tid >> 6;
  const int wm = w >> 1, wn = w & 1;
  const int wg = blockIdx.x;
  const int swz = (wg & 7) * 1600 + (wg >> 3);  // bijective XCD swizzle (12800%8==0)
  const int bn = (swz % 25) * 128;
  const long long bm = (long long)(swz / 25) * 128;

  // staging: lane l -> row l>>2, stored-chunk l&3 holds global chunk (l&3)^((l>>3)&3)
  const int kc = ((lane & 3) ^ ((lane >> 3) & 3)) * 8;
  const f16* gA = A + (bm + w * 16 + (lane >> 2)) * (long long)lda + kc;
  const f16* gB = Bw + (long long)(bn + w * 16 + (lane >> 2)) * 800 + kc;

  const int lr = lane & 15;
  // swizzled read chunk: logical chunk (lane>>4) at slot (lane>>4)^((row>>1)&3), row&15==lr
  const int kswz = (((lane >> 4) ^ ((lr >> 1) & 3)) << 3);
  const int nk = K / 32;

  f32x4 acc[4][4] = {};

#define STAGE(bb, k0)                                            \
  do {                                                           \
    gl_lds16(gA + (k0), &As[bb][w * 512]);                       \
    gl_lds16(gA + 64LL * lda + (k0), &As[bb][64 * 32 + w * 512]); \
    gl_lds16(gB + (k0), &Bs[bb][w * 512]);                       \
    gl_lds16(gB + 64LL * 800 + (k0), &Bs[bb][64 * 32 + w * 512]); \
  } while (0)

  STAGE(0, 0);
  __syncthreads();
  int cur = 0;
  for (int kt = 0; kt < nk; ++kt) {
    if (kt + 1 < nk) STAGE(cur ^ 1, (kt + 1) * 32);
    f16x8 af[4], bf[4];
#pragma unroll
    for (int mt = 0; mt < 4; ++mt)
      af[mt] = *(const f16x8*)&As[cur][(wm * 64 + mt * 16 + lr) * 32 + kswz];
#pragma unroll
    for (int nt = 0; nt < 4; ++nt)
      bf[nt] = *(const f16x8*)&Bs[cur][(wn * 64 + nt * 16 + lr) * 32 + kswz];
#pragma unroll
    for (int mt = 0; mt < 4; ++mt)
#pragma unroll
      for (int nt = 0; nt < 4; ++nt)
        acc[mt][nt] = __builtin_amdgcn_mfma_f32_16x16x32_f16(af[mt], bf[nt], acc[mt][nt], 0, 0, 0);
    __syncthreads();  // drains next-tile gl_lds; protects buffer overwrite
    cur ^= 1;
  }
#undef STAGE

#pragma unroll
  for (int mt = 0; mt < 4; ++mt) {
#pragma unroll
    for (int nt = 0; nt < 4; ++nt) {
      long long gm = bm + wm * 64 + mt * 16 + ((lane >> 4) * 4);
      int gn = bn + wn * 64 + nt * 16 + lr;  // linear, coalesced
#pragma unroll
      for (int r = 0; r < 4; ++r)
        C[(gm + r) * XPLD + gn] = (f16)acc[mt][nt][r];
    }
  }
}

// ---------------- persistent recurrence (round-7 config: 400 blocks, 25 slices) ----------------
__global__ __launch_bounds__(256, 2) void k_rnn(
    const f16* __restrict__ xp, const f16* __restrict__ whh,
    const float* __restrict__ bias2, f16* __restrict__ h16,
    float* __restrict__ hn, float* __restrict__ cn,
    f16* __restrict__ outf16, float* __restrict__ outf32,
    unsigned* __restrict__ flags) {
  __shared__ f16 Wl[64 * WPAD];
  __shared__ int bsT[T_STEPS], offT[T_STEPS];

  const int tid = threadIdx.x;
  const int slice = blockIdx.x % 25;
  const int q = blockIdx.x / 25;  // 0..15 : dir*8 + bt
  const int dir = q >> 3, bt = q & 7;
  const int lane = tid & 63, w = tid >> 6;
  const int lr = lane & 15, kreg = (lane >> 4) * 8;
  const int qr4 = (lane >> 4) * 4;
  const int j0 = slice * 16;
  const int j = j0 + lr;
  unsigned* gflag = flags + (size_t)q * (25 * 32);
  unsigned* myflag = gflag + slice * 32;
  const unsigned* peer = gflag + (lane < 25 ? lane : 0) * 32;

  if (tid == 0) {
    double step = (1.0 - 1024.0) / 127.0;
    for (int i = 0; i < T_STEPS; ++i) bsT[i] = (int)floor((double)i * step + 1024.0);
    bsT[127] = 1; bsT[0] = 1024;
    int sum = 0;
    for (int i = 0; i < T_STEPS; ++i) sum += bsT[i];
    int diff = 65536 - sum;
    while (diff != 0) {
      if (diff > 0) {
        for (int jj = 1; jj < T_STEPS && diff != 0; ++jj) {
          int cap = bsT[jj - 1] - bsT[jj];
          int add = cap < diff ? cap : diff;
          bsT[jj] += add; diff -= add;
        }
      } else {
        for (int jj = T_STEPS - 1; jj >= 1 && diff != 0; --jj) {
          int nxt = (jj + 1 < T_STEPS) ? bsT[jj + 1] : 1;
          int room = bsT[jj] - nxt;
          int sub = room < (-diff) ? room : (-diff);
          bsT[jj] -= sub; diff += sub;
        }
      }
    }
    int a0 = 0;
    for (int i = 0; i < T_STEPS; ++i) { offT[i] = a0; a0 += bsT[i]; }
  }

  // W slice -> LDS (64 rows = 4 gates x 16 j; 416 cols padded to 424)
  const f16* whhD = whh + (size_t)dir * (G4 * HLD);
  {
    int rr = tid >> 2, seg = tid & 3;
    int g = rr >> 4, jr = rr & 15;
    const f16* src = whhD + (size_t)(g * HID + j0 + jr) * HLD + seg * 104;
    f16* dst = &Wl[rr * WPAD + seg * 104];
#pragma unroll
    for (int kk = 0; kk < 13; ++kk)
      *(f16x8*)(dst + kk * 8) = *(const f16x8*)(src + kk * 8);
  }
  const float* biD = bias2 + dir * G4;
  const float bi0 = biD[j], bi1 = biD[HID + j], bi2 = biD[2 * HID + j], bi3 = biD[3 * HID + j];
  float* hp = hn + (size_t)dir * (1024 * HID);
  float* cp = cn + (size_t)dir * (1024 * HID);
  __syncthreads();

  int s_begin = 0;
  if (dir) {  // backward: tile inactive until bs grows past it (h rows still 0)
    while (s_begin < T_STEPS && bsT[T_STEPS - 1 - s_begin] <= bt * 128) ++s_begin;
  }
  const int rowb = bt * 128 + w * 32;
  float ch[2][4] = {{0.f, 0.f, 0.f, 0.f}, {0.f, 0.f, 0.f, 0.f}};

  // initial x prefetch (step s_begin), guarded by bs
  f16x4 xgA[2][4], xgB[2][4];
  {
    int tt = dir ? (T_STEPS - 1 - s_begin) : s_begin;
    int bs0 = bsT[tt], off0 = offT[tt];
#pragma unroll
    for (int mt = 0; mt < 2; ++mt)
#pragma unroll
      for (int r = 0; r < 4; ++r) {
        int b = rowb + mt * 16 + qr4 + r;
        if (b < bs0)
          xgA[mt][r] = *(const f16x4*)(xp + (size_t)(off0 + b) * XPLD
                                       + dir * G4 + slice * 64 + lr * 4);
      }
  }

#pragma unroll 1
  for (int s = s_begin; s < T_STEPS; ++s) {
    const int t = dir ? (T_STEPS - 1 - s) : s;
    const int bs = bsT[t], off = offT[t];
    const bool lastStep = (s == T_STEPS - 1) || (!dir && bsT[s + 1] <= bt * 128);

    // prefetch NEXT step's x (2-deep pipeline; guarded by next bs)
    if (!lastStep) {
      int tn = dir ? (T_STEPS - 2 - s) : (s + 1);
      int bsn = bsT[tn], offn = offT[tn];
#pragma unroll
      for (int mt = 0; mt < 2; ++mt)
#pragma unroll
        for (int r = 0; r < 4; ++r) {
          int b = rowb + mt * 16 + qr4 + r;
          if (b < bsn)
            xgB[mt][r] = *(const f16x4*)(xp + (size_t)(offn + b) * XPLD
                                         + dir * G4 + slice * 64 + lr * 4);
        }
    }

    // wait: all 25 peer blocks completed step s-1
    if (s > s_begin) {
      if (w == 0) {
        while (true) {
          unsigned vv = ld_cc4(peer);
          if (!__ballot((lane < 25) && (vv < (unsigned)s))) break;
          __builtin_amdgcn_s_sleep(1);
        }
      }
      __syncthreads();
    }

    const int cur = s & 1;
    const f16* hr = h16 + (size_t)((dir << 1) | cur) * (1024 * HLD);
    f16* hww = h16 + (size_t)((dir << 1) | (cur ^ 1)) * (1024 * HLD);

    const f16* ha = hr + (size_t)(rowb + lr) * HLD + kreg;
    f16x8 hfa[13], hfb[13];
#pragma unroll
    for (int kk = 0; kk < 13; ++kk) {
      hfa[kk] = ld_cc(ha + kk * 32);
      hfb[kk] = ld_cc(ha + 16 * HLD + kk * 32);
    }
    asm volatile("s_waitcnt vmcnt(0)" ::: "memory");
    __builtin_amdgcn_sched_barrier(0);

    f32x4 acc[2][4] = {};
#pragma unroll
    for (int kk = 0; kk < 13; ++kk) {
#pragma unroll
      for (int g = 0; g < 4; ++g) {
        f16x8 bf = *(const f16x8*)&Wl[(g * 16 + lr) * WPAD + kk * 32 + kreg];
        acc[0][g] = __builtin_amdgcn_mfma_f32_16x16x32_f16(hfa[kk], bf, acc[0][g], 0, 0, 0);
        acc[1][g] = __builtin_amdgcn_mfma_f32_16x16x32_f16(hfb[kk], bf, acc[1][g], 0, 0, 0);
      }
    }

    float hnw[2][4];
    f16 hv16[2][4];
#pragma unroll
    for (int mt = 0; mt < 2; ++mt) {
#pragma unroll
      for (int r = 0; r < 4; ++r) {
        int b = rowb + mt * 16 + qr4 + r;
        if (b < bs) {
          float Gi = acc[mt][0][r] + (float)xgA[mt][r][0] + bi0;
          float Gf = acc[mt][1][r] + (float)xgA[mt][r][1] + bi1;
          float Gg = acc[mt][2][r] + (float)xgA[mt][r][2] + bi2;
          float Go = acc[mt][3][r] + (float)xgA[mt][r][3] + bi3;
          float ii = 1.f / (1.f + __expf(-Gi));
          float ff = 1.f / (1.f + __expf(-Gf));
          float gg = 1.f - 2.f / (__expf(2.f * Gg) + 1.f);
          float oo = 1.f / (1.f + __expf(-Go));
          float cnew = ff * ch[mt][r] + ii * gg;
          ch[mt][r] = cnew;
          float hnew = oo * (1.f - 2.f / (__expf(2.f * cnew) + 1.f));
          union { f16 f; unsigned short u; } cv; cv.f = (f16)hnew;
          st_cc2(&hww[(size_t)b * HLD + j], (unsigned)cv.u);
          hnw[mt][r] = hnew;
          hv16[mt][r] = cv.f;
        }
      }
    }

    if (!lastStep) {
      __syncthreads();                                 // implicit vmcnt(0): h ACKed at L3
      if (tid == 0) st_cc4(myflag, (unsigned)(s + 1)); // publish AFTER h visible
    }

    // deferred outputs (overlap next step's prefetch/spin)
#pragma unroll
    for (int mt = 0; mt < 2; ++mt) {
#pragma unroll
      for (int r = 0; r < 4; ++r) {
        int b = rowb + mt * 16 + qr4 + r;
        if (b < bs) {
          size_t prow = (size_t)(off + b);
          if (outf32) outf32[prow * 800 + dir * HID + j] = hnw[mt][r];
          else        outf16[prow * 800 + dir * HID + j] = hv16[mt][r];
          bool lastv = dir ? (s == T_STEPS - 1)
                           : (s == T_STEPS - 1 || bsT[s + 1] <= b);
          if (lastv) {
            cp[(size_t)b * HID + j] = ch[mt][r];
            hp[(size_t)b * HID + j] = hnw[mt][r];
          }
        }
      }
    }
    if (lastStep) break;
    // rotate x pipeline
#pragma unroll
    for (int mt = 0; mt < 2; ++mt)
#pragma unroll
      for (int r = 0; r < 4; ++r) xgA[mt][r] = xgB[mt][r];
  }
}

// ---------------- fallback per-step kernel (matches xproj gate layout) ----------------
__global__ __launch_bounds__(256) void k_step(
    const f16* __restrict__ xp, const f16* __restrict__ whh,
    const float* __restrict__ bias2, const f16* __restrict__ h16r0,
    f16* __restrict__ h16w0, float* __restrict__ hn, float* __restrict__ cn,
    f16* __restrict__ outf16, float* __restrict__ outf32,
    int bs_f, int off_f, int bs_b, int off_b, int nTf) {
  const int slice = blockIdx.x % 25;
  const int tl = blockIdx.x / 25;
  int dir, bt, bs, off;
  if (tl < nTf) { dir = 0; bt = tl; bs = bs_f; off = off_f; }
  else          { dir = 1; bt = tl - nTf; bs = bs_b; off = off_b; }
  const int lane = threadIdx.x & 63, w = threadIdx.x >> 6;
  const int lr = lane & 15, kreg = (lane >> 4) * 8;
  const int b0 = bt * 128;
  const int j0 = slice * 16;
  const f16* hr = h16r0 + (size_t)dir * (2 * 1024 * HLD);
  f16* hw = h16w0 + (size_t)dir * (2 * 1024 * HLD);
  const f16* W = whh + (size_t)dir * (G4 * HLD);
  const float* bi = bias2 + dir * G4;
  float* hp = hn + (size_t)dir * (1024 * HID);
  float* cp = cn + (size_t)dir * (1024 * HID);

  f32x4 acc[2][4] = {};
  for (int k0 = 0; k0 < HLD; k0 += 32) {
    f16x8 af0 = *(const f16x8*)&hr[(b0 + (w * 2 + 0) * 16 + lr) * HLD + k0 + kreg];
    f16x8 af1 = *(const f16x8*)&hr[(b0 + (w * 2 + 1) * 16 + lr) * HLD + k0 + kreg];
#pragma unroll
    for (int g = 0; g < 4; ++g) {
      f16x8 bf = *(const f16x8*)&W[(g * HID + j0 + lr) * HLD + k0 + kreg];
      acc[0][g] = __builtin_amdgcn_mfma_f32_16x16x32_f16(af0, bf, acc[0][g], 0, 0, 0);
      acc[1][g] = __builtin_amdgcn_mfma_f32_16x16x32_f16(af1, bf, acc[1][g], 0, 0, 0);
    }
  }
  const int j = j0 + lr;
#pragma unroll
  for (int mt = 0; mt < 2; ++mt) {
#pragma unroll
    for (int r = 0; r < 4; ++r) {
      int b = b0 + (w * 2 + mt) * 16 + (lane >> 4) * 4 + r;
      if (b < bs) {
        size_t prow = (size_t)(off + b);
        const f16* xr = xp + prow * XPLD + dir * G4 + slice * 64 + lr * 4;
        float Gi = acc[mt][0][r] + (float)xr[0] + bi[j];
        float Gf = acc[mt][1][r] + (float)xr[1] + bi[HID + j];
        float Gg = acc[mt][2][r] + (float)xr[2] + bi[2 * HID + j];
        float Go = acc[mt][3][r] + (float)xr[3] + bi[3 * HID + j];
        float ii = 1.f / (1.f + __expf(-Gi));
        float ff = 1.f / (1.f + __expf(-Gf));
        float gg = 1.f - 2.f / (__expf(2.f * Gg) + 1.f);
        float oo = 1.f / (1.f + __expf(-Go));
        float co = cp[b * HID + j];
        float cnew = ff * co + ii * gg;
        float hnew = oo * (1.f - 2.f / (__expf(2.f * cnew) + 1.f));
        cp[b * HID + j] = cnew;
        hp[b * HID + j] = hnew;
        hw[b * HLD + j] = (f16)hnew;
        if (outf32) outf32[prow * 800 + dir * HID + j] = hnew;
        else        outf16[prow * 800 + dir * HID + j] = (f16)hnew;
      }
    }
  }
}

// ---------------- host ----------------
extern "C" void kernel_launch(void* const* d_in, const int* in_sizes, int n_in,
                              void* d_out, int out_size, void* d_ws, size_t ws_size,
                              hipStream_t stream) {
  (void)in_sizes; (void)n_in; (void)out_size; (void)ws_size;
  const float* x   = (const float*)d_in[0];
  const float* Wih = (const float*)d_in[1];
  const float* Whh = (const float*)d_in[2];
  const float* bih = (const float*)d_in[3];
  const float* bhh = (const float*)d_in[4];
  float* out = (float*)d_out;

  long long bsv[128];
  {
    double step = (1.0 - 1024.0) / 127.0;
    for (int i = 0; i < 128; ++i) bsv[i] = (long long)floor((double)i * step + 1024.0);
    bsv[127] = 1; bsv[0] = 1024;
    long long sum = 0;
    for (int i = 0; i < 128; ++i) sum += bsv[i];
    long long diff = 65536 - sum;
    while (diff != 0) {
      if (diff > 0) {
        for (int jj = 1; jj < 128 && diff != 0; ++jj) {
          long long cap = bsv[jj - 1] - bsv[jj];
          long long add = cap < diff ? cap : diff;
          bsv[jj] += add; diff -= add;
        }
      } else {
        for (int jj = 127; jj >= 1 && diff != 0; --jj) {
          long long nxt = (jj + 1 < 128) ? bsv[jj + 1] : 1;
          long long room = bsv[jj] - nxt;
          long long sub = room < (-diff) ? room : (-diff);
          bsv[jj] -= sub; diff += sub;
        }
      }
    }
  }
  long long offv[128], a0 = 0;
  for (int i = 0; i < 128; ++i) { offv[i] = a0; a0 += bsv[i]; }

  char* p = (char*)d_ws;
  f16*      x16   = (f16*)(p);                 // 65536x400 f16 (+256B zero pad)
  f16*      wih16 = (f16*)(p + 52429056LL);    // 6x1600x800 f16, gate-permuted rows
  f16*      whh16 = (f16*)(p + 67789056LL);    // 6x1600x416 f16 (zero-padded K)
  float*    bias  = (float*)(p + 75776256LL);  // 6x1600 f32
  f16*      xproj = (f16*)(p + 75814656LL);    // (65536+128)x3200 f16
  unsigned* flags = (unsigned*)(p + 495654656LL);  // 3 layers x 16 groups x 25 x 128B
  f16*      layA  = (f16*)(p + 496064256LL);   // 65536x800 f16
  f16*      layB  = (f16*)(p + 600921856LL);   // 65536x800 f16
  f16*      h16   = (f16*)(p + 705779456LL);   // 2 dir x 2 pp x 1024x416 f16

  hipMemsetAsync(p + 52428800LL, 0, 256, stream);              // x16 K-pad
  hipMemsetAsync(out + 52428800LL, 0, 4915200LL * 4, stream);  // h_n + c_n
  hipMemsetAsync(flags, 0, 3 * 16 * 25 * 128, stream);         // all layer flags

  k_cvt_f16<<<2048, 256, 0, stream>>>(x, x16, 26214400LL);
  k_cvt_wih<<<2048, 256, 0, stream>>>(Wih, wih16);
  k_cvt_whh<<<2048, 256, 0, stream>>>(Whh, whh16, 9600);
  k_bias<<<40, 256, 0, stream>>>(bih, bhh, bias, 9600);

  int occ = 0;
  hipOccupancyMaxActiveBlocksPerMultiprocessor(&occ, k_rnn, 256, 0);
  const bool persistent = (occ >= 2);  // 2/CU x 256 CU = 512 >= 400 co-resident

  const long long OUTP = 52428800LL, HNSZ = 2457600LL;

  for (int L = 0; L < 3; ++L) {
    const f16* Ain = (L == 0) ? x16 : (L == 1 ? layA : layB);
    int lda = (L == 0) ? 400 : 800;
    int K   = (L == 0) ? 416 : 800;
    k_gemm<<<12800, 256, 0, stream>>>(Ain, wih16 + (size_t)(2 * L) * 1600 * 800,
                                      xproj, lda, K);
    hipMemsetAsync(h16, 0, 3407872LL, stream);
    float* hnL = out + OUTP + (size_t)(2 * L) * 409600;
    float* cnL = out + OUTP + HNSZ + (size_t)(2 * L) * 409600;
    f16* o16 = (L == 0) ? layA : (L == 1 ? layB : nullptr);
    float* o32 = (L == 2) ? out : nullptr;
    if (persistent) {
      k_rnn<<<RNN_BLOCKS, 256, 0, stream>>>(
          xproj, whh16 + (size_t)(2 * L) * 1600 * HLD, bias + (size_t)(2 * L) * 1600,
          h16, hnL, cnL, o16, o32, flags + (size_t)L * 16 * 25 * 32);
    } else {
      for (int s = 0; s < 128; ++s) {
        int tf = s, tb = 127 - s;
        int bsf = (int)bsv[tf], bsb = (int)bsv[tb];
        int nTf = (bsf + 127) / 128, nTb = (bsb + 127) / 128;
        k_step<<<25 * (nTf + nTb), 256, 0, stream>>>(
            xproj, whh16 + (size_t)(2 * L) * 1600 * HLD, bias + (size_t)(2 * L) * 1600,
            h16 + (size_t)(s & 1) * 1024 * HLD, h16 + (size_t)((s + 1) & 1) * 1024 * HLD,
            hnL, cnL, o16, o32,
            bsf, (int)offv[tf], bsb, (int)offv[tb], nTf);
      }
    }
  }
}

// Round 10
// 7899.812 us; speedup vs baseline: 1.0645x; 1.0006x over previous
//
#include <hip/hip_runtime.h>
#include <math.h>

using f16 = _Float16;
typedef __attribute__((ext_vector_type(8))) _Float16 f16x8;
typedef __attribute__((ext_vector_type(4))) _Float16 f16x4;
typedef __attribute__((ext_vector_type(4))) float f32x4;

#define T_STEPS 128
#define HID 400
#define G4 1600
#define XPLD 3200
#define HLD 416
#define WPAD 424
#define RNN_BLOCKS 400

__device__ __forceinline__ void gl_lds16(const void* g, void* l) {
  __builtin_amdgcn_global_load_lds((const __attribute__((address_space(1))) void*)g,
                                   (__attribute__((address_space(3))) void*)l, 16, 0, 0);
}

// cross-XCD-coherent ops: bypass L1+L2, hit the L3 coherence point
__device__ __forceinline__ f16x8 ld_cc(const f16* p) {
  f16x8 r;
  asm volatile("global_load_dwordx4 %0, %1, off sc0 sc1" : "=v"(r) : "v"(p));
  return r;  // caller must s_waitcnt vmcnt(0) + sched_barrier before use
}
__device__ __forceinline__ void st_cc2(f16* p, unsigned v) {
  asm volatile("global_store_short %0, %1, off sc0 sc1" :: "v"(p), "v"(v) : "memory");
}
__device__ __forceinline__ void st_cc4(unsigned* p, unsigned v) {
  asm volatile("global_store_dword %0, %1, off sc0 sc1" :: "v"(p), "v"(v) : "memory");
}
__device__ __forceinline__ unsigned ld_cc4(const unsigned* p) {
  unsigned v;
  asm volatile("global_load_dword %0, %1, off sc0 sc1\n\ts_waitcnt vmcnt(0)"
               : "=v"(v) : "v"(p) : "memory");
  return v;
}

// ---------------- conversion kernels ----------------
__global__ void k_cvt_f16(const float* __restrict__ s, f16* __restrict__ d, long long n) {
  long long i = ((long long)blockIdx.x * blockDim.x + threadIdx.x) * 4;
  long long stride = (long long)gridDim.x * blockDim.x * 4;
  for (; i < n; i += stride) {
    float4 v = *(const float4*)(s + i);
    f16x4 o = { (f16)v.x, (f16)v.y, (f16)v.z, (f16)v.w };
    *(f16x4*)(d + i) = o;
  }
}

// Wih f32 -> f16 with gate-interleave ROW permutation folded in:
// out row R = L*3200 + dirn*1600 + (j/16)*64 + (j%16)*4 + g  <-  in row (2L+dirn)*1600 + g*400 + j
__global__ void k_cvt_wih(const float* __restrict__ s, f16* __restrict__ d) {
  long long n4 = 9600LL * 200;  // 4 elems per iter
  for (long long i = (long long)blockIdx.x * blockDim.x + threadIdx.x; i < n4;
       i += (long long)gridDim.x * blockDim.x) {
    long long i4 = i * 4;
    int R = (int)(i4 / 800), c = (int)(i4 % 800);
    int L = R / 3200, rem = R % 3200;
    int dirn = rem / 1600, q = rem % 1600;
    int g = q & 3, jlo = (q >> 2) & 15, jhi = q >> 6;
    int inrow = (2 * L + dirn) * 1600 + g * HID + jhi * 16 + jlo;
    float4 v = *(const float4*)(s + (long long)inrow * 800 + c);
    f16x4 o = { (f16)v.x, (f16)v.y, (f16)v.z, (f16)v.w };
    *(f16x4*)(d + i4) = o;
  }
}

__global__ void k_cvt_whh(const float* __restrict__ s, f16* __restrict__ d, int nrows) {
  long long n = (long long)nrows * HLD;
  for (long long i = (long long)blockIdx.x * blockDim.x + threadIdx.x; i < n;
       i += (long long)gridDim.x * blockDim.x) {
    int row = (int)(i / HLD), c = (int)(i % HLD);
    d[i] = (c < HID) ? (f16)s[(long long)row * HID + c] : (f16)0.f;
  }
}

__global__ void k_bias(const float* __restrict__ a, const float* __restrict__ b,
                       float* __restrict__ d, int n) {
  for (int i = blockIdx.x * blockDim.x + threadIdx.x; i < n; i += gridDim.x * blockDim.x)
    d[i] = a[i] + b[i];
}

// ---------------- input-projection GEMM (3-buffer counted-vmcnt pipeline, T4) ----------------
// C[m][n] = sum_k A[m][k]*Bw[n][k]; 128x128 tile, BK=32.
// Pipeline: 2 K-tiles of gl_lds stay in flight; per iter: s_waitcnt vmcnt(4)
// (current buffer's 4 loads done, next buffer's 4 still flying) -> raw s_barrier ->
// ds_read(cur) -> STAGE(kt+2 into 3rd buffer) -> MFMA. vmcnt never drains to 0
// in the loop (HK/AITER pattern). Overwrite safety: buffer (kt+2)%3 was last
// read at iter kt-1; every wave's reads completed before its kt-1 MFMA, which
// precedes barrier kt; STAGE is issued after barrier kt.
__global__ __launch_bounds__(256) void k_gemm(const f16* __restrict__ A,
                                              const f16* __restrict__ Bw,
                                              f16* __restrict__ C, int lda, int K) {
  __shared__ f16 As[3][128 * 32];
  __shared__ f16 Bs[3][128 * 32];
  const int tid = threadIdx.x;
  const int lane = tid & 63, w = tid >> 6;
  const int wm = w >> 1, wn = w & 1;
  const int wg = blockIdx.x;
  const int swz = (wg & 7) * 1600 + (wg >> 3);  // bijective XCD swizzle (12800%8==0)
  const int bn = (swz % 25) * 128;
  const long long bm = (long long)(swz / 25) * 128;

  // staging: lane l -> row l>>2, stored-chunk l&3 holds global chunk (l&3)^((l>>3)&3)
  const int kc = ((lane & 3) ^ ((lane >> 3) & 3)) * 8;
  const f16* gA = A + (bm + w * 16 + (lane >> 2)) * (long long)lda + kc;
  const f16* gB = Bw + (long long)(bn + w * 16 + (lane >> 2)) * 800 + kc;

  const int lr = lane & 15;
  const int kswz = (((lane >> 4) ^ ((lr >> 1) & 3)) << 3);
  const int nk = K / 32;

  f32x4 acc[4][4] = {};

#define STAGE(bb, k0)                                            \
  do {                                                           \
    gl_lds16(gA + (k0), &As[bb][w * 512]);                       \
    gl_lds16(gA + 64LL * lda + (k0), &As[bb][64 * 32 + w * 512]); \
    gl_lds16(gB + (k0), &Bs[bb][w * 512]);                       \
    gl_lds16(gB + 64LL * 800 + (k0), &Bs[bb][64 * 32 + w * 512]); \
  } while (0)

  STAGE(0, 0);
  STAGE(1, 32);
  int cur = 0;
  for (int kt = 0; kt < nk; ++kt) {
    if (kt + 1 < nk) asm volatile("s_waitcnt vmcnt(4)" ::: "memory");
    else             asm volatile("s_waitcnt vmcnt(0)" ::: "memory");
    __builtin_amdgcn_s_barrier();   // raw: no implicit drain of in-flight next tile
    f16x8 af[4], bf[4];
#pragma unroll
    for (int mt = 0; mt < 4; ++mt)
      af[mt] = *(const f16x8*)&As[cur][(wm * 64 + mt * 16 + lr) * 32 + kswz];
#pragma unroll
    for (int nt = 0; nt < 4; ++nt)
      bf[nt] = *(const f16x8*)&Bs[cur][(wn * 64 + nt * 16 + lr) * 32 + kswz];
    if (kt + 2 < nk) {
      int nb = cur + 2; if (nb >= 3) nb -= 3;
      STAGE(nb, (kt + 2) * 32);
    }
#pragma unroll
    for (int mt = 0; mt < 4; ++mt)
#pragma unroll
      for (int nt = 0; nt < 4; ++nt)
        acc[mt][nt] = __builtin_amdgcn_mfma_f32_16x16x32_f16(af[mt], bf[nt], acc[mt][nt], 0, 0, 0);
    ++cur; if (cur >= 3) cur -= 3;
  }
#undef STAGE

#pragma unroll
  for (int mt = 0; mt < 4; ++mt) {
#pragma unroll
    for (int nt = 0; nt < 4; ++nt) {
      long long gm = bm + wm * 64 + mt * 16 + ((lane >> 4) * 4);
      int gn = bn + wn * 64 + nt * 16 + lr;  // linear, coalesced
#pragma unroll
      for (int r = 0; r < 4; ++r)
        C[(gm + r) * XPLD + gn] = (f16)acc[mt][nt][r];
    }
  }
}

// ---------------- persistent recurrence (round-7/9 config: 400 blocks, 25 slices) ----------------
__global__ __launch_bounds__(256, 2) void k_rnn(
    const f16* __restrict__ xp, const f16* __restrict__ whh,
    const float* __restrict__ bias2, f16* __restrict__ h16,
    float* __restrict__ hn, float* __restrict__ cn,
    f16* __restrict__ outf16, float* __restrict__ outf32,
    unsigned* __restrict__ flags) {
  __shared__ f16 Wl[64 * WPAD];
  __shared__ int bsT[T_STEPS], offT[T_STEPS];

  const int tid = threadIdx.x;
  const int slice = blockIdx.x % 25;
  const int q = blockIdx.x / 25;  // 0..15 : dir*8 + bt
  const int dir = q >> 3, bt = q & 7;
  const int lane = tid & 63, w = tid >> 6;
  const int lr = lane & 15, kreg = (lane >> 4) * 8;
  const int qr4 = (lane >> 4) * 4;
  const int j0 = slice * 16;
  const int j = j0 + lr;
  unsigned* gflag = flags + (size_t)q * (25 * 32);
  unsigned* myflag = gflag + slice * 32;
  const unsigned* peer = gflag + (lane < 25 ? lane : 0) * 32;

  if (tid == 0) {
    double step = (1.0 - 1024.0) / 127.0;
    for (int i = 0; i < T_STEPS; ++i) bsT[i] = (int)floor((double)i * step + 1024.0);
    bsT[127] = 1; bsT[0] = 1024;
    int sum = 0;
    for (int i = 0; i < T_STEPS; ++i) sum += bsT[i];
    int diff = 65536 - sum;
    while (diff != 0) {
      if (diff > 0) {
        for (int jj = 1; jj < T_STEPS && diff != 0; ++jj) {
          int cap = bsT[jj - 1] - bsT[jj];
          int add = cap < diff ? cap : diff;
          bsT[jj] += add; diff -= add;
        }
      } else {
        for (int jj = T_STEPS - 1; jj >= 1 && diff != 0; --jj) {
          int nxt = (jj + 1 < T_STEPS) ? bsT[jj + 1] : 1;
          int room = bsT[jj] - nxt;
          int sub = room < (-diff) ? room : (-diff);
          bsT[jj] -= sub; diff += sub;
        }
      }
    }
    int a0 = 0;
    for (int i = 0; i < T_STEPS; ++i) { offT[i] = a0; a0 += bsT[i]; }
  }

  // W slice -> LDS (64 rows = 4 gates x 16 j; 416 cols padded to 424)
  const f16* whhD = whh + (size_t)dir * (G4 * HLD);
  {
    int rr = tid >> 2, seg = tid & 3;
    int g = rr >> 4, jr = rr & 15;
    const f16* src = whhD + (size_t)(g * HID + j0 + jr) * HLD + seg * 104;
    f16* dst = &Wl[rr * WPAD + seg * 104];
#pragma unroll
    for (int kk = 0; kk < 13; ++kk)
      *(f16x8*)(dst + kk * 8) = *(const f16x8*)(src + kk * 8);
  }
  const float* biD = bias2 + dir * G4;
  const float bi0 = biD[j], bi1 = biD[HID + j], bi2 = biD[2 * HID + j], bi3 = biD[3 * HID + j];
  float* hp = hn + (size_t)dir * (1024 * HID);
  float* cp = cn + (size_t)dir * (1024 * HID);
  __syncthreads();

  int s_begin = 0;
  if (dir) {  // backward: tile inactive until bs grows past it (h rows still 0)
    while (s_begin < T_STEPS && bsT[T_STEPS - 1 - s_begin] <= bt * 128) ++s_begin;
  }
  const int rowb = bt * 128 + w * 32;
  float ch[2][4] = {{0.f, 0.f, 0.f, 0.f}, {0.f, 0.f, 0.f, 0.f}};

  // initial x prefetch (step s_begin), guarded by bs
  f16x4 xgA[2][4], xgB[2][4];
  {
    int tt = dir ? (T_STEPS - 1 - s_begin) : s_begin;
    int bs0 = bsT[tt], off0 = offT[tt];
#pragma unroll
    for (int mt = 0; mt < 2; ++mt)
#pragma unroll
      for (int r = 0; r < 4; ++r) {
        int b = rowb + mt * 16 + qr4 + r;
        if (b < bs0)
          xgA[mt][r] = *(const f16x4*)(xp + (size_t)(off0 + b) * XPLD
                                       + dir * G4 + slice * 64 + lr * 4);
      }
  }

#pragma unroll 1
  for (int s = s_begin; s < T_STEPS; ++s) {
    const int t = dir ? (T_STEPS - 1 - s) : s;
    const int bs = bsT[t], off = offT[t];
    const bool lastStep = (s == T_STEPS - 1) || (!dir && bsT[s + 1] <= bt * 128);

    // prefetch NEXT step's x (2-deep pipeline; guarded by next bs)
    if (!lastStep) {
      int tn = dir ? (T_STEPS - 2 - s) : (s + 1);
      int bsn = bsT[tn], offn = offT[tn];
#pragma unroll
      for (int mt = 0; mt < 2; ++mt)
#pragma unroll
        for (int r = 0; r < 4; ++r) {
          int b = rowb + mt * 16 + qr4 + r;
          if (b < bsn)
            xgB[mt][r] = *(const f16x4*)(xp + (size_t)(offn + b) * XPLD
                                         + dir * G4 + slice * 64 + lr * 4);
        }
    }

    // wait: all 25 peer blocks completed step s-1
    if (s > s_begin) {
      if (w == 0) {
        while (true) {
          unsigned vv = ld_cc4(peer);
          if (!__ballot((lane < 25) && (vv < (unsigned)s))) break;
          __builtin_amdgcn_s_sleep(1);
        }
      }
      __syncthreads();
    }

    const int cur = s & 1;
    const f16* hr = h16 + (size_t)((dir << 1) | cur) * (1024 * HLD);
    f16* hww = h16 + (size_t)((dir << 1) | (cur ^ 1)) * (1024 * HLD);

    const f16* ha = hr + (size_t)(rowb + lr) * HLD + kreg;
    f16x8 hfa[13], hfb[13];
#pragma unroll
    for (int kk = 0; kk < 13; ++kk) {
      hfa[kk] = ld_cc(ha + kk * 32);
      hfb[kk] = ld_cc(ha + 16 * HLD + kk * 32);
    }
    asm volatile("s_waitcnt vmcnt(0)" ::: "memory");
    __builtin_amdgcn_sched_barrier(0);

    f32x4 acc[2][4] = {};
#pragma unroll
    for (int kk = 0; kk < 13; ++kk) {
#pragma unroll
      for (int g = 0; g < 4; ++g) {
        f16x8 bf = *(const f16x8*)&Wl[(g * 16 + lr) * WPAD + kk * 32 + kreg];
        acc[0][g] = __builtin_amdgcn_mfma_f32_16x16x32_f16(hfa[kk], bf, acc[0][g], 0, 0, 0);
        acc[1][g] = __builtin_amdgcn_mfma_f32_16x16x32_f16(hfb[kk], bf, acc[1][g], 0, 0, 0);
      }
    }

    float hnw[2][4];
    f16 hv16[2][4];
#pragma unroll
    for (int mt = 0; mt < 2; ++mt) {
#pragma unroll
      for (int r = 0; r < 4; ++r) {
        int b = rowb + mt * 16 + qr4 + r;
        if (b < bs) {
          float Gi = acc[mt][0][r] + (float)xgA[mt][r][0] + bi0;
          float Gf = acc[mt][1][r] + (float)xgA[mt][r][1] + bi1;
          float Gg = acc[mt][2][r] + (float)xgA[mt][r][2] + bi2;
          float Go = acc[mt][3][r] + (float)xgA[mt][r][3] + bi3;
          float ii = 1.f / (1.f + __expf(-Gi));
          float ff = 1.f / (1.f + __expf(-Gf));
          float gg = 1.f - 2.f / (__expf(2.f * Gg) + 1.f);
          float oo = 1.f / (1.f + __expf(-Go));
          float cnew = ff * ch[mt][r] + ii * gg;
          ch[mt][r] = cnew;
          float hnew = oo * (1.f - 2.f / (__expf(2.f * cnew) + 1.f));
          union { f16 f; unsigned short u; } cv; cv.f = (f16)hnew;
          st_cc2(&hww[(size_t)b * HLD + j], (unsigned)cv.u);
          hnw[mt][r] = hnew;
          hv16[mt][r] = cv.f;
        }
      }
    }

    if (!lastStep) {
      __syncthreads();                                 // implicit vmcnt(0): h ACKed at L3
      if (tid == 0) st_cc4(myflag, (unsigned)(s + 1)); // publish AFTER h visible
    }

    // deferred outputs (overlap next step's prefetch/spin)
#pragma unroll
    for (int mt = 0; mt < 2; ++mt) {
#pragma unroll
      for (int r = 0; r < 4; ++r) {
        int b = rowb + mt * 16 + qr4 + r;
        if (b < bs) {
          size_t prow = (size_t)(off + b);
          if (outf32) outf32[prow * 800 + dir * HID + j] = hnw[mt][r];
          else        outf16[prow * 800 + dir * HID + j] = hv16[mt][r];
          bool lastv = dir ? (s == T_STEPS - 1)
                           : (s == T_STEPS - 1 || bsT[s + 1] <= b);
          if (lastv) {
            cp[(size_t)b * HID + j] = ch[mt][r];
            hp[(size_t)b * HID + j] = hnw[mt][r];
          }
        }
      }
    }
    if (lastStep) break;
    // rotate x pipeline
#pragma unroll
    for (int mt = 0; mt < 2; ++mt)
#pragma unroll
      for (int r = 0; r < 4; ++r) xgA[mt][r] = xgB[mt][r];
  }
}

// ---------------- fallback per-step kernel (matches xproj gate layout) ----------------
__global__ __launch_bounds__(256) void k_step(
    const f16* __restrict__ xp, const f16* __restrict__ whh,
    const float* __restrict__ bias2, const f16* __restrict__ h16r0,
    f16* __restrict__ h16w0, float* __restrict__ hn, float* __restrict__ cn,
    f16* __restrict__ outf16, float* __restrict__ outf32,
    int bs_f, int off_f, int bs_b, int off_b, int nTf) {
  const int slice = blockIdx.x % 25;
  const int tl = blockIdx.x / 25;
  int dir, bt, bs, off;
  if (tl < nTf) { dir = 0; bt = tl; bs = bs_f; off = off_f; }
  else          { dir = 1; bt = tl - nTf; bs = bs_b; off = off_b; }
  const int lane = threadIdx.x & 63, w = threadIdx.x >> 6;
  const int lr = lane & 15, kreg = (lane >> 4) * 8;
  const int b0 = bt * 128;
  const int j0 = slice * 16;
  const f16* hr = h16r0 + (size_t)dir * (2 * 1024 * HLD);
  f16* hw = h16w0 + (size_t)dir * (2 * 1024 * HLD);
  const f16* W = whh + (size_t)dir * (G4 * HLD);
  const float* bi = bias2 + dir * G4;
  float* hp = hn + (size_t)dir * (1024 * HID);
  float* cp = cn + (size_t)dir * (1024 * HID);

  f32x4 acc[2][4] = {};
  for (int k0 = 0; k0 < HLD; k0 += 32) {
    f16x8 af0 = *(const f16x8*)&hr[(b0 + (w * 2 + 0) * 16 + lr) * HLD + k0 + kreg];
    f16x8 af1 = *(const f16x8*)&hr[(b0 + (w * 2 + 1) * 16 + lr) * HLD + k0 + kreg];
#pragma unroll
    for (int g = 0; g < 4; ++g) {
      f16x8 bf = *(const f16x8*)&W[(g * HID + j0 + lr) * HLD + k0 + kreg];
      acc[0][g] = __builtin_amdgcn_mfma_f32_16x16x32_f16(af0, bf, acc[0][g], 0, 0, 0);
      acc[1][g] = __builtin_amdgcn_mfma_f32_16x16x32_f16(af1, bf, acc[1][g], 0, 0, 0);
    }
  }
  const int j = j0 + lr;
#pragma unroll
  for (int mt = 0; mt < 2; ++mt) {
#pragma unroll
    for (int r = 0; r < 4; ++r) {
      int b = b0 + (w * 2 + mt) * 16 + (lane >> 4) * 4 + r;
      if (b < bs) {
        size_t prow = (size_t)(off + b);
        const f16* xr = xp + prow * XPLD + dir * G4 + slice * 64 + lr * 4;
        float Gi = acc[mt][0][r] + (float)xr[0] + bi[j];
        float Gf = acc[mt][1][r] + (float)xr[1] + bi[HID + j];
        float Gg = acc[mt][2][r] + (float)xr[2] + bi[2 * HID + j];
        float Go = acc[mt][3][r] + (float)xr[3] + bi[3 * HID + j];
        float ii = 1.f / (1.f + __expf(-Gi));
        float ff = 1.f / (1.f + __expf(-Gf));
        float gg = 1.f - 2.f / (__expf(2.f * Gg) + 1.f);
        float oo = 1.f / (1.f + __expf(-Go));
        float co = cp[b * HID + j];
        float cnew = ff * co + ii * gg;
        float hnew = oo * (1.f - 2.f / (__expf(2.f * cnew) + 1.f));
        cp[b * HID + j] = cnew;
        hp[b * HID + j] = hnew;
        hw[b * HLD + j] = (f16)hnew;
        if (outf32) outf32[prow * 800 + dir * HID + j] = hnew;
        else        outf16[prow * 800 + dir * HID + j] = (f16)hnew;
      }
    }
  }
}

// ---------------- host ----------------
extern "C" void kernel_launch(void* const* d_in, const int* in_sizes, int n_in,
                              void* d_out, int out_size, void* d_ws, size_t ws_size,
                              hipStream_t stream) {
  (void)in_sizes; (void)n_in; (void)out_size; (void)ws_size;
  const float* x   = (const float*)d_in[0];
  const float* Wih = (const float*)d_in[1];
  const float* Whh = (const float*)d_in[2];
  const float* bih = (const float*)d_in[3];
  const float* bhh = (const float*)d_in[4];
  float* out = (float*)d_out;

  long long bsv[128];
  {
    double step = (1.0 - 1024.0) / 127.0;
    for (int i = 0; i < 128; ++i) bsv[i] = (long long)floor((double)i * step + 1024.0);
    bsv[127] = 1; bsv[0] = 1024;
    long long sum = 0;
    for (int i = 0; i < 128; ++i) sum += bsv[i];
    long long diff = 65536 - sum;
    while (diff != 0) {
      if (diff > 0) {
        for (int jj = 1; jj < 128 && diff != 0; ++jj) {
          long long cap = bsv[jj - 1] - bsv[jj];
          long long add = cap < diff ? cap : diff;
          bsv[jj] += add; diff -= add;
        }
      } else {
        for (int jj = 127; jj >= 1 && diff != 0; --jj) {
          long long nxt = (jj + 1 < 128) ? bsv[jj + 1] : 1;
          long long room = bsv[jj] - nxt;
          long long sub = room < (-diff) ? room : (-diff);
          bsv[jj] -= sub; diff += sub;
        }
      }
    }
  }
  long long offv[128], a0 = 0;
  for (int i = 0; i < 128; ++i) { offv[i] = a0; a0 += bsv[i]; }

  char* p = (char*)d_ws;
  f16*      x16   = (f16*)(p);                 // 65536x400 f16 (+256B zero pad)
  f16*      wih16 = (f16*)(p + 52429056LL);    // 6x1600x800 f16, gate-permuted rows
  f16*      whh16 = (f16*)(p + 67789056LL);    // 6x1600x416 f16 (zero-padded K)
  float*    bias  = (float*)(p + 75776256LL);  // 6x1600 f32
  f16*      xproj = (f16*)(p + 75814656LL);    // (65536+128)x3200 f16
  unsigned* flags = (unsigned*)(p + 495654656LL);  // 3 layers x 16 groups x 25 x 128B
  f16*      layA  = (f16*)(p + 496064256LL);   // 65536x800 f16
  f16*      layB  = (f16*)(p + 600921856LL);   // 65536x800 f16
  f16*      h16   = (f16*)(p + 705779456LL);   // 2 dir x 2 pp x 1024x416 f16

  hipMemsetAsync(p + 52428800LL, 0, 256, stream);              // x16 K-pad
  hipMemsetAsync(out + 52428800LL, 0, 4915200LL * 4, stream);  // h_n + c_n
  hipMemsetAsync(flags, 0, 3 * 16 * 25 * 128, stream);         // all layer flags

  k_cvt_f16<<<2048, 256, 0, stream>>>(x, x16, 26214400LL);
  k_cvt_wih<<<2048, 256, 0, stream>>>(Wih, wih16);
  k_cvt_whh<<<2048, 256, 0, stream>>>(Whh, whh16, 9600);
  k_bias<<<40, 256, 0, stream>>>(bih, bhh, bias, 9600);

  int occ = 0;
  hipOccupancyMaxActiveBlocksPerMultiprocessor(&occ, k_rnn, 256, 0);
  const bool persistent = (occ >= 2);  // 2/CU x 256 CU = 512 >= 400 co-resident

  const long long OUTP = 52428800LL, HNSZ = 2457600LL;

  for (int L = 0; L < 3; ++L) {
    const f16* Ain = (L == 0) ? x16 : (L == 1 ? layA : layB);
    int lda = (L == 0) ? 400 : 800;
    int K   = (L == 0) ? 416 : 800;
    k_gemm<<<12800, 256, 0, stream>>>(Ain, wih16 + (size_t)(2 * L) * 1600 * 800,
                                      xproj, lda, K);
    hipMemsetAsync(h16, 0, 3407872LL, stream);
    float* hnL = out + OUTP + (size_t)(2 * L) * 409600;
    float* cnL = out + OUTP + HNSZ + (size_t)(2 * L) * 409600;
    f16* o16 = (L == 0) ? layA : (L == 1 ? layB : nullptr);
    float* o32 = (L == 2) ? out : nullptr;
    if (persistent) {
      k_rnn<<<RNN_BLOCKS, 256, 0, stream>>>(
          xproj, whh16 + (size_t)(2 * L) * 1600 * HLD, bias + (size_t)(2 * L) * 1600,
          h16, hnL, cnL, o16, o32, flags + (size_t)L * 16 * 25 * 32);
    } else {
      for (int s = 0; s < 128; ++s) {
        int tf = s, tb = 127 - s;
        int bsf = (int)bsv[tf], bsb = (int)bsv[tb];
        int nTf = (bsf + 127) / 128, nTb = (bsb + 127) / 128;
        k_step<<<25 * (nTf + nTb), 256, 0, stream>>>(
            xproj, whh16 + (size_t)(2 * L) * 1600 * HLD, bias + (size_t)(2 * L) * 1600,
            h16 + (size_t)(s & 1) * 1024 * HLD, h16 + (size_t)((s + 1) & 1) * 1024 * HLD,
            hnL, cnL, o16, o32,
            bsf, (int)offv[tf], bsb, (int)offv[tb], nTf);
      }
    }
  }
}

// Round 11
// 7682.903 us; speedup vs baseline: 1.0946x; 1.0282x over previous
//
#include <hip/hip_runtime.h>
#include <math.h>

using f16 = _Float16;
typedef __attribute__((ext_vector_type(8))) _Float16 f16x8;
typedef __attribute__((ext_vector_type(4))) _Float16 f16x4;
typedef __attribute__((ext_vector_type(4))) float f32x4;

#define T_STEPS 128
#define HID 400
#define G4 1600
#define XPLD 3200
#define HLD 416
#define WPAD 424
#define RNN_BLOCKS 400

__device__ __forceinline__ void gl_lds16(const void* g, void* l) {
  __builtin_amdgcn_global_load_lds((const __attribute__((address_space(1))) void*)g,
                                   (__attribute__((address_space(3))) void*)l, 16, 0, 0);
}

// cross-XCD-coherent ops: bypass L1+L2, hit the L3 coherence point
__device__ __forceinline__ f16x8 ld_cc(const f16* p) {
  f16x8 r;
  asm volatile("global_load_dwordx4 %0, %1, off sc0 sc1" : "=v"(r) : "v"(p));
  return r;  // caller must s_waitcnt vmcnt(0) + sched_barrier before use
}
__device__ __forceinline__ void st_cc2(f16* p, unsigned v) {
  asm volatile("global_store_short %0, %1, off sc0 sc1" :: "v"(p), "v"(v) : "memory");
}
__device__ __forceinline__ void st_cc4(unsigned* p, unsigned v) {
  asm volatile("global_store_dword %0, %1, off sc0 sc1" :: "v"(p), "v"(v) : "memory");
}
__device__ __forceinline__ unsigned ld_cc4(const unsigned* p) {
  unsigned v;
  asm volatile("global_load_dword %0, %1, off sc0 sc1\n\ts_waitcnt vmcnt(0)"
               : "=v"(v) : "v"(p) : "memory");
  return v;
}

// ---------------- conversion kernels ----------------
__global__ void k_cvt_f16(const float* __restrict__ s, f16* __restrict__ d, long long n) {
  long long i = ((long long)blockIdx.x * blockDim.x + threadIdx.x) * 4;
  long long stride = (long long)gridDim.x * blockDim.x * 4;
  for (; i < n; i += stride) {
    float4 v = *(const float4*)(s + i);
    f16x4 o = { (f16)v.x, (f16)v.y, (f16)v.z, (f16)v.w };
    *(f16x4*)(d + i) = o;
  }
}

// Wih f32 -> f16 with gate-interleave ROW permutation folded in:
// out row R = L*3200 + dirn*1600 + (j/16)*64 + (j%16)*4 + g  <-  in row (2L+dirn)*1600 + g*400 + j
__global__ void k_cvt_wih(const float* __restrict__ s, f16* __restrict__ d) {
  long long n4 = 9600LL * 200;  // 4 elems per iter
  for (long long i = (long long)blockIdx.x * blockDim.x + threadIdx.x; i < n4;
       i += (long long)gridDim.x * blockDim.x) {
    long long i4 = i * 4;
    int R = (int)(i4 / 800), c = (int)(i4 % 800);
    int L = R / 3200, rem = R % 3200;
    int dirn = rem / 1600, q = rem % 1600;
    int g = q & 3, jlo = (q >> 2) & 15, jhi = q >> 6;
    int inrow = (2 * L + dirn) * 1600 + g * HID + jhi * 16 + jlo;
    float4 v = *(const float4*)(s + (long long)inrow * 800 + c);
    f16x4 o = { (f16)v.x, (f16)v.y, (f16)v.z, (f16)v.w };
    *(f16x4*)(d + i4) = o;
  }
}

__global__ void k_cvt_whh(const float* __restrict__ s, f16* __restrict__ d, int nrows) {
  long long n = (long long)nrows * HLD;
  for (long long i = (long long)blockIdx.x * blockDim.x + threadIdx.x; i < n;
       i += (long long)gridDim.x * blockDim.x) {
    int row = (int)(i / HLD), c = (int)(i % HLD);
    d[i] = (c < HID) ? (f16)s[(long long)row * HID + c] : (f16)0.f;
  }
}

__global__ void k_bias(const float* __restrict__ a, const float* __restrict__ b,
                       float* __restrict__ d, int n) {
  for (int i = blockIdx.x * blockDim.x + threadIdx.x; i < n; i += gridDim.x * blockDim.x)
    d[i] = a[i] + b[i];
}

// ---------------- input-projection GEMM (256x128 tile, 8 waves, 3-buf T4) ----------------
// C[m][n] = sum_k A[m][k]*Bw[n][k]; BK=32. 32 MFMA per barrier (2x the 128^2 tile).
// 3-buffer counted-vmcnt: per iter s_waitcnt vmcnt(3) (current tile's 3 staging
// loads done, next tile's 3 in flight) -> raw s_barrier -> ds_read -> STAGE(kt+2)
// -> MFMA. vmcnt never drains to 0 in-loop. Chunk-XOR LDS swizzle (source-side +
// read-side, rule 21) keeps ds_read_b128 conflict-free.
__global__ __launch_bounds__(512) void k_gemm(const f16* __restrict__ A,
                                              const f16* __restrict__ Bw,
                                              f16* __restrict__ C, int lda, int K) {
  __shared__ f16 As[3][256 * 32];
  __shared__ f16 Bs[3][128 * 32];
  const int tid = threadIdx.x;
  const int lane = tid & 63, v = tid >> 6;  // 8 waves
  const int wm = v >> 1, wn = v & 1;        // 4 x 2 quadrants of 64x64
  const int wg = blockIdx.x;
  const int swz = (wg & 7) * 800 + (wg >> 3);  // bijective XCD swizzle (6400%8==0)
  const int bn = (swz % 25) * 128;
  const long long bm = (long long)(swz / 25) * 256;

  // staging: chunk id ca = v*64+lane; row ca>>2; stored-chunk ca&3 holds global
  // chunk (ca&3)^((ca>>3)&3)  (v*8 = 0 mod 4, so per-lane formula is wave-invariant)
  const int kc = ((lane & 3) ^ ((lane >> 3) & 3)) * 8;
  const int srow = (v * 64 + lane) >> 2;
  const f16* gA0 = A + (bm + srow) * (long long)lda + kc;
  const f16* gA1 = A + (bm + 128 + srow) * (long long)lda + kc;
  const f16* gB0 = Bw + (long long)(bn + srow) * 800 + kc;

  const int lr = lane & 15;
  const int kswz = (((lane >> 4) ^ ((lr >> 1) & 3)) << 3);
  const int nk = K / 32;

  f32x4 acc[4][4] = {};

#define STAGE(bb, k0)                              \
  do {                                             \
    gl_lds16(gA0 + (k0), &As[bb][v * 512]);        \
    gl_lds16(gA1 + (k0), &As[bb][4096 + v * 512]); \
    gl_lds16(gB0 + (k0), &Bs[bb][v * 512]);        \
  } while (0)

  STAGE(0, 0);
  STAGE(1, 32);
  int cur = 0;
  for (int kt = 0; kt < nk; ++kt) {
    if (kt + 1 < nk) asm volatile("s_waitcnt vmcnt(3)" ::: "memory");
    else             asm volatile("s_waitcnt vmcnt(0)" ::: "memory");
    __builtin_amdgcn_s_barrier();   // raw: in-flight next-tile loads stay queued
    f16x8 af[4], bf[4];
#pragma unroll
    for (int mt = 0; mt < 4; ++mt)
      af[mt] = *(const f16x8*)&As[cur][(wm * 64 + mt * 16 + lr) * 32 + kswz];
#pragma unroll
    for (int nt = 0; nt < 4; ++nt)
      bf[nt] = *(const f16x8*)&Bs[cur][(wn * 64 + nt * 16 + lr) * 32 + kswz];
    if (kt + 2 < nk) {
      int nb = cur + 2; if (nb >= 3) nb -= 3;
      STAGE(nb, (kt + 2) * 32);
    }
#pragma unroll
    for (int mt = 0; mt < 4; ++mt)
#pragma unroll
      for (int nt = 0; nt < 4; ++nt)
        acc[mt][nt] = __builtin_amdgcn_mfma_f32_16x16x32_f16(af[mt], bf[nt], acc[mt][nt], 0, 0, 0);
    ++cur; if (cur >= 3) cur -= 3;
  }
#undef STAGE

#pragma unroll
  for (int mt = 0; mt < 4; ++mt) {
#pragma unroll
    for (int nt = 0; nt < 4; ++nt) {
      long long gm = bm + wm * 64 + mt * 16 + ((lane >> 4) * 4);
      int gn = bn + wn * 64 + nt * 16 + lr;  // linear, coalesced
#pragma unroll
      for (int r = 0; r < 4; ++r)
        C[(gm + r) * XPLD + gn] = (f16)acc[mt][nt][r];
    }
  }
}

// ---------------- persistent recurrence (400 blocks, 25 slices; all-wave poll) ----------------
__global__ __launch_bounds__(256, 2) void k_rnn(
    const f16* __restrict__ xp, const f16* __restrict__ whh,
    const float* __restrict__ bias2, f16* __restrict__ h16,
    float* __restrict__ hn, float* __restrict__ cn,
    f16* __restrict__ outf16, float* __restrict__ outf32,
    unsigned* __restrict__ flags) {
  __shared__ f16 Wl[64 * WPAD];
  __shared__ int bsT[T_STEPS], offT[T_STEPS];

  const int tid = threadIdx.x;
  const int slice = blockIdx.x % 25;
  const int q = blockIdx.x / 25;  // 0..15 : dir*8 + bt
  const int dir = q >> 3, bt = q & 7;
  const int lane = tid & 63, w = tid >> 6;
  const int lr = lane & 15, kreg = (lane >> 4) * 8;
  const int qr4 = (lane >> 4) * 4;
  const int j0 = slice * 16;
  const int j = j0 + lr;
  unsigned* gflag = flags + (size_t)q * (25 * 32);
  unsigned* myflag = gflag + slice * 32;
  const unsigned* peer = gflag + (lane < 25 ? lane : 0) * 32;

  if (tid == 0) {
    double step = (1.0 - 1024.0) / 127.0;
    for (int i = 0; i < T_STEPS; ++i) bsT[i] = (int)floor((double)i * step + 1024.0);
    bsT[127] = 1; bsT[0] = 1024;
    int sum = 0;
    for (int i = 0; i < T_STEPS; ++i) sum += bsT[i];
    int diff = 65536 - sum;
    while (diff != 0) {
      if (diff > 0) {
        for (int jj = 1; jj < T_STEPS && diff != 0; ++jj) {
          int cap = bsT[jj - 1] - bsT[jj];
          int add = cap < diff ? cap : diff;
          bsT[jj] += add; diff -= add;
        }
      } else {
        for (int jj = T_STEPS - 1; jj >= 1 && diff != 0; --jj) {
          int nxt = (jj + 1 < T_STEPS) ? bsT[jj + 1] : 1;
          int room = bsT[jj] - nxt;
          int sub = room < (-diff) ? room : (-diff);
          bsT[jj] -= sub; diff += sub;
        }
      }
    }
    int a0 = 0;
    for (int i = 0; i < T_STEPS; ++i) { offT[i] = a0; a0 += bsT[i]; }
  }

  // W slice -> LDS (64 rows = 4 gates x 16 j; 416 cols padded to 424)
  const f16* whhD = whh + (size_t)dir * (G4 * HLD);
  {
    int rr = tid >> 2, seg = tid & 3;
    int g = rr >> 4, jr = rr & 15;
    const f16* src = whhD + (size_t)(g * HID + j0 + jr) * HLD + seg * 104;
    f16* dst = &Wl[rr * WPAD + seg * 104];
#pragma unroll
    for (int kk = 0; kk < 13; ++kk)
      *(f16x8*)(dst + kk * 8) = *(const f16x8*)(src + kk * 8);
  }
  const float* biD = bias2 + dir * G4;
  const float bi0 = biD[j], bi1 = biD[HID + j], bi2 = biD[2 * HID + j], bi3 = biD[3 * HID + j];
  float* hp = hn + (size_t)dir * (1024 * HID);
  float* cp = cn + (size_t)dir * (1024 * HID);
  __syncthreads();

  int s_begin = 0;
  if (dir) {  // backward: tile inactive until bs grows past it (h rows still 0)
    while (s_begin < T_STEPS && bsT[T_STEPS - 1 - s_begin] <= bt * 128) ++s_begin;
  }
  const int rowb = bt * 128 + w * 32;
  float ch[2][4] = {{0.f, 0.f, 0.f, 0.f}, {0.f, 0.f, 0.f, 0.f}};

  // initial x prefetch (step s_begin), guarded by bs
  f16x4 xgA[2][4], xgB[2][4];
  {
    int tt = dir ? (T_STEPS - 1 - s_begin) : s_begin;
    int bs0 = bsT[tt], off0 = offT[tt];
#pragma unroll
    for (int mt = 0; mt < 2; ++mt)
#pragma unroll
      for (int r = 0; r < 4; ++r) {
        int b = rowb + mt * 16 + qr4 + r;
        if (b < bs0)
          xgA[mt][r] = *(const f16x4*)(xp + (size_t)(off0 + b) * XPLD
                                       + dir * G4 + slice * 64 + lr * 4);
      }
  }

#pragma unroll 1
  for (int s = s_begin; s < T_STEPS; ++s) {
    const int t = dir ? (T_STEPS - 1 - s) : s;
    const int bs = bsT[t], off = offT[t];
    const bool lastStep = (s == T_STEPS - 1) || (!dir && bsT[s + 1] <= bt * 128);

    // prefetch NEXT step's x (2-deep pipeline; guarded by next bs)
    if (!lastStep) {
      int tn = dir ? (T_STEPS - 2 - s) : (s + 1);
      int bsn = bsT[tn], offn = offT[tn];
#pragma unroll
      for (int mt = 0; mt < 2; ++mt)
#pragma unroll
        for (int r = 0; r < 4; ++r) {
          int b = rowb + mt * 16 + qr4 + r;
          if (b < bsn)
            xgB[mt][r] = *(const f16x4*)(xp + (size_t)(offn + b) * XPLD
                                         + dir * G4 + slice * 64 + lr * 4);
        }
    }

    // wait: all 25 peers done step s-1 — EVERY wave polls and proceeds
    // independently (no funnel barrier; each wave self-orders poll -> h loads)
    if (s > s_begin) {
      while (true) {
        unsigned vv = ld_cc4(peer);
        if (!__ballot((lane < 25) && (vv < (unsigned)s))) break;
        __builtin_amdgcn_s_sleep(1);
      }
    }

    const int cur = s & 1;
    const f16* hr = h16 + (size_t)((dir << 1) | cur) * (1024 * HLD);
    f16* hww = h16 + (size_t)((dir << 1) | (cur ^ 1)) * (1024 * HLD);

    const f16* ha = hr + (size_t)(rowb + lr) * HLD + kreg;
    f16x8 hfa[13], hfb[13];
#pragma unroll
    for (int kk = 0; kk < 13; ++kk) {
      hfa[kk] = ld_cc(ha + kk * 32);
      hfb[kk] = ld_cc(ha + 16 * HLD + kk * 32);
    }
    asm volatile("s_waitcnt vmcnt(0)" ::: "memory");
    __builtin_amdgcn_sched_barrier(0);

    __builtin_amdgcn_s_setprio(1);
    f32x4 acc[2][4] = {};
#pragma unroll
    for (int kk = 0; kk < 13; ++kk) {
#pragma unroll
      for (int g = 0; g < 4; ++g) {
        f16x8 bf = *(const f16x8*)&Wl[(g * 16 + lr) * WPAD + kk * 32 + kreg];
        acc[0][g] = __builtin_amdgcn_mfma_f32_16x16x32_f16(hfa[kk], bf, acc[0][g], 0, 0, 0);
        acc[1][g] = __builtin_amdgcn_mfma_f32_16x16x32_f16(hfb[kk], bf, acc[1][g], 0, 0, 0);
      }
    }
    __builtin_amdgcn_s_setprio(0);

    float hnw[2][4];
    f16 hv16[2][4];
#pragma unroll
    for (int mt = 0; mt < 2; ++mt) {
#pragma unroll
      for (int r = 0; r < 4; ++r) {
        int b = rowb + mt * 16 + qr4 + r;
        if (b < bs) {
          float Gi = acc[mt][0][r] + (float)xgA[mt][r][0] + bi0;
          float Gf = acc[mt][1][r] + (float)xgA[mt][r][1] + bi1;
          float Gg = acc[mt][2][r] + (float)xgA[mt][r][2] + bi2;
          float Go = acc[mt][3][r] + (float)xgA[mt][r][3] + bi3;
          float ii = 1.f / (1.f + __expf(-Gi));
          float ff = 1.f / (1.f + __expf(-Gf));
          float gg = 1.f - 2.f / (__expf(2.f * Gg) + 1.f);
          float oo = 1.f / (1.f + __expf(-Go));
          float cnew = ff * ch[mt][r] + ii * gg;
          ch[mt][r] = cnew;
          float hnew = oo * (1.f - 2.f / (__expf(2.f * cnew) + 1.f));
          union { f16 f; unsigned short u; } cv; cv.f = (f16)hnew;
          st_cc2(&hww[(size_t)b * HLD + j], (unsigned)cv.u);
          hnw[mt][r] = hnew;
          hv16[mt][r] = cv.f;
        }
      }
    }

    if (!lastStep) {
      __syncthreads();                                 // implicit vmcnt(0): h ACKed at L3
      if (tid == 0) st_cc4(myflag, (unsigned)(s + 1)); // publish AFTER h visible
    }

    // deferred outputs (overlap next step's prefetch/spin)
#pragma unroll
    for (int mt = 0; mt < 2; ++mt) {
#pragma unroll
      for (int r = 0; r < 4; ++r) {
        int b = rowb + mt * 16 + qr4 + r;
        if (b < bs) {
          size_t prow = (size_t)(off + b);
          if (outf32) outf32[prow * 800 + dir * HID + j] = hnw[mt][r];
          else        outf16[prow * 800 + dir * HID + j] = hv16[mt][r];
          bool lastv = dir ? (s == T_STEPS - 1)
                           : (s == T_STEPS - 1 || bsT[s + 1] <= b);
          if (lastv) {
            cp[(size_t)b * HID + j] = ch[mt][r];
            hp[(size_t)b * HID + j] = hnw[mt][r];
          }
        }
      }
    }
    if (lastStep) break;
    // rotate x pipeline
#pragma unroll
    for (int mt = 0; mt < 2; ++mt)
#pragma unroll
      for (int r = 0; r < 4; ++r) xgA[mt][r] = xgB[mt][r];
  }
}

// ---------------- fallback per-step kernel (matches xproj gate layout) ----------------
__global__ __launch_bounds__(256) void k_step(
    const f16* __restrict__ xp, const f16* __restrict__ whh,
    const float* __restrict__ bias2, const f16* __restrict__ h16r0,
    f16* __restrict__ h16w0, float* __restrict__ hn, float* __restrict__ cn,
    f16* __restrict__ outf16, float* __restrict__ outf32,
    int bs_f, int off_f, int bs_b, int off_b, int nTf) {
  const int slice = blockIdx.x % 25;
  const int tl = blockIdx.x / 25;
  int dir, bt, bs, off;
  if (tl < nTf) { dir = 0; bt = tl; bs = bs_f; off = off_f; }
  else          { dir = 1; bt = tl - nTf; bs = bs_b; off = off_b; }
  const int lane = threadIdx.x & 63, w = threadIdx.x >> 6;
  const int lr = lane & 15, kreg = (lane >> 4) * 8;
  const int b0 = bt * 128;
  const int j0 = slice * 16;
  const f16* hr = h16r0 + (size_t)dir * (2 * 1024 * HLD);
  f16* hw = h16w0 + (size_t)dir * (2 * 1024 * HLD);
  const f16* W = whh + (size_t)dir * (G4 * HLD);
  const float* bi = bias2 + dir * G4;
  float* hp = hn + (size_t)dir * (1024 * HID);
  float* cp = cn + (size_t)dir * (1024 * HID);

  f32x4 acc[2][4] = {};
  for (int k0 = 0; k0 < HLD; k0 += 32) {
    f16x8 af0 = *(const f16x8*)&hr[(b0 + (w * 2 + 0) * 16 + lr) * HLD + k0 + kreg];
    f16x8 af1 = *(const f16x8*)&hr[(b0 + (w * 2 + 1) * 16 + lr) * HLD + k0 + kreg];
#pragma unroll
    for (int g = 0; g < 4; ++g) {
      f16x8 bf = *(const f16x8*)&W[(g * HID + j0 + lr) * HLD + k0 + kreg];
      acc[0][g] = __builtin_amdgcn_mfma_f32_16x16x32_f16(af0, bf, acc[0][g], 0, 0, 0);
      acc[1][g] = __builtin_amdgcn_mfma_f32_16x16x32_f16(af1, bf, acc[1][g], 0, 0, 0);
    }
  }
  const int j = j0 + lr;
#pragma unroll
  for (int mt = 0; mt < 2; ++mt) {
#pragma unroll
    for (int r = 0; r < 4; ++r) {
      int b = b0 + (w * 2 + mt) * 16 + (lane >> 4) * 4 + r;
      if (b < bs) {
        size_t prow = (size_t)(off + b);
        const f16* xr = xp + prow * XPLD + dir * G4 + slice * 64 + lr * 4;
        float Gi = acc[mt][0][r] + (float)xr[0] + bi[j];
        float Gf = acc[mt][1][r] + (float)xr[1] + bi[HID + j];
        float Gg = acc[mt][2][r] + (float)xr[2] + bi[2 * HID + j];
        float Go = acc[mt][3][r] + (float)xr[3] + bi[3 * HID + j];
        float ii = 1.f / (1.f + __expf(-Gi));
        float ff = 1.f / (1.f + __expf(-Gf));
        float gg = 1.f - 2.f / (__expf(2.f * Gg) + 1.f);
        float oo = 1.f / (1.f + __expf(-Go));
        float co = cp[b * HID + j];
        float cnew = ff * co + ii * gg;
        float hnew = oo * (1.f - 2.f / (__expf(2.f * cnew) + 1.f));
        cp[b * HID + j] = cnew;
        hp[b * HID + j] = hnew;
        hw[b * HLD + j] = (f16)hnew;
        if (outf32) outf32[prow * 800 + dir * HID + j] = hnew;
        else        outf16[prow * 800 + dir * HID + j] = (f16)hnew;
      }
    }
  }
}

// ---------------- host ----------------
extern "C" void kernel_launch(void* const* d_in, const int* in_sizes, int n_in,
                              void* d_out, int out_size, void* d_ws, size_t ws_size,
                              hipStream_t stream) {
  (void)in_sizes; (void)n_in; (void)out_size; (void)ws_size;
  const float* x   = (const float*)d_in[0];
  const float* Wih = (const float*)d_in[1];
  const float* Whh = (const float*)d_in[2];
  const float* bih = (const float*)d_in[3];
  const float* bhh = (const float*)d_in[4];
  float* out = (float*)d_out;

  long long bsv[128];
  {
    double step = (1.0 - 1024.0) / 127.0;
    for (int i = 0; i < 128; ++i) bsv[i] = (long long)floor((double)i * step + 1024.0);
    bsv[127] = 1; bsv[0] = 1024;
    long long sum = 0;
    for (int i = 0; i < 128; ++i) sum += bsv[i];
    long long diff = 65536 - sum;
    while (diff != 0) {
      if (diff > 0) {
        for (int jj = 1; jj < 128 && diff != 0; ++jj) {
          long long cap = bsv[jj - 1] - bsv[jj];
          long long add = cap < diff ? cap : diff;
          bsv[jj] += add; diff -= add;
        }
      } else {
        for (int jj = 127; jj >= 1 && diff != 0; --jj) {
          long long nxt = (jj + 1 < 128) ? bsv[jj + 1] : 1;
          long long room = bsv[jj] - nxt;
          long long sub = room < (-diff) ? room : (-diff);
          bsv[jj] -= sub; diff += sub;
        }
      }
    }
  }
  long long offv[128], a0 = 0;
  for (int i = 0; i < 128; ++i) { offv[i] = a0; a0 += bsv[i]; }

  char* p = (char*)d_ws;
  f16*      x16   = (f16*)(p);                 // 65536x400 f16 (+256B zero pad)
  f16*      wih16 = (f16*)(p + 52429056LL);    // 6x1600x800 f16, gate-permuted rows
  f16*      whh16 = (f16*)(p + 67789056LL);    // 6x1600x416 f16 (zero-padded K)
  float*    bias  = (float*)(p + 75776256LL);  // 6x1600 f32
  f16*      xproj = (f16*)(p + 75814656LL);    // (65536+128)x3200 f16
  unsigned* flags = (unsigned*)(p + 495654656LL);  // 3 layers x 16 groups x 25 x 128B
  f16*      layA  = (f16*)(p + 496064256LL);   // 65536x800 f16
  f16*      layB  = (f16*)(p + 600921856LL);   // 65536x800 f16
  f16*      h16   = (f16*)(p + 705779456LL);   // 2 dir x 2 pp x 1024x416 f16

  hipMemsetAsync(p + 52428800LL, 0, 256, stream);              // x16 K-pad
  hipMemsetAsync(out + 52428800LL, 0, 4915200LL * 4, stream);  // h_n + c_n
  hipMemsetAsync(flags, 0, 3 * 16 * 25 * 128, stream);         // all layer flags

  k_cvt_f16<<<2048, 256, 0, stream>>>(x, x16, 26214400LL);
  k_cvt_wih<<<2048, 256, 0, stream>>>(Wih, wih16);
  k_cvt_whh<<<2048, 256, 0, stream>>>(Whh, whh16, 9600);
  k_bias<<<40, 256, 0, stream>>>(bih, bhh, bias, 9600);

  int occ = 0;
  hipOccupancyMaxActiveBlocksPerMultiprocessor(&occ, k_rnn, 256, 0);
  const bool persistent = (occ >= 2);  // 2/CU x 256 CU = 512 >= 400 co-resident

  const long long OUTP = 52428800LL, HNSZ = 2457600LL;

  for (int L = 0; L < 3; ++L) {
    const f16* Ain = (L == 0) ? x16 : (L == 1 ? layA : layB);
    int lda = (L == 0) ? 400 : 800;
    int K   = (L == 0) ? 416 : 800;
    k_gemm<<<6400, 512, 0, stream>>>(Ain, wih16 + (size_t)(2 * L) * 1600 * 800,
                                     xproj, lda, K);
    hipMemsetAsync(h16, 0, 3407872LL, stream);
    float* hnL = out + OUTP + (size_t)(2 * L) * 409600;
    float* cnL = out + OUTP + HNSZ + (size_t)(2 * L) * 409600;
    f16* o16 = (L == 0) ? layA : (L == 1 ? layB : nullptr);
    float* o32 = (L == 2) ? out : nullptr;
    if (persistent) {
      k_rnn<<<RNN_BLOCKS, 256, 0, stream>>>(
          xproj, whh16 + (size_t)(2 * L) * 1600 * HLD, bias + (size_t)(2 * L) * 1600,
          h16, hnL, cnL, o16, o32, flags + (size_t)L * 16 * 25 * 32);
    } else {
      for (int s = 0; s < 128; ++s) {
        int tf = s, tb = 127 - s;
        int bsf = (int)bsv[tf], bsb = (int)bsv[tb];
        int nTf = (bsf + 127) / 128, nTb = (bsb + 127) / 128;
        k_step<<<25 * (nTf + nTb), 256, 0, stream>>>(
            xproj, whh16 + (size_t)(2 * L) * 1600 * HLD, bias + (size_t)(2 * L) * 1600,
            h16 + (size_t)(s & 1) * 1024 * HLD, h16 + (size_t)((s + 1) & 1) * 1024 * HLD,
            hnL, cnL, o16, o32,
            bsf, (int)offv[tf], bsb, (int)offv[tb], nTf);
      }
    }
  }
}

// Round 12
// 7669.424 us; speedup vs baseline: 1.0965x; 1.0018x over previous
//
#include <hip/hip_runtime.h>
#include <math.h>

using f16 = _Float16;
typedef __attribute__((ext_vector_type(8))) _Float16 f16x8;
typedef __attribute__((ext_vector_type(4))) _Float16 f16x4;
typedef __attribute__((ext_vector_type(4))) float f32x4;

#define T_STEPS 128
#define HID 400
#define G4 1600
#define XPLD 3200
#define HLD 416
#define WPAD 424
#define NSL 13
#define JW 32
#define RNN_BLOCKS (NSL * 16)

__device__ __forceinline__ void gl_lds16(const void* g, void* l) {
  __builtin_amdgcn_global_load_lds((const __attribute__((address_space(1))) void*)g,
                                   (__attribute__((address_space(3))) void*)l, 16, 0, 0);
}

// cross-XCD-coherent ops: bypass L1+L2, hit the L3 coherence point
__device__ __forceinline__ f16x8 ld_cc(const f16* p) {
  f16x8 r;
  asm volatile("global_load_dwordx4 %0, %1, off sc0 sc1" : "=v"(r) : "v"(p));
  return r;  // caller must s_waitcnt vmcnt(0) + sched_barrier before use
}
__device__ __forceinline__ void st_cc2(f16* p, unsigned v) {
  asm volatile("global_store_short %0, %1, off sc0 sc1" :: "v"(p), "v"(v) : "memory");
}
__device__ __forceinline__ void st_cc4(unsigned* p, unsigned v) {
  asm volatile("global_store_dword %0, %1, off sc0 sc1" :: "v"(p), "v"(v) : "memory");
}
__device__ __forceinline__ unsigned ld_cc4(const unsigned* p) {
  unsigned v;
  asm volatile("global_load_dword %0, %1, off sc0 sc1\n\ts_waitcnt vmcnt(0)"
               : "=v"(v) : "v"(p) : "memory");
  return v;
}

// ---------------- conversion kernels ----------------
__global__ void k_cvt_f16(const float* __restrict__ s, f16* __restrict__ d, long long n) {
  long long i = ((long long)blockIdx.x * blockDim.x + threadIdx.x) * 4;
  long long stride = (long long)gridDim.x * blockDim.x * 4;
  for (; i < n; i += stride) {
    float4 v = *(const float4*)(s + i);
    f16x4 o = { (f16)v.x, (f16)v.y, (f16)v.z, (f16)v.w };
    *(f16x4*)(d + i) = o;
  }
}

// Wih f32 -> f16 with gate-interleave ROW permutation folded in:
// out row R = L*3200 + dirn*1600 + (j/16)*64 + (j%16)*4 + g  <-  in row (2L+dirn)*1600 + g*400 + j
__global__ void k_cvt_wih(const float* __restrict__ s, f16* __restrict__ d) {
  long long n4 = 9600LL * 200;  // 4 elems per iter
  for (long long i = (long long)blockIdx.x * blockDim.x + threadIdx.x; i < n4;
       i += (long long)gridDim.x * blockDim.x) {
    long long i4 = i * 4;
    int R = (int)(i4 / 800), c = (int)(i4 % 800);
    int L = R / 3200, rem = R % 3200;
    int dirn = rem / 1600, q = rem % 1600;
    int g = q & 3, jlo = (q >> 2) & 15, jhi = q >> 6;
    int inrow = (2 * L + dirn) * 1600 + g * HID + jhi * 16 + jlo;
    float4 v = *(const float4*)(s + (long long)inrow * 800 + c);
    f16x4 o = { (f16)v.x, (f16)v.y, (f16)v.z, (f16)v.w };
    *(f16x4*)(d + i4) = o;
  }
}

__global__ void k_cvt_whh(const float* __restrict__ s, f16* __restrict__ d, int nrows) {
  long long n = (long long)nrows * HLD;
  for (long long i = (long long)blockIdx.x * blockDim.x + threadIdx.x; i < n;
       i += (long long)gridDim.x * blockDim.x) {
    int row = (int)(i / HLD), c = (int)(i % HLD);
    d[i] = (c < HID) ? (f16)s[(long long)row * HID + c] : (f16)0.f;
  }
}

__global__ void k_bias(const float* __restrict__ a, const float* __restrict__ b,
                       float* __restrict__ d, int n) {
  for (int i = blockIdx.x * blockDim.x + threadIdx.x; i < n; i += gridDim.x * blockDim.x)
    d[i] = a[i] + b[i];
}

// ---------------- input-projection GEMM (256x128 tile, 8 waves, 3-buf T4) ----------------
__global__ __launch_bounds__(512) void k_gemm(const f16* __restrict__ A,
                                              const f16* __restrict__ Bw,
                                              f16* __restrict__ C, int lda, int K) {
  __shared__ f16 As[3][256 * 32];
  __shared__ f16 Bs[3][128 * 32];
  const int tid = threadIdx.x;
  const int lane = tid & 63, v = tid >> 6;  // 8 waves
  const int wm = v >> 1, wn = v & 1;        // 4 x 2 quadrants of 64x64
  const int wg = blockIdx.x;
  const int swz = (wg & 7) * 800 + (wg >> 3);  // bijective XCD swizzle (6400%8==0)
  const int bn = (swz % 25) * 128;
  const long long bm = (long long)(swz / 25) * 256;

  const int kc = ((lane & 3) ^ ((lane >> 3) & 3)) * 8;
  const int srow = (v * 64 + lane) >> 2;
  const f16* gA0 = A + (bm + srow) * (long long)lda + kc;
  const f16* gA1 = A + (bm + 128 + srow) * (long long)lda + kc;
  const f16* gB0 = Bw + (long long)(bn + srow) * 800 + kc;

  const int lr = lane & 15;
  const int kswz = (((lane >> 4) ^ ((lr >> 1) & 3)) << 3);
  const int nk = K / 32;

  f32x4 acc[4][4] = {};

#define STAGE(bb, k0)                              \
  do {                                             \
    gl_lds16(gA0 + (k0), &As[bb][v * 512]);        \
    gl_lds16(gA1 + (k0), &As[bb][4096 + v * 512]); \
    gl_lds16(gB0 + (k0), &Bs[bb][v * 512]);        \
  } while (0)

  STAGE(0, 0);
  STAGE(1, 32);
  int cur = 0;
  for (int kt = 0; kt < nk; ++kt) {
    if (kt + 1 < nk) asm volatile("s_waitcnt vmcnt(3)" ::: "memory");
    else             asm volatile("s_waitcnt vmcnt(0)" ::: "memory");
    __builtin_amdgcn_s_barrier();   // raw: in-flight next-tile loads stay queued
    f16x8 af[4], bf[4];
#pragma unroll
    for (int mt = 0; mt < 4; ++mt)
      af[mt] = *(const f16x8*)&As[cur][(wm * 64 + mt * 16 + lr) * 32 + kswz];
#pragma unroll
    for (int nt = 0; nt < 4; ++nt)
      bf[nt] = *(const f16x8*)&Bs[cur][(wn * 64 + nt * 16 + lr) * 32 + kswz];
    if (kt + 2 < nk) {
      int nb = cur + 2; if (nb >= 3) nb -= 3;
      STAGE(nb, (kt + 2) * 32);
    }
#pragma unroll
    for (int mt = 0; mt < 4; ++mt)
#pragma unroll
      for (int nt = 0; nt < 4; ++nt)
        acc[mt][nt] = __builtin_amdgcn_mfma_f32_16x16x32_f16(af[mt], bf[nt], acc[mt][nt], 0, 0, 0);
    ++cur; if (cur >= 3) cur -= 3;
  }
#undef STAGE

#pragma unroll
  for (int mt = 0; mt < 4; ++mt) {
#pragma unroll
    for (int nt = 0; nt < 4; ++nt) {
      long long gm = bm + wm * 64 + mt * 16 + ((lane >> 4) * 4);
      int gn = bn + wn * 64 + nt * 16 + lr;  // linear, coalesced
#pragma unroll
      for (int r = 0; r < 4; ++r)
        C[(gm + r) * XPLD + gn] = (f16)acc[mt][nt][r];
    }
  }
}

// ---------------- persistent recurrence (208 blocks, 13 slices, wave-granular sync) ----------------
// 13 slices x 16 groups (dir x 8 bt of 128 rows); 512 threads = 8 waves, wave w
// owns rows [bt*128+w*16, +16) x 32 j-cols. W slice (128x424 f16, 108KB) in LDS.
// Sync: per-(group,wave) 128B flag line; wave w of slice s writes dword s after
// its own vmcnt(0); waiters poll ONE line (13 lanes, 1 L3 transaction). Zero
// in-loop barriers. Safety: same-w waves are flag-ordered (they read/write the
// same rows); different-w waves touch disjoint rows.
__global__ __launch_bounds__(512) void k_rnn(
    const f16* __restrict__ xp, const f16* __restrict__ whh,
    const float* __restrict__ bias2, f16* __restrict__ h16,
    float* __restrict__ hn, float* __restrict__ cn,
    f16* __restrict__ outf16, float* __restrict__ outf32,
    unsigned* __restrict__ flags) {
  __shared__ f16 Wl[128 * WPAD];  // 4 gates x 32 j rows, 416(+8) cols = 108.5 KB
  __shared__ int bsT[T_STEPS], offT[T_STEPS];

  const int tid = threadIdx.x;
  const int slice = blockIdx.x % NSL;
  const int q = blockIdx.x / NSL;  // 0..15 : dir*8 + bt
  const int dir = q >> 3, bt = q & 7;
  const int lane = tid & 63, w = tid >> 6;  // 8 waves
  const int lr = lane & 15, kreg = (lane >> 4) * 8;
  const int qr4 = (lane >> 4) * 4;
  const int j0 = slice * JW;
  unsigned* line = flags + ((size_t)q * 8 + w) * 32;  // 128B per (group,wave)
  const unsigned* peer = line + (lane < NSL ? lane : 0);

  if (tid == 0) {
    double step = (1.0 - 1024.0) / 127.0;
    for (int i = 0; i < T_STEPS; ++i) bsT[i] = (int)floor((double)i * step + 1024.0);
    bsT[127] = 1; bsT[0] = 1024;
    int sum = 0;
    for (int i = 0; i < T_STEPS; ++i) sum += bsT[i];
    int diff = 65536 - sum;
    while (diff != 0) {
      if (diff > 0) {
        for (int jj = 1; jj < T_STEPS && diff != 0; ++jj) {
          int cap = bsT[jj - 1] - bsT[jj];
          int add = cap < diff ? cap : diff;
          bsT[jj] += add; diff -= add;
        }
      } else {
        for (int jj = T_STEPS - 1; jj >= 1 && diff != 0; --jj) {
          int nxt = (jj + 1 < T_STEPS) ? bsT[jj + 1] : 1;
          int room = bsT[jj] - nxt;
          int sub = room < (-diff) ? room : (-diff);
          bsT[jj] -= sub; diff += sub;
        }
      }
    }
    int a0 = 0;
    for (int i = 0; i < T_STEPS; ++i) { offT[i] = a0; a0 += bsT[i]; }
  }

  // W slice -> LDS: 128 rows (4 gates x 32 j), 416 cols (pad stride 424).
  // slice 12 rows j>=400 read overrun garbage -> only feeds guarded (dead) cells.
  const f16* whhD = whh + (size_t)dir * (G4 * HLD);
  {
    int rr = tid >> 2, seg = tid & 3;
    int g = rr >> 5, jsub = rr & 31;
    const f16* src = whhD + (size_t)(g * HID + j0 + jsub) * HLD + seg * 104;
    f16* dst = &Wl[rr * WPAD + seg * 104];
#pragma unroll
    for (int kk = 0; kk < 13; ++kk)
      *(f16x8*)(dst + kk * 8) = *(const f16x8*)(src + kk * 8);
  }
  const float* biD = bias2 + dir * G4;
  float bi[2][4];
#pragma unroll
  for (int h = 0; h < 2; ++h) {
    int jc = j0 + h * 16 + lr;
#pragma unroll
    for (int g = 0; g < 4; ++g)
      bi[h][g] = (jc < HID) ? biD[g * HID + jc] : 0.f;
  }
  float* hp = hn + (size_t)dir * (1024 * HID);
  float* cp = cn + (size_t)dir * (1024 * HID);
  __syncthreads();  // W + tables ready (only barrier in the kernel)

  int s_begin = 0;
  if (dir) {  // backward: tile inactive until bs grows past it (h rows still 0)
    while (s_begin < T_STEPS && bsT[T_STEPS - 1 - s_begin] <= bt * 128) ++s_begin;
  }
  const int rowb = bt * 128 + w * 16;  // wave's 16 rows
  float ch[2][4] = {};  // [h][r]

  // initial x prefetch (step s_begin), guarded by bs
  f16x4 xgA[2][4], xgB[2][4];
  {
    int tt = dir ? (T_STEPS - 1 - s_begin) : s_begin;
    int bs0 = bsT[tt], off0 = offT[tt];
#pragma unroll
    for (int r = 0; r < 4; ++r) {
      int b = rowb + qr4 + r;
      if (b < bs0) {
        const f16* xr = xp + (size_t)(off0 + b) * XPLD + dir * G4 + slice * 128 + lr * 4;
        xgA[0][r] = *(const f16x4*)(xr);
        xgA[1][r] = *(const f16x4*)(xr + 64);
      }
    }
  }

#pragma unroll 1
  for (int s = s_begin; s < T_STEPS; ++s) {
    const int t = dir ? (T_STEPS - 1 - s) : s;
    const int bs = bsT[t], off = offT[t];
    const bool lastStep = (s == T_STEPS - 1) || (!dir && bsT[s + 1] <= bt * 128);

    // prefetch NEXT step's x (2-deep; guarded by next bs)
    if (!lastStep) {
      int tn = dir ? (T_STEPS - 2 - s) : (s + 1);
      int bsn = bsT[tn], offn = offT[tn];
#pragma unroll
      for (int r = 0; r < 4; ++r) {
        int b = rowb + qr4 + r;
        if (b < bsn) {
          const f16* xr = xp + (size_t)(offn + b) * XPLD + dir * G4 + slice * 128 + lr * 4;
          xgB[0][r] = *(const f16x4*)(xr);
          xgB[1][r] = *(const f16x4*)(xr + 64);
        }
      }
    }

    // wait: same-index waves of all 13 slices done step s-1 (one-line poll)
    if (s > s_begin) {
      while (true) {
        unsigned vv = ld_cc4(peer);
        if (!__ballot((lane < NSL) && (vv < (unsigned)s))) break;
        __builtin_amdgcn_s_sleep(1);
      }
    }

    const int cur = s & 1;
    const f16* hr = h16 + (size_t)((dir << 1) | cur) * (1024 * HLD);
    f16* hww = h16 + (size_t)((dir << 1) | (cur ^ 1)) * (1024 * HLD);

    // issue the wave's 13 h loads (16 rows x 416 cols), single drain, MFMA
    const f16* ha = hr + (size_t)(rowb + lr) * HLD + kreg;
    f16x8 hf[13];
#pragma unroll
    for (int kk = 0; kk < 13; ++kk) hf[kk] = ld_cc(ha + kk * 32);
    asm volatile("s_waitcnt vmcnt(0)" ::: "memory");
    __builtin_amdgcn_sched_barrier(0);

    __builtin_amdgcn_s_setprio(1);
    f32x4 acc[8] = {};  // [g*2+h]
#pragma unroll
    for (int kk = 0; kk < 13; ++kk) {
#pragma unroll
      for (int nt = 0; nt < 8; ++nt) {
        f16x8 bf = *(const f16x8*)&Wl[(((nt >> 1) << 5) + ((nt & 1) << 4) + lr) * WPAD
                                      + kk * 32 + kreg];
        acc[nt] = __builtin_amdgcn_mfma_f32_16x16x32_f16(hf[kk], bf, acc[nt], 0, 0, 0);
      }
    }
    __builtin_amdgcn_s_setprio(0);

    float hnw[2][4];
    f16 hv16[2][4];
#pragma unroll
    for (int h = 0; h < 2; ++h) {
      const int jc = j0 + h * 16 + lr;
#pragma unroll
      for (int r = 0; r < 4; ++r) {
        int b = rowb + qr4 + r;
        if (b < bs && jc < HID) {  // pad-j cells never stored -> h pad stays 0
          float Gi = acc[0 + h][r] + (float)xgA[h][r][0] + bi[h][0];
          float Gf = acc[2 + h][r] + (float)xgA[h][r][1] + bi[h][1];
          float Gg = acc[4 + h][r] + (float)xgA[h][r][2] + bi[h][2];
          float Go = acc[6 + h][r] + (float)xgA[h][r][3] + bi[h][3];
          float ii = 1.f / (1.f + __expf(-Gi));
          float ff = 1.f / (1.f + __expf(-Gf));
          float gg = 1.f - 2.f / (__expf(2.f * Gg) + 1.f);
          float oo = 1.f / (1.f + __expf(-Go));
          float cnew = ff * ch[h][r] + ii * gg;
          ch[h][r] = cnew;
          float hnew = oo * (1.f - 2.f / (__expf(2.f * cnew) + 1.f));
          union { f16 f; unsigned short u; } cv; cv.f = (f16)hnew;
          st_cc2(&hww[(size_t)b * HLD + jc], (unsigned)cv.u);
          hnw[h][r] = hnew;
          hv16[h][r] = cv.f;
        }
      }
    }

    if (!lastStep) {
      asm volatile("s_waitcnt vmcnt(0)" ::: "memory");  // this wave's h ACKed at L3
      if (lane == 0) st_cc4((unsigned*)(line + slice), (unsigned)(s + 1));
    }

    // deferred outputs (overlap next step's prefetch/spin)
#pragma unroll
    for (int h = 0; h < 2; ++h) {
      const int jc = j0 + h * 16 + lr;
#pragma unroll
      for (int r = 0; r < 4; ++r) {
        int b = rowb + qr4 + r;
        if (b < bs && jc < HID) {
          size_t prow = (size_t)(off + b);
          if (outf32) outf32[prow * 800 + dir * HID + jc] = hnw[h][r];
          else        outf16[prow * 800 + dir * HID + jc] = hv16[h][r];
          bool lastv = dir ? (s == T_STEPS - 1)
                           : (s == T_STEPS - 1 || bsT[s + 1] <= b);
          if (lastv) {
            cp[(size_t)b * HID + jc] = ch[h][r];
            hp[(size_t)b * HID + jc] = hnw[h][r];
          }
        }
      }
    }
    if (lastStep) break;
    // rotate x pipeline
#pragma unroll
    for (int h = 0; h < 2; ++h)
#pragma unroll
      for (int r = 0; r < 4; ++r) xgA[h][r] = xgB[h][r];
  }
}

// ---------------- fallback per-step kernel (matches xproj gate layout) ----------------
__global__ __launch_bounds__(256) void k_step(
    const f16* __restrict__ xp, const f16* __restrict__ whh,
    const float* __restrict__ bias2, const f16* __restrict__ h16r0,
    f16* __restrict__ h16w0, float* __restrict__ hn, float* __restrict__ cn,
    f16* __restrict__ outf16, float* __restrict__ outf32,
    int bs_f, int off_f, int bs_b, int off_b, int nTf) {
  const int slice = blockIdx.x % 25;
  const int tl = blockIdx.x / 25;
  int dir, bt, bs, off;
  if (tl < nTf) { dir = 0; bt = tl; bs = bs_f; off = off_f; }
  else          { dir = 1; bt = tl - nTf; bs = bs_b; off = off_b; }
  const int lane = threadIdx.x & 63, w = threadIdx.x >> 6;
  const int lr = lane & 15, kreg = (lane >> 4) * 8;
  const int b0 = bt * 128;
  const int j0 = slice * 16;
  const f16* hr = h16r0 + (size_t)dir * (2 * 1024 * HLD);
  f16* hw = h16w0 + (size_t)dir * (2 * 1024 * HLD);
  const f16* W = whh + (size_t)dir * (G4 * HLD);
  const float* bi = bias2 + dir * G4;
  float* hp = hn + (size_t)dir * (1024 * HID);
  float* cp = cn + (size_t)dir * (1024 * HID);

  f32x4 acc[2][4] = {};
  for (int k0 = 0; k0 < HLD; k0 += 32) {
    f16x8 af0 = *(const f16x8*)&hr[(b0 + (w * 2 + 0) * 16 + lr) * HLD + k0 + kreg];
    f16x8 af1 = *(const f16x8*)&hr[(b0 + (w * 2 + 1) * 16 + lr) * HLD + k0 + kreg];
#pragma unroll
    for (int g = 0; g < 4; ++g) {
      f16x8 bf = *(const f16x8*)&W[(g * HID + j0 + lr) * HLD + k0 + kreg];
      acc[0][g] = __builtin_amdgcn_mfma_f32_16x16x32_f16(af0, bf, acc[0][g], 0, 0, 0);
      acc[1][g] = __builtin_amdgcn_mfma_f32_16x16x32_f16(af1, bf, acc[1][g], 0, 0, 0);
    }
  }
  const int j = j0 + lr;
#pragma unroll
  for (int mt = 0; mt < 2; ++mt) {
#pragma unroll
    for (int r = 0; r < 4; ++r) {
      int b = b0 + (w * 2 + mt) * 16 + (lane >> 4) * 4 + r;
      if (b < bs) {
        size_t prow = (size_t)(off + b);
        const f16* xr = xp + prow * XPLD + dir * G4 + slice * 64 + lr * 4;
        float Gi = acc[mt][0][r] + (float)xr[0] + bi[j];
        float Gf = acc[mt][1][r] + (float)xr[1] + bi[HID + j];
        float Gg = acc[mt][2][r] + (float)xr[2] + bi[2 * HID + j];
        float Go = acc[mt][3][r] + (float)xr[3] + bi[3 * HID + j];
        float ii = 1.f / (1.f + __expf(-Gi));
        float ff = 1.f / (1.f + __expf(-Gf));
        float gg = 1.f - 2.f / (__expf(2.f * Gg) + 1.f);
        float oo = 1.f / (1.f + __expf(-Go));
        float co = cp[b * HID + j];
        float cnew = ff * co + ii * gg;
        float hnew = oo * (1.f - 2.f / (__expf(2.f * cnew) + 1.f));
        cp[b * HID + j] = cnew;
        hp[b * HID + j] = hnew;
        hw[b * HLD + j] = (f16)hnew;
        if (outf32) outf32[prow * 800 + dir * HID + j] = hnew;
        else        outf16[prow * 800 + dir * HID + j] = (f16)hnew;
      }
    }
  }
}

// ---------------- host ----------------
extern "C" void kernel_launch(void* const* d_in, const int* in_sizes, int n_in,
                              void* d_out, int out_size, void* d_ws, size_t ws_size,
                              hipStream_t stream) {
  (void)in_sizes; (void)n_in; (void)out_size; (void)ws_size;
  const float* x   = (const float*)d_in[0];
  const float* Wih = (const float*)d_in[1];
  const float* Whh = (const float*)d_in[2];
  const float* bih = (const float*)d_in[3];
  const float* bhh = (const float*)d_in[4];
  float* out = (float*)d_out;

  long long bsv[128];
  {
    double step = (1.0 - 1024.0) / 127.0;
    for (int i = 0; i < 128; ++i) bsv[i] = (long long)floor((double)i * step + 1024.0);
    bsv[127] = 1; bsv[0] = 1024;
    long long sum = 0;
    for (int i = 0; i < 128; ++i) sum += bsv[i];
    long long diff = 65536 - sum;
    while (diff != 0) {
      if (diff > 0) {
        for (int jj = 1; jj < 128 && diff != 0; ++jj) {
          long long cap = bsv[jj - 1] - bsv[jj];
          long long add = cap < diff ? cap : diff;
          bsv[jj] += add; diff -= add;
        }
      } else {
        for (int jj = 127; jj >= 1 && diff != 0; --jj) {
          long long nxt = (jj + 1 < 128) ? bsv[jj + 1] : 1;
          long long room = bsv[jj] - nxt;
          long long sub = room < (-diff) ? room : (-diff);
          bsv[jj] -= sub; diff += sub;
        }
      }
    }
  }
  long long offv[128], a0 = 0;
  for (int i = 0; i < 128; ++i) { offv[i] = a0; a0 += bsv[i]; }

  char* p = (char*)d_ws;
  f16*      x16   = (f16*)(p);                 // 65536x400 f16 (+256B zero pad)
  f16*      wih16 = (f16*)(p + 52429056LL);    // 6x1600x800 f16, gate-permuted rows
  f16*      whh16 = (f16*)(p + 67789056LL);    // 6x1600x416 f16 (zero-padded K)
  float*    bias  = (float*)(p + 75776256LL);  // 6x1600 f32
  f16*      xproj = (f16*)(p + 75814656LL);    // (65536+128)x3200 f16
  unsigned* flags = (unsigned*)(p + 495654656LL);  // 3 layers x 16 groups x 8 waves x 128B
  f16*      layA  = (f16*)(p + 496064256LL);   // 65536x800 f16
  f16*      layB  = (f16*)(p + 600921856LL);   // 65536x800 f16
  f16*      h16   = (f16*)(p + 705779456LL);   // 2 dir x 2 pp x 1024x416 f16

  hipMemsetAsync(p + 52428800LL, 0, 256, stream);              // x16 K-pad
  hipMemsetAsync(out + 52428800LL, 0, 4915200LL * 4, stream);  // h_n + c_n
  hipMemsetAsync(flags, 0, 3 * 16 * 8 * 128, stream);          // all layer flags

  k_cvt_f16<<<2048, 256, 0, stream>>>(x, x16, 26214400LL);
  k_cvt_wih<<<2048, 256, 0, stream>>>(Wih, wih16);
  k_cvt_whh<<<2048, 256, 0, stream>>>(Whh, whh16, 9600);
  k_bias<<<40, 256, 0, stream>>>(bih, bhh, bias, 9600);

  int occ = 0;
  hipOccupancyMaxActiveBlocksPerMultiprocessor(&occ, k_rnn, 512, 0);
  const bool persistent = (occ >= 1);  // 208 blocks <= 256 CUs at 1/CU

  const long long OUTP = 52428800LL, HNSZ = 2457600LL;

  for (int L = 0; L < 3; ++L) {
    const f16* Ain = (L == 0) ? x16 : (L == 1 ? layA : layB);
    int lda = (L == 0) ? 400 : 800;
    int K   = (L == 0) ? 416 : 800;
    k_gemm<<<6400, 512, 0, stream>>>(Ain, wih16 + (size_t)(2 * L) * 1600 * 800,
                                     xproj, lda, K);
    hipMemsetAsync(h16, 0, 3407872LL, stream);
    float* hnL = out + OUTP + (size_t)(2 * L) * 409600;
    float* cnL = out + OUTP + HNSZ + (size_t)(2 * L) * 409600;
    f16* o16 = (L == 0) ? layA : (L == 1 ? layB : nullptr);
    float* o32 = (L == 2) ? out : nullptr;
    if (persistent) {
      k_rnn<<<RNN_BLOCKS, 512, 0, stream>>>(
          xproj, whh16 + (size_t)(2 * L) * 1600 * HLD, bias + (size_t)(2 * L) * 1600,
          h16, hnL, cnL, o16, o32, flags + (size_t)L * 16 * 8 * 32);
    } else {
      for (int s = 0; s < 128; ++s) {
        int tf = s, tb = 127 - s;
        int bsf = (int)bsv[tf], bsb = (int)bsv[tb];
        int nTf = (bsf + 127) / 128, nTb = (bsb + 127) / 128;
        k_step<<<25 * (nTf + nTb), 256, 0, stream>>>(
            xproj, whh16 + (size_t)(2 * L) * 1600 * HLD, bias + (size_t)(2 * L) * 1600,
            h16 + (size_t)(s & 1) * 1024 * HLD, h16 + (size_t)((s + 1) & 1) * 1024 * HLD,
            hnL, cnL, o16, o32,
            bsf, (int)offv[tf], bsb, (int)offv[tb], nTf);
      }
    }
  }
}